// Round 5
// baseline (308.162 us; speedup 1.0000x reference)
//
#include <hip/hip_runtime.h>
#include <hip/hip_bf16.h>
#include <math.h>

#define B_ 2
#define T_ 512
#define D_ 1024
#define H_ 16
#define R_ 32
#define DH 64
#define BT_ (B_*T_)
#define BH_ (B_*H_)

typedef __attribute__((ext_vector_type(8))) short bf16x8;
typedef __attribute__((ext_vector_type(4))) short s16x4;
typedef __attribute__((ext_vector_type(4))) float f32x4;

#define MFMA_BF16(a, b, c) __builtin_amdgcn_mfma_f32_16x16x32_bf16(a, b, c, 0, 0, 0)

static __device__ __forceinline__ short bf16s(float v) {
  __hip_bfloat16 b = __float2bfloat16(v);
  return *reinterpret_cast<short*>(&b);
}

// ---- shared MFMA helpers (layout verified in R2) ----
__device__ __forceinline__ bf16x8 ldfrag(const __hip_bfloat16 s[][72], int b16, int kb, int fr, int kq) {
  return *(const bf16x8*)&s[b16 * 16 + fr][kb * 32 + kq * 8];
}
__device__ __forceinline__ void stage64(const __hip_bfloat16* __restrict__ g, int ldg,
                                        __hip_bfloat16 s[][72], int tid) {
#pragma unroll
  for (int l = 0; l < 2; ++l) {
    int f = tid + l * 256;
    int r = f >> 3, c = (f & 7) << 3;
    *(int4*)&s[r][c] = *(const int4*)&g[(size_t)r * ldg + c];
  }
}

// ---- global_load_lds 16B direct-to-LDS (m97 pattern) ----
typedef const __attribute__((address_space(1))) void* as1cv;
typedef __attribute__((address_space(3))) void* as3v;
__device__ __forceinline__ void gl16(const __hip_bfloat16* g, __hip_bfloat16* l) {
  __builtin_amdgcn_global_load_lds((as1cv)g, (as3v)l, 16, 0, 0);
}

// ======================= split fp32 -> bf16 hi/lo =======================
__global__ __launch_bounds__(256) void split_f32(const float* __restrict__ in,
                                                 __hip_bfloat16* __restrict__ hi,
                                                 __hip_bfloat16* __restrict__ lo) {
  int i4 = blockIdx.x * 256 + threadIdx.x;
  float4 v = ((const float4*)in)[i4];
  s16x4 ph, pl;
  float c[4] = {v.x, v.y, v.z, v.w};
#pragma unroll
  for (int u = 0; u < 4; ++u) {
    __hip_bfloat16 h = __float2bfloat16(c[u]);
    ph[u] = *reinterpret_cast<short*>(&h);
    pl[u] = bf16s(c[u] - __bfloat162float(h));
  }
  ((s16x4*)hi)[i4] = ph;
  ((s16x4*)lo)[i4] = pl;
}

// ======================= transpose + split weights: W[K][N] -> WT hi/lo [N][K] ============
__global__ __launch_bounds__(256) void splitT_k(const float* __restrict__ Wm,
                                                __hip_bfloat16* __restrict__ thi,
                                                __hip_bfloat16* __restrict__ tlo) {
  __shared__ float tile[64][65];
  const int bn = blockIdx.x * 64, bk = blockIdx.y * 64;
  const int tid = threadIdx.x;
#pragma unroll
  for (int l = 0; l < 4; ++l) {
    int f = tid + l * 256; int r = f >> 4, c = (f & 15) << 2;
    *(float4*)&tile[r][c] = *(const float4*)&Wm[(size_t)(bk + r) * D_ + bn + c];
  }
  __syncthreads();
#pragma unroll
  for (int l = 0; l < 4; ++l) {
    int f = tid + l * 256; int n = f >> 4, k0 = (f & 15) << 2;
    s16x4 ph, pl;
#pragma unroll
    for (int u = 0; u < 4; ++u) {
      float v = tile[k0 + u][n];
      __hip_bfloat16 h = __float2bfloat16(v);
      ph[u] = *reinterpret_cast<short*>(&h);
      pl[u] = bf16s(v - __bfloat162float(h));
    }
    *(s16x4*)&thi[(size_t)(bn + n) * D_ + bk + k0] = ph;
    *(s16x4*)&tlo[(size_t)(bn + n) * D_ + bk + k0] = pl;
  }
}

// ======================= concat+transpose+split small proj weights [wA|bw|gw] -> [64][D] ==
__global__ __launch_bounds__(256) void splitcat_k(const float* __restrict__ wA,
                                                  const float* __restrict__ bw,
                                                  const float* __restrict__ gw,
                                                  __hip_bfloat16* __restrict__ thi,
                                                  __hip_bfloat16* __restrict__ tlo) {
  int n = blockIdx.x;          // 0..63
  int tid = threadIdx.x;
  for (int k = tid; k < D_; k += 256) {
    float v;
    if (n < 32) v = wA[(size_t)k * R_ + n];
    else if (n < 48) v = bw[(size_t)k * H_ + (n - 32)];
    else v = gw[(size_t)k * H_ + (n - 48)];
    __hip_bfloat16 h = __float2bfloat16(v);
    thi[(size_t)n * D_ + k] = h;
    tlo[(size_t)n * D_ + k] = __float2bfloat16(v - __bfloat162float(h));
  }
}

// ======================= big fp32-class GEMM: 128-col tile, virtual K=3072 =======================
// 3-pass hi/lo fold: pass0 ahi*bhi, pass1 alo*bhi, pass2 ahi*blo.
// MODE 0 (QKV fused, N=3072): n<2048 -> qk fp32 [m][2048]; n>=2048 -> V hi/lo bf16 [B,H,dh,T].
// MODE 1 (Wo): C[m][1024] fp32.
// BM: 128 (waves 2x2, 4 m-frags) or 64 (waves 2x2, 2 m-frags).
template<int MODE, int BM>
__global__ __launch_bounds__(256) void gemm128(const __hip_bfloat16* __restrict__ ah,
                                               const __hip_bfloat16* __restrict__ al,
                                               const __hip_bfloat16* __restrict__ bhp,
                                               const __hip_bfloat16* __restrict__ blp,
                                               float* __restrict__ C,
                                               __hip_bfloat16* __restrict__ vhi,
                                               __hip_bfloat16* __restrict__ vlo) {
  constexpr int MF = BM / 32;                 // m-frags per wave
  __shared__ __hip_bfloat16 As[2][BM][64];
  __shared__ __hip_bfloat16 Bs[2][128][64];
  const int bm = blockIdx.y * BM, bn = blockIdx.x * 128;
  const int tid = threadIdx.x, w = tid >> 6, lane = tid & 63;
  const int wr = (w >> 1) * (BM / 2), wc = (w & 1) * 64;
  const int fr = lane & 15, kq = lane >> 4;
  const f32x4 zf = {0.f, 0.f, 0.f, 0.f};
  f32x4 acc[MF][4];
#pragma unroll
  for (int m = 0; m < MF; ++m)
#pragma unroll
    for (int n = 0; n < 4; ++n) acc[m][n] = zf;

  const __hip_bfloat16* a0p = ah + (size_t)bm * D_;
  const __hip_bfloat16* a1p = al + (size_t)bm * D_;
  const __hip_bfloat16* b0p = bhp + (size_t)bn * D_;
  const __hip_bfloat16* b1p = blp + (size_t)bn * D_;

  // prologue: stage k-tile 0 into buffer 0
#pragma unroll
  for (int i = 0; i < BM / 32; ++i) {
    int chunk = w * (BM * 2) + i * 64 + lane;
    int row = chunk >> 3, c8 = chunk & 7;
    gl16(a0p + (size_t)row * D_ + c8 * 8, &As[0][0][0] + chunk * 8);
  }
#pragma unroll
  for (int i = 0; i < 4; ++i) {
    int chunk = w * 256 + i * 64 + lane;
    int row = chunk >> 3, c8 = chunk & 7;
    gl16(b0p + (size_t)row * D_ + c8 * 8, &Bs[0][0][0] + chunk * 8);
  }
  __syncthreads();   // drains vmcnt(0) before barrier

  for (int t = 0; t < 48; ++t) {
    const int cur = t & 1;
    if (t + 1 < 48) {                        // prefetch next k-tile into buf^1
      const int tn = t + 1, p = tn >> 4, k0 = (tn & 15) * 64;
      const __hip_bfloat16* ap = (p == 1) ? a1p : a0p;
      const __hip_bfloat16* bp = (p == 2) ? b1p : b0p;
#pragma unroll
      for (int i = 0; i < BM / 32; ++i) {
        int chunk = w * (BM * 2) + i * 64 + lane;
        int row = chunk >> 3, c8 = chunk & 7;
        gl16(ap + (size_t)row * D_ + k0 + c8 * 8, &As[cur ^ 1][0][0] + chunk * 8);
      }
#pragma unroll
      for (int i = 0; i < 4; ++i) {
        int chunk = w * 256 + i * 64 + lane;
        int row = chunk >> 3, c8 = chunk & 7;
        gl16(bp + (size_t)row * D_ + k0 + c8 * 8, &Bs[cur ^ 1][0][0] + chunk * 8);
      }
    }
    bf16x8 af[MF][2], bfr[4][2];
#pragma unroll
    for (int m = 0; m < MF; ++m) {
      af[m][0] = *(const bf16x8*)&As[cur][wr + m * 16 + fr][kq * 8];
      af[m][1] = *(const bf16x8*)&As[cur][wr + m * 16 + fr][32 + kq * 8];
    }
#pragma unroll
    for (int n = 0; n < 4; ++n) {
      bfr[n][0] = *(const bf16x8*)&Bs[cur][wc + n * 16 + fr][kq * 8];
      bfr[n][1] = *(const bf16x8*)&Bs[cur][wc + n * 16 + fr][32 + kq * 8];
    }
#pragma unroll
    for (int m = 0; m < MF; ++m)
#pragma unroll
      for (int n = 0; n < 4; ++n) {
        acc[m][n] = MFMA_BF16(af[m][0], bfr[n][0], acc[m][n]);
        acc[m][n] = MFMA_BF16(af[m][1], bfr[n][1], acc[m][n]);
      }
    __syncthreads();   // next buffer staged (vmcnt drained) + this buffer's reads done
  }

  // epilogue
#pragma unroll
  for (int m = 0; m < MF; ++m) {
#pragma unroll
    for (int n = 0; n < 4; ++n) {
#pragma unroll
      for (int reg = 0; reg < 4; ++reg) {
        int gm = bm + wr + m * 16 + kq * 4 + reg;
        int gn = bn + wc + n * 16 + fr;
        float v = acc[m][n][reg];
        if (MODE == 1) {
          C[(size_t)gm * D_ + gn] = v;
        } else {
          if (gn < 2048) {
            C[(size_t)gm * 2048 + gn] = v;         // q (gn<1024) | k (gn>=1024)
          } else {
            int nv = gn - 2048, h = nv >> 6, dd = nv & 63, b = gm >> 9, tt = gm & 511;
            size_t oi = (((size_t)(b * H_ + h)) * DH + dd) * T_ + tt;
            __hip_bfloat16 hv = __float2bfloat16(v);
            vhi[oi] = hv;
            vlo[oi] = __float2bfloat16(v - __bfloat162float(hv));
          }
        }
      }
    }
  }
}

// ======================= small GEMM for ycat (M=BT, N=64) via 3x bf16 MFMA ============
__global__ __launch_bounds__(256) void gemm_ycat(const __hip_bfloat16* __restrict__ ah,
                                                 const __hip_bfloat16* __restrict__ al,
                                                 const __hip_bfloat16* __restrict__ bh,
                                                 const __hip_bfloat16* __restrict__ bl,
                                                 float* __restrict__ C) {
  __shared__ __hip_bfloat16 Ah[64][72], Al[64][72], Bh[64][72], Bl[64][72];
  const int bm = blockIdx.y * 64;
  const int tid = threadIdx.x, w = tid >> 6, lane = tid & 63;
  const int fr = lane & 15, kq = lane >> 4;
  const f32x4 zf = {0.f, 0.f, 0.f, 0.f};
  f32x4 acc[4] = {zf, zf, zf, zf};
  for (int k0 = 0; k0 < D_; k0 += 64) {
    __syncthreads();
    stage64(ah + (size_t)bm * D_ + k0, D_, Ah, tid);
    stage64(al + (size_t)bm * D_ + k0, D_, Al, tid);
    stage64(bh + k0, D_, Bh, tid);
    stage64(bl + k0, D_, Bl, tid);
    __syncthreads();
    bf16x8 ah0 = ldfrag(Ah, w, 0, fr, kq), ah1 = ldfrag(Ah, w, 1, fr, kq);
    bf16x8 al0 = ldfrag(Al, w, 0, fr, kq), al1 = ldfrag(Al, w, 1, fr, kq);
#pragma unroll
    for (int nb = 0; nb < 4; ++nb) {
      bf16x8 b0 = ldfrag(Bh, nb, 0, fr, kq), b1 = ldfrag(Bh, nb, 1, fr, kq);
      bf16x8 c0 = ldfrag(Bl, nb, 0, fr, kq), c1 = ldfrag(Bl, nb, 1, fr, kq);
      acc[nb] = MFMA_BF16(ah0, b0, acc[nb]); acc[nb] = MFMA_BF16(ah1, b1, acc[nb]);
      acc[nb] = MFMA_BF16(ah0, c0, acc[nb]); acc[nb] = MFMA_BF16(ah1, c1, acc[nb]);
      acc[nb] = MFMA_BF16(al0, b0, acc[nb]); acc[nb] = MFMA_BF16(al1, b1, acc[nb]);
    }
  }
#pragma unroll
  for (int nb = 0; nb < 4; ++nb) {
    int n = nb * 16 + fr;
#pragma unroll
    for (int reg = 0; reg < 4; ++reg) {
      int m = bm + w * 16 + kq * 4 + reg;
      C[(size_t)m * 64 + n] = acc[nb][reg];
    }
  }
}

// ======================= gates: beta, logsigmoid + cumsum =======================
__global__ __launch_bounds__(512) void gate_cumsum(const float* __restrict__ ycat,
                                                   const float* __restrict__ gb,
                                                   float* __restrict__ beta,
                                                   float* __restrict__ G) {
  __shared__ float s[T_];
  int bh = blockIdx.x, b = bh >> 4, h = bh & 15, t = threadIdx.x;
  int bt = b * T_ + t;
  float by = ycat[(size_t)bt * 64 + 32 + h];
  beta[(size_t)bh * T_ + t] = 2.f / (1.f + expf(-by));
  float gy = ycat[(size_t)bt * 64 + 48 + h] + gb[h];
  s[t] = fminf(gy, 0.f) - log1pf(expf(-fabsf(gy)));
  __syncthreads();
  for (int off = 1; off < T_; off <<= 1) {
    float v = (t >= off) ? s[t - off] : 0.f;
    __syncthreads();
    s[t] += v;
    __syncthreads();
  }
  G[(size_t)bh * T_ + t] = s[t];
}

// ======================= w: low-rank expand + conv3 + silu + unit-normalize ===========
__global__ __launch_bounds__(1024) void wdir_k(const float* __restrict__ ycat,
                                               const float* __restrict__ wB,
                                               const float* __restrict__ convw,
                                               float* __restrict__ wT,
                                               __hip_bfloat16* __restrict__ wb16) {
  int bt = blockIdx.x, b = bt / T_, t = bt - b * T_;
  __shared__ float wl[3][R_];
  int tid = threadIdx.x;
  if (tid < 3 * R_) {
    int row = tid / R_, r = tid - row * R_;
    int ts = t - row;
    wl[row][r] = (ts >= 0) ? ycat[(size_t)(b * T_ + ts) * 64 + r] : 0.f;
  }
  __syncthreads();
  float f0 = 0.f, f1 = 0.f, f2 = 0.f;
  for (int r = 0; r < R_; ++r) {
    float wb = wB[(size_t)r * D_ + tid];
    f0 += wl[0][r] * wb; f1 += wl[1][r] * wb; f2 += wl[2][r] * wb;
  }
  float y = f2 * convw[tid * 3 + 0] + f1 * convw[tid * 3 + 1] + f0 * convw[tid * 3 + 2];
  float s = y / (1.f + expf(-y));                       // silu
  float ss = s * s;
#pragma unroll
  for (int m = 32; m >= 1; m >>= 1) ss += __shfl_xor(ss, m);
  float outv = s * rsqrtf(ss + 1e-12f);
  int h = tid >> 6, dd = tid & 63;
  size_t o = (((size_t)(b * H_ + h)) * T_ + t) * DH + dd;
  wT[o] = outv;
  wb16[o] = __float2bfloat16(outv);
}

// ======================= rmsnorm q,k (from unified qk buffer) -> bf16 [B,H,T,dh] ==========
__global__ __launch_bounds__(1024) void rmsT_k(const float* __restrict__ qk,
                                               const float* __restrict__ qnw,
                                               const float* __restrict__ knw,
                                               __hip_bfloat16* __restrict__ qb16,
                                               __hip_bfloat16* __restrict__ kb16) {
  int bt = blockIdx.x, b = bt / T_, t = bt - b * T_;
  int tid = threadIdx.x, h = tid >> 6, dd = tid & 63;
  float qv = qk[(size_t)bt * 2048 + tid];
  float kv = qk[(size_t)bt * 2048 + 1024 + tid];
  float sq = qv * qv, sk = kv * kv;
#pragma unroll
  for (int m = 32; m >= 1; m >>= 1) { sq += __shfl_xor(sq, m); sk += __shfl_xor(sk, m); }
  float qs = qv * rsqrtf(sq * (1.f / DH) + 1e-5f) * qnw[dd];
  float ks = kv * rsqrtf(sk * (1.f / DH) + 1e-5f) * knw[dd];
  size_t o = (((size_t)(b * H_ + h)) * T_ + t) * DH + dd;
  qb16[o] = __float2bfloat16(qs);
  kb16[o] = __float2bfloat16(ks);
}

// ======================= per-block unit-lower-triangular inverse =======================
__global__ __launch_bounds__(256) void linv_k(const float* __restrict__ wT,
                                              const float* __restrict__ beta,
                                              __hip_bfloat16* __restrict__ linv) {
  __shared__ float Wsh[64][68];
  __shared__ float Csh[64][65];
  __shared__ float Li[64][68];
  __shared__ float bI[64];
  const int I = blockIdx.x, bhx = blockIdx.y;
  const int tid = threadIdx.x;
#pragma unroll
  for (int l = 0; l < 4; ++l) {
    int f = tid + l * 256; int r = f >> 4, c = (f & 15) << 2;
    *(float4*)&Wsh[r][c] = *(const float4*)&wT[((size_t)bhx * T_ + I * 64 + r) * DH + c];
  }
  if (tid < 64) bI[tid] = beta[(size_t)bhx * T_ + I * 64 + tid];
#pragma unroll
  for (int l = 0; l < 16; ++l) {
    int e = tid + l * 256; int r = e >> 6, c = e & 63;
    Li[r][c] = (r == c) ? 1.f : 0.f;
  }
  __syncthreads();
  const int tm = (tid >> 4) << 2, tn = (tid & 15) << 2;
  float cc[4][4] = {};
  for (int dd = 0; dd < 64; ++dd) {
    float a0 = Wsh[tm + 0][dd], a1 = Wsh[tm + 1][dd], a2 = Wsh[tm + 2][dd], a3 = Wsh[tm + 3][dd];
    float b0 = Wsh[tn + 0][dd], b1 = Wsh[tn + 1][dd], b2 = Wsh[tn + 2][dd], b3 = Wsh[tn + 3][dd];
    cc[0][0] += a0 * b0; cc[0][1] += a0 * b1; cc[0][2] += a0 * b2; cc[0][3] += a0 * b3;
    cc[1][0] += a1 * b0; cc[1][1] += a1 * b1; cc[1][2] += a1 * b2; cc[1][3] += a1 * b3;
    cc[2][0] += a2 * b0; cc[2][1] += a2 * b1; cc[2][2] += a2 * b2; cc[2][3] += a2 * b3;
    cc[3][0] += a3 * b0; cc[3][1] += a3 * b1; cc[3][2] += a3 * b2; cc[3][3] += a3 * b3;
  }
#pragma unroll
  for (int ii = 0; ii < 4; ++ii)
#pragma unroll
    for (int jj = 0; jj < 4; ++jj)
      Csh[tm + ii][tn + jj] = (tm + ii > tn + jj) ? cc[ii][jj] * bI[tn + jj] : 0.f;
  __syncthreads();
  const int sL = tid & 63, g = tid >> 6;
  for (int r = 0; r < 63; ++r) {
    float lr = Li[r][sL];
    for (int r2 = r + 1 + g; r2 < 64; r2 += 4)
      Li[r2][sL] -= Csh[r2][r] * lr;
    __syncthreads();
  }
#pragma unroll
  for (int l = 0; l < 4; ++l) {
    int f = tid + l * 256; int r = f >> 4, c0 = (f & 15) << 2;
    s16x4 p;
    p.x = bf16s(Li[r][c0 + 0]); p.y = bf16s(Li[r][c0 + 1]);
    p.z = bf16s(Li[r][c0 + 2]); p.w = bf16s(Li[r][c0 + 3]);
    *(s16x4*)&linv[((size_t)(bhx * 8 + I)) * 4096 + r * 64 + c0] = p;
  }
}

// ======================= WY chain: per column-chunk, MFMA recurrence =======================
__global__ __launch_bounds__(256) void chain_k(const __hip_bfloat16* __restrict__ kb,
                                               const __hip_bfloat16* __restrict__ wb,
                                               const __hip_bfloat16* __restrict__ linv,
                                               const float* __restrict__ beta,
                                               __hip_bfloat16* __restrict__ abT) {
  __shared__ __hip_bfloat16 Kb[64][72];   // [j][d]
  __shared__ __hip_bfloat16 Ws[64][72];   // [t][d]
  __shared__ __hip_bfloat16 WsT[64][72];  // [d][t]
  __shared__ __hip_bfloat16 Ls[64][72];   // [t][s]
  __shared__ __hip_bfloat16 Mhi[64][72];  // [j][d] = -M hi
  __shared__ __hip_bfloat16 Mlo[64][72];  // [j][d] = -M lo
  __shared__ __hip_bfloat16 Ps[64][72];   // [j][t] PT, then reused as X
  __shared__ float bI[64];
  const int ch = blockIdx.x, bhx = blockIdx.y;
  const int tid = threadIdx.x, w = tid >> 6, lane = tid & 63;
  const int fr = lane & 15, kq = lane >> 4;
  const size_t hb = (size_t)bhx * T_;
  const f32x4 zf = {0.f, 0.f, 0.f, 0.f};

  stage64(kb + (hb + ch * 64) * DH, DH, Kb, tid);
  for (int f = tid; f < 576; f += 256) {
    ((int4*)Mhi)[f] = make_int4(0, 0, 0, 0);
    ((int4*)Mlo)[f] = make_int4(0, 0, 0, 0);
  }
  f32x4 macc[4] = {zf, zf, zf, zf};

  for (int I = ch; I < 8; ++I) {
    __syncthreads();                                           // B1
    stage64(wb + (hb + I * 64) * DH, DH, Ws, tid);
    stage64(linv + ((size_t)(bhx * 8 + I)) * 4096, 64, Ls, tid);
    if (tid < 64) bI[tid] = beta[hb + I * 64 + tid];
    const int jr = w * 16 + kq * 4;
    if (I > ch) {
#pragma unroll
      for (int nb = 0; nb < 4; ++nb) {
        int d = nb * 16 + fr;
#pragma unroll
        for (int reg = 0; reg < 4; ++reg) {
          float m = -macc[nb][reg];
          __hip_bfloat16 h = __float2bfloat16(m);
          Mhi[jr + reg][d] = h;
          Mlo[jr + reg][d] = __float2bfloat16(m - __bfloat162float(h));
        }
      }
    }
    __syncthreads();                                           // B2
#pragma unroll
    for (int l = 0; l < 16; ++l) {
      int e = tid + l * 256;
      int t = e >> 6, d = e & 63;
      WsT[d][t] = Ws[t][d];
    }
    bf16x8 kb0 = ldfrag(Kb, w, 0, fr, kq), kb1 = ldfrag(Kb, w, 1, fr, kq);
    f32x4 pt[4];
#pragma unroll
    for (int nb = 0; nb < 4; ++nb) {
      bf16x8 b0 = ldfrag(Ws, nb, 0, fr, kq), b1 = ldfrag(Ws, nb, 1, fr, kq);
      pt[nb] = MFMA_BF16(kb0, b0, zf);
      pt[nb] = MFMA_BF16(kb1, b1, pt[nb]);
      if (I > ch) {
        bf16x8 mh0 = ldfrag(Mhi, w, 0, fr, kq), mh1 = ldfrag(Mhi, w, 1, fr, kq);
        bf16x8 ml0 = ldfrag(Mlo, w, 0, fr, kq), ml1 = ldfrag(Mlo, w, 1, fr, kq);
        pt[nb] = MFMA_BF16(mh0, b0, pt[nb]); pt[nb] = MFMA_BF16(mh1, b1, pt[nb]);
        pt[nb] = MFMA_BF16(ml0, b0, pt[nb]); pt[nb] = MFMA_BF16(ml1, b1, pt[nb]);
      }
    }
#pragma unroll
    for (int nb = 0; nb < 4; ++nb) {
      int t = nb * 16 + fr;
#pragma unroll
      for (int reg = 0; reg < 4; ++reg) {
        float v = pt[nb][reg];
        if (I == ch && t <= jr + reg) v = 0.f;
        Ps[jr + reg][t] = __float2bfloat16(v);
      }
    }
    __syncthreads();                                           // B3
    bf16x8 la0 = ldfrag(Ls, w, 0, fr, kq), la1 = ldfrag(Ls, w, 1, fr, kq);
    f32x4 av[4];
#pragma unroll
    for (int nb = 0; nb < 4; ++nb) {
      bf16x8 p0 = ldfrag(Ps, nb, 0, fr, kq), p1 = ldfrag(Ps, nb, 1, fr, kq);
      av[nb] = MFMA_BF16(la0, p0, zf);
      av[nb] = MFMA_BF16(la1, p1, av[nb]);
    }
    __syncthreads();                                           // B4
    const int tr = w * 16 + kq * 4;
#pragma unroll
    for (int nb = 0; nb < 4; ++nb) {
      s16x4 p;
      p.x = bf16s(bI[tr + 0] * av[nb][0]);
      p.y = bf16s(bI[tr + 1] * av[nb][1]);
      p.z = bf16s(bI[tr + 2] * av[nb][2]);
      p.w = bf16s(bI[tr + 3] * av[nb][3]);
      *(s16x4*)&Ps[nb * 16 + fr][tr] = p;
    }
    __syncthreads();                                           // B5
#pragma unroll
    for (int l = 0; l < 2; ++l) {
      int f = tid + l * 256;
      int r = f >> 3, c = (f & 7) << 3;
      *(int4*)&abT[(hb + ch * 64 + r) * T_ + I * 64 + c] = *(const int4*)&Ps[r][c];
    }
    bf16x8 xa0 = ldfrag(Ps, w, 0, fr, kq), xa1 = ldfrag(Ps, w, 1, fr, kq);
#pragma unroll
    for (int nb = 0; nb < 4; ++nb) {
      bf16x8 wt0 = ldfrag(WsT, nb, 0, fr, kq), wt1 = ldfrag(WsT, nb, 1, fr, kq);
      macc[nb] = MFMA_BF16(xa0, wt0, macc[nb]);
      macc[nb] = MFMA_BF16(xa1, wt1, macc[nb]);
    }
  }
}

// ======================= S via MFMA: S = Q K^T - tril(Q W^T) @ (beta A) =======================
__global__ __launch_bounds__(256) void s_mfma(const __hip_bfloat16* __restrict__ qb,
                                              const __hip_bfloat16* __restrict__ kb,
                                              const __hip_bfloat16* __restrict__ wb,
                                              const __hip_bfloat16* __restrict__ abT,
                                              float* __restrict__ S) {
  __shared__ __hip_bfloat16 Qs[64][72];
  __shared__ __hip_bfloat16 Bs[64][72];
  __shared__ __hip_bfloat16 Cs[64][72];
  __shared__ __hip_bfloat16 Ms[64][72];
  int ti = blockIdx.x;
  int it = 0, accum = 0;
  while (accum + it + 1 <= ti) { accum += it + 1; ++it; }
  const int jt = ti - accum;
  const int bh = blockIdx.y;
  const int tid = threadIdx.x, w = tid >> 6, lane = tid & 63;
  const int fr = lane & 15, kq = lane >> 4;
  const size_t hb = (size_t)bh * T_;

  stage64(qb + (hb + it * 64) * DH, DH, Qs, tid);
  stage64(kb + (hb + jt * 64) * DH, DH, Bs, tid);
  __syncthreads();

  const bf16x8 a0 = ldfrag(Qs, w, 0, fr, kq);
  const bf16x8 a1 = ldfrag(Qs, w, 1, fr, kq);

  f32x4 acc[4];
  const f32x4 zero = {0.f, 0.f, 0.f, 0.f};
#pragma unroll
  for (int nb = 0; nb < 4; ++nb) {
    acc[nb] = MFMA_BF16(a0, ldfrag(Bs, nb, 0, fr, kq), zero);
    acc[nb] = MFMA_BF16(a1, ldfrag(Bs, nb, 1, fr, kq), acc[nb]);
  }

  for (int c = jt; c <= it; ++c) {
    __syncthreads();
    stage64(wb + (hb + c * 64) * DH, DH, Bs, tid);
    stage64(abT + (hb + jt * 64) * T_ + c * 64, T_, Cs, tid);
    __syncthreads();
    f32x4 qw[4];
#pragma unroll
    for (int nb = 0; nb < 4; ++nb) {
      qw[nb] = MFMA_BF16(a0, ldfrag(Bs, nb, 0, fr, kq), zero);
      qw[nb] = MFMA_BF16(a1, ldfrag(Bs, nb, 1, fr, kq), qw[nb]);
    }
    const int row0 = w * 16 + kq * 4;
    const bool diag = (c == it);
#pragma unroll
    for (int nb = 0; nb < 4; ++nb) {
      int col = nb * 16 + fr;
#pragma unroll
      for (int reg = 0; reg < 4; ++reg) {
        float v = -qw[nb][reg];
        if (diag && col > row0 + reg) v = 0.f;
        Ms[row0 + reg][col] = __float2bfloat16(v);
      }
    }
    __syncthreads();
    const bf16x8 m0 = ldfrag(Ms, w, 0, fr, kq);
    const bf16x8 m1 = ldfrag(Ms, w, 1, fr, kq);
#pragma unroll
    for (int nb = 0; nb < 4; ++nb) {
      acc[nb] = MFMA_BF16(m0, ldfrag(Cs, nb, 0, fr, kq), acc[nb]);
      acc[nb] = MFMA_BF16(m1, ldfrag(Cs, nb, 1, fr, kq), acc[nb]);
    }
  }
#pragma unroll
  for (int nb = 0; nb < 4; ++nb) {
    int j = jt * 64 + nb * 16 + fr;
#pragma unroll
    for (int reg = 0; reg < 4; ++reg) {
      S[(hb + it * 64 + w * 16 + kq * 4 + reg) * T_ + j] = acc[nb][reg];
    }
  }
}

// ======================= softmax, causal, P written bf16 in place =======================
__global__ __launch_bounds__(64) void softmax_k(float* __restrict__ S, const float* __restrict__ G) {
  int i = blockIdx.x, bh = blockIdx.y;
  int lane = threadIdx.x;
  const float Gi = G[(size_t)bh * T_ + i];
  float* row = S + ((size_t)bh * T_ + i) * T_;
  const float* Gb = G + (size_t)bh * T_;
  float l[8];
  float m = -3e38f;
#pragma unroll
  for (int c = 0; c < 8; ++c) {
    int j = lane + c * 64;
    if (j <= i) { float v = row[j] * 0.125f + Gi - Gb[j]; l[c] = v; m = fmaxf(m, v); }
    else l[c] = -3e38f;
  }
#pragma unroll
  for (int mm = 32; mm >= 1; mm >>= 1) m = fmaxf(m, __shfl_xor(m, mm));
  float ssum = 0.f;
#pragma unroll
  for (int c = 0; c < 8; ++c) {
    int j = lane + c * 64;
    float p = (j <= i) ? expf(l[c] - m) : 0.f;
    l[c] = p; ssum += p;
  }
#pragma unroll
  for (int mm = 32; mm >= 1; mm >>= 1) ssum += __shfl_xor(ssum, mm);
  float inv = 1.f / ssum;
  __hip_bfloat16* prow = (__hip_bfloat16*)row;
#pragma unroll
  for (int c = 0; c < 8; ++c) prow[lane + c * 64] = __float2bfloat16(l[c] * inv);
}

// ======================= o = P @ V via MFMA (P bf16, V hi/lo bf16 transposed) ==========
__global__ __launch_bounds__(256) void pv_mfma(const __hip_bfloat16* __restrict__ pb,  // ld 2*T_
                                               const __hip_bfloat16* __restrict__ vhi, // [BH,dh,T]
                                               const __hip_bfloat16* __restrict__ vlo,
                                               __hip_bfloat16* __restrict__ ohi,
                                               __hip_bfloat16* __restrict__ olo) {
  __shared__ __hip_bfloat16 Ps[64][72];   // [i][t]
  __shared__ __hip_bfloat16 Vh[64][72];   // [dd][t]
  __shared__ __hip_bfloat16 Vl[64][72];   // [dd][t]
  const int it = blockIdx.x, bh = blockIdx.y;
  const int b = bh >> 4, h = bh & 15;
  const int tid = threadIdx.x, w = tid >> 6, lane = tid & 63;
  const int fr = lane & 15, kq = lane >> 4;
  const f32x4 zf = {0.f, 0.f, 0.f, 0.f};
  f32x4 acc[4] = {zf, zf, zf, zf};
  for (int c = 0; c <= it; ++c) {
    __syncthreads();
    stage64(pb + ((size_t)bh * T_ + it * 64) * (2 * T_) + c * 64, 2 * T_, Ps, tid);
    stage64(vhi + ((size_t)bh * DH) * T_ + c * 64, T_, Vh, tid);
    stage64(vlo + ((size_t)bh * DH) * T_ + c * 64, T_, Vl, tid);
    __syncthreads();
    bf16x8 p0 = ldfrag(Ps, w, 0, fr, kq), p1 = ldfrag(Ps, w, 1, fr, kq);
#pragma unroll
    for (int nb = 0; nb < 4; ++nb) {
      acc[nb] = MFMA_BF16(p0, ldfrag(Vh, nb, 0, fr, kq), acc[nb]);
      acc[nb] = MFMA_BF16(p1, ldfrag(Vh, nb, 1, fr, kq), acc[nb]);
      acc[nb] = MFMA_BF16(p0, ldfrag(Vl, nb, 0, fr, kq), acc[nb]);
      acc[nb] = MFMA_BF16(p1, ldfrag(Vl, nb, 1, fr, kq), acc[nb]);
    }
  }
#pragma unroll
  for (int nb = 0; nb < 4; ++nb) {
    int dd = nb * 16 + fr;
#pragma unroll
    for (int reg = 0; reg < 4; ++reg) {
      int i = it * 64 + w * 16 + kq * 4 + reg;
      size_t oi = ((size_t)(b * T_ + i)) * D_ + h * 64 + dd;
      float v = acc[nb][reg];
      __hip_bfloat16 hv = __float2bfloat16(v);
      ohi[oi] = hv;
      olo[oi] = __float2bfloat16(v - __bfloat162float(hv));
    }
  }
}

// ======================= launch =======================
extern "C" void kernel_launch(void* const* d_in, const int* in_sizes, int n_in,
                              void* d_out, int out_size, void* d_ws, size_t ws_size,
                              hipStream_t stream) {
  (void)in_sizes; (void)n_in; (void)out_size; (void)ws_size;
  const float* x     = (const float*)d_in[0];
  const float* Wq    = (const float*)d_in[1];
  const float* Wk    = (const float*)d_in[2];
  const float* Wv    = (const float*)d_in[3];
  const float* Wo    = (const float*)d_in[4];
  const float* wA    = (const float*)d_in[5];
  const float* wB    = (const float*)d_in[6];
  const float* convw = (const float*)d_in[7];
  const float* bw    = (const float*)d_in[8];
  const float* gw    = (const float*)d_in[9];
  const float* gb    = (const float*)d_in[10];
  const float* qnw   = (const float*)d_in[11];
  const float* knw   = (const float*)d_in[12];

  const size_t N1 = (size_t)BT_ * D_;          // 1,048,576
  const size_t NTT = (size_t)BH_ * T_ * T_;    // 8,388,608
  float* ws = (float*)d_ws;
  float* qk   = ws;                        // [BT][2048] fp32 (q | k)
  float* wTb  = qk + (size_t)BT_ * 2048;   // [BH,T,dh] fp32
  float* ycat = wTb + N1;                  // [BT,64] fp32
  float* S    = ycat + (size_t)BT_ * 64;   // [BH,T,T] fp32 (P bf16 aliases rows)
  float* beta = S + NTT;
  float* G    = beta + (size_t)BH_ * T_;
  __hip_bfloat16* qb16  = (__hip_bfloat16*)(G + (size_t)BH_ * T_);
  __hip_bfloat16* kb16  = qb16 + N1;
  __hip_bfloat16* wb16  = kb16 + N1;
  __hip_bfloat16* abT   = wb16 + N1;            // [BH,T(j),T(t)] bf16
  __hip_bfloat16* linvb = abT + NTT;            // [BH,8,64,64] bf16
  __hip_bfloat16* xhi   = linvb + (size_t)BH_ * 8 * 4096;
  __hip_bfloat16* xlo   = xhi + N1;
  __hip_bfloat16* obhi  = xlo + N1;
  __hip_bfloat16* oblo  = obhi + N1;
  __hip_bfloat16* woThi = oblo + N1;
  __hip_bfloat16* woTlo = woThi + N1;
  __hip_bfloat16* vhi   = woTlo + N1;           // [BH,dh,T] bf16
  __hip_bfloat16* vlo   = vhi + N1;
  __hip_bfloat16* wcThi = vlo + N1;             // [64][D]
  __hip_bfloat16* wcTlo = wcThi + (size_t)64 * D_;
  // fused QKV weight [3072][1024] hi/lo aliases S (S written later in stream order)
  __hip_bfloat16* wqkvThi = (__hip_bfloat16*)S;
  __hip_bfloat16* wqkvTlo = wqkvThi + (size_t)3072 * D_;

  dim3 g16(16, 16);
  split_f32<<<1024, 256, 0, stream>>>(x, xhi, xlo);
  splitT_k<<<g16, 256, 0, stream>>>(Wq, wqkvThi, wqkvTlo);
  splitT_k<<<g16, 256, 0, stream>>>(Wk, wqkvThi + (size_t)1024 * D_, wqkvTlo + (size_t)1024 * D_);
  splitT_k<<<g16, 256, 0, stream>>>(Wv, wqkvThi + (size_t)2048 * D_, wqkvTlo + (size_t)2048 * D_);
  splitT_k<<<g16, 256, 0, stream>>>(Wo, woThi, woTlo);
  splitcat_k<<<64, 256, 0, stream>>>(wA, bw, gw, wcThi, wcTlo);
  // fused Q|K|V projection: M=1024, N=3072, virtual K=3072
  gemm128<0, 128><<<dim3(24, 8), 256, 0, stream>>>(xhi, xlo, wqkvThi, wqkvTlo, qk, vhi, vlo);
  gemm_ycat<<<dim3(1, 16), 256, 0, stream>>>(xhi, xlo, wcThi, wcTlo, ycat);
  gate_cumsum<<<BH_, 512, 0, stream>>>(ycat, gb, beta, G);
  wdir_k<<<BT_, 1024, 0, stream>>>(ycat, wB, convw, wTb, wb16);
  rmsT_k<<<BT_, 1024, 0, stream>>>(qk, qnw, knw, qb16, kb16);
  linv_k<<<dim3(8, BH_), 256, 0, stream>>>(wTb, beta, linvb);
  chain_k<<<dim3(8, BH_), 256, 0, stream>>>(kb16, wb16, linvb, beta, abT);
  s_mfma<<<dim3(36, BH_), 256, 0, stream>>>(qb16, kb16, wb16, abT, S);
  softmax_k<<<dim3(T_, BH_), 64, 0, stream>>>(S, G);
  pv_mfma<<<dim3(8, BH_), 256, 0, stream>>>((const __hip_bfloat16*)S, vhi, vlo, obhi, oblo);
  // output projection: M=1024, N=1024, virtual K=3072 (BM=64 for CU coverage)
  gemm128<1, 64><<<dim3(8, 16), 256, 0, stream>>>(obhi, oblo, woThi, woTlo, (float*)d_out, nullptr, nullptr);
}

// Round 6
// 246.091 us; speedup vs baseline: 1.2522x; 1.2522x over previous
//
#include <hip/hip_runtime.h>
#include <hip/hip_bf16.h>
#include <math.h>

#define B_ 2
#define T_ 512
#define D_ 1024
#define H_ 16
#define R_ 32
#define DH 64
#define BT_ (B_*T_)
#define BH_ (B_*H_)

typedef __attribute__((ext_vector_type(8))) short bf16x8;
typedef __attribute__((ext_vector_type(4))) short s16x4;
typedef __attribute__((ext_vector_type(4))) float f32x4;

#define MFMA_BF16(a, b, c) __builtin_amdgcn_mfma_f32_16x16x32_bf16(a, b, c, 0, 0, 0)

static __device__ __forceinline__ short bf16s(float v) {
  __hip_bfloat16 b = __float2bfloat16(v);
  return *reinterpret_cast<short*>(&b);
}

// ---- shared MFMA helpers (layout verified in R2; [72] pad = 144B stride, conflict-free) ----
__device__ __forceinline__ bf16x8 ldfrag(const __hip_bfloat16 s[][72], int b16, int kb, int fr, int kq) {
  return *(const bf16x8*)&s[b16 * 16 + fr][kb * 32 + kq * 8];
}
__device__ __forceinline__ void stage64(const __hip_bfloat16* __restrict__ g, int ldg,
                                        __hip_bfloat16 s[][72], int tid) {
#pragma unroll
  for (int l = 0; l < 2; ++l) {
    int f = tid + l * 256;
    int r = f >> 3, c = (f & 7) << 3;
    *(int4*)&s[r][c] = *(const int4*)&g[(size_t)r * ldg + c];
  }
}

// ---- global_load_lds 16B direct-to-LDS (m97 pattern) ----
typedef const __attribute__((address_space(1))) void* as1cv;
typedef __attribute__((address_space(3))) void* as3v;
__device__ __forceinline__ void gl16(const __hip_bfloat16* g, __hip_bfloat16* l) {
  __builtin_amdgcn_global_load_lds((as1cv)g, (as3v)l, 16, 0, 0);
}

// ======================= split fp32 -> bf16 hi/lo =======================
__global__ __launch_bounds__(256) void split_f32(const float* __restrict__ in,
                                                 __hip_bfloat16* __restrict__ hi,
                                                 __hip_bfloat16* __restrict__ lo) {
  int i4 = blockIdx.x * 256 + threadIdx.x;
  float4 v = ((const float4*)in)[i4];
  s16x4 ph, pl;
  float c[4] = {v.x, v.y, v.z, v.w};
#pragma unroll
  for (int u = 0; u < 4; ++u) {
    __hip_bfloat16 h = __float2bfloat16(c[u]);
    ph[u] = *reinterpret_cast<short*>(&h);
    pl[u] = bf16s(c[u] - __bfloat162float(h));
  }
  ((s16x4*)hi)[i4] = ph;
  ((s16x4*)lo)[i4] = pl;
}

// ======================= transpose + split weights: W[K][N] -> WT hi/lo [N][K] ============
__global__ __launch_bounds__(256) void splitT_k(const float* __restrict__ Wm,
                                                __hip_bfloat16* __restrict__ thi,
                                                __hip_bfloat16* __restrict__ tlo) {
  __shared__ float tile[64][65];
  const int bn = blockIdx.x * 64, bk = blockIdx.y * 64;
  const int tid = threadIdx.x;
#pragma unroll
  for (int l = 0; l < 4; ++l) {
    int f = tid + l * 256; int r = f >> 4, c = (f & 15) << 2;
    *(float4*)&tile[r][c] = *(const float4*)&Wm[(size_t)(bk + r) * D_ + bn + c];
  }
  __syncthreads();
#pragma unroll
  for (int l = 0; l < 4; ++l) {
    int f = tid + l * 256; int n = f >> 4, k0 = (f & 15) << 2;
    s16x4 ph, pl;
#pragma unroll
    for (int u = 0; u < 4; ++u) {
      float v = tile[k0 + u][n];
      __hip_bfloat16 h = __float2bfloat16(v);
      ph[u] = *reinterpret_cast<short*>(&h);
      pl[u] = bf16s(v - __bfloat162float(h));
    }
    *(s16x4*)&thi[(size_t)(bn + n) * D_ + bk + k0] = ph;
    *(s16x4*)&tlo[(size_t)(bn + n) * D_ + bk + k0] = pl;
  }
}

// ======================= concat+transpose+split small proj weights [wA|bw|gw] -> [64][D] ==
__global__ __launch_bounds__(256) void splitcat_k(const float* __restrict__ wA,
                                                  const float* __restrict__ bw,
                                                  const float* __restrict__ gw,
                                                  __hip_bfloat16* __restrict__ thi,
                                                  __hip_bfloat16* __restrict__ tlo) {
  int n = blockIdx.x;          // 0..63
  int tid = threadIdx.x;
  for (int k = tid; k < D_; k += 256) {
    float v;
    if (n < 32) v = wA[(size_t)k * R_ + n];
    else if (n < 48) v = bw[(size_t)k * H_ + (n - 32)];
    else v = gw[(size_t)k * H_ + (n - 48)];
    __hip_bfloat16 h = __float2bfloat16(v);
    thi[(size_t)n * D_ + k] = h;
    tlo[(size_t)n * D_ + k] = __float2bfloat16(v - __bfloat162float(h));
  }
}

// ======================= big fp32-class GEMM: swizzled LDS, virtual K=3072 =======================
// 3-pass hi/lo fold: pass0 ahi*bhi, pass1 alo*bhi, pass2 ahi*blo.
// LDS XOR swizzle (rule #21): linear gl_lds dest; SOURCE chunk pre-swizzled c8^=(row&7);
// fragment reads apply the same XOR -> 2-way bank aliasing (free) instead of 16-way.
// MODE 0 (QKV fused, N=3072): gn<2048 -> qk fp32 [m][2048]; gn>=2048 -> V hi/lo bf16 [B,H,dh,T].
// MODE 1 (Wo): C[m][1024] fp32.
template<int MODE, int BM, int BN>
__global__ __launch_bounds__(256) void gemm128(const __hip_bfloat16* __restrict__ ah,
                                               const __hip_bfloat16* __restrict__ al,
                                               const __hip_bfloat16* __restrict__ bhp,
                                               const __hip_bfloat16* __restrict__ blp,
                                               float* __restrict__ C,
                                               __hip_bfloat16* __restrict__ vhi,
                                               __hip_bfloat16* __restrict__ vlo) {
  constexpr int MF = BM / 32;                 // m-frags per wave (2x2 wave grid)
  constexpr int NF = BN / 32;                 // n-frags per wave
  __shared__ __hip_bfloat16 As[2][BM][64];
  __shared__ __hip_bfloat16 Bs[2][BN][64];
  const int bm = blockIdx.y * BM, bn = blockIdx.x * BN;
  const int tid = threadIdx.x, w = tid >> 6, lane = tid & 63;
  const int wr = (w >> 1) * (BM / 2), wc = (w & 1) * (BN / 2);
  const int fr = lane & 15, kq = lane >> 4;
  const f32x4 zf = {0.f, 0.f, 0.f, 0.f};
  f32x4 acc[MF][NF];
#pragma unroll
  for (int m = 0; m < MF; ++m)
#pragma unroll
    for (int n = 0; n < NF; ++n) acc[m][n] = zf;

  const __hip_bfloat16* a0p = ah + (size_t)bm * D_;
  const __hip_bfloat16* a1p = al + (size_t)bm * D_;
  const __hip_bfloat16* b0p = bhp + (size_t)bn * D_;
  const __hip_bfloat16* b1p = blp + (size_t)bn * D_;

  // prologue: stage k-tile 0 into buffer 0 (source chunk swizzled)
#pragma unroll
  for (int i = 0; i < BM / 32; ++i) {
    int chunk = w * (BM * 2) + i * 64 + lane;
    int row = chunk >> 3, c8 = (chunk & 7) ^ (row & 7);
    gl16(a0p + (size_t)row * D_ + c8 * 8, &As[0][0][0] + chunk * 8);
  }
#pragma unroll
  for (int i = 0; i < BN / 32; ++i) {
    int chunk = w * (BN * 2) + i * 64 + lane;
    int row = chunk >> 3, c8 = (chunk & 7) ^ (row & 7);
    gl16(b0p + (size_t)row * D_ + c8 * 8, &Bs[0][0][0] + chunk * 8);
  }
  __syncthreads();   // drains vmcnt(0) before barrier

  for (int t = 0; t < 48; ++t) {
    const int cur = t & 1;
    if (t + 1 < 48) {                        // prefetch next k-tile into buf^1
      const int tn = t + 1, p = tn >> 4, k0 = (tn & 15) * 64;
      const __hip_bfloat16* ap = (p == 1) ? a1p : a0p;
      const __hip_bfloat16* bp = (p == 2) ? b1p : b0p;
#pragma unroll
      for (int i = 0; i < BM / 32; ++i) {
        int chunk = w * (BM * 2) + i * 64 + lane;
        int row = chunk >> 3, c8 = (chunk & 7) ^ (row & 7);
        gl16(ap + (size_t)row * D_ + k0 + c8 * 8, &As[cur ^ 1][0][0] + chunk * 8);
      }
#pragma unroll
      for (int i = 0; i < BN / 32; ++i) {
        int chunk = w * (BN * 2) + i * 64 + lane;
        int row = chunk >> 3, c8 = (chunk & 7) ^ (row & 7);
        gl16(bp + (size_t)row * D_ + k0 + c8 * 8, &Bs[cur ^ 1][0][0] + chunk * 8);
      }
    }
    bf16x8 af[MF][2], bfr[NF][2];
#pragma unroll
    for (int m = 0; m < MF; ++m) {
      int ra = wr + m * 16 + fr, sa = ra & 7;
      af[m][0] = *(const bf16x8*)&As[cur][ra][(kq ^ sa) * 8];
      af[m][1] = *(const bf16x8*)&As[cur][ra][((kq + 4) ^ sa) * 8];
    }
#pragma unroll
    for (int n = 0; n < NF; ++n) {
      int rb = wc + n * 16 + fr, sb = rb & 7;
      bfr[n][0] = *(const bf16x8*)&Bs[cur][rb][(kq ^ sb) * 8];
      bfr[n][1] = *(const bf16x8*)&Bs[cur][rb][((kq + 4) ^ sb) * 8];
    }
#pragma unroll
    for (int m = 0; m < MF; ++m)
#pragma unroll
      for (int n = 0; n < NF; ++n) {
        acc[m][n] = MFMA_BF16(af[m][0], bfr[n][0], acc[m][n]);
        acc[m][n] = MFMA_BF16(af[m][1], bfr[n][1], acc[m][n]);
      }
    __syncthreads();   // next buffer staged (vmcnt drained) + this buffer's reads done
  }

  // epilogue
#pragma unroll
  for (int m = 0; m < MF; ++m) {
#pragma unroll
    for (int n = 0; n < NF; ++n) {
#pragma unroll
      for (int reg = 0; reg < 4; ++reg) {
        int gm = bm + wr + m * 16 + kq * 4 + reg;
        int gn = bn + wc + n * 16 + fr;
        float v = acc[m][n][reg];
        if (MODE == 1) {
          C[(size_t)gm * D_ + gn] = v;
        } else {
          if (gn < 2048) {
            C[(size_t)gm * 2048 + gn] = v;         // q (gn<1024) | k (gn>=1024)
          } else {
            int nv = gn - 2048, h = nv >> 6, dd = nv & 63, b = gm >> 9, tt = gm & 511;
            size_t oi = (((size_t)(b * H_ + h)) * DH + dd) * T_ + tt;
            __hip_bfloat16 hv = __float2bfloat16(v);
            vhi[oi] = hv;
            vlo[oi] = __float2bfloat16(v - __bfloat162float(hv));
          }
        }
      }
    }
  }
}

// ======================= small GEMM for ycat (M=BT, N=64) via 3x bf16 MFMA ============
__global__ __launch_bounds__(256) void gemm_ycat(const __hip_bfloat16* __restrict__ ah,
                                                 const __hip_bfloat16* __restrict__ al,
                                                 const __hip_bfloat16* __restrict__ bh,
                                                 const __hip_bfloat16* __restrict__ bl,
                                                 float* __restrict__ C) {
  __shared__ __hip_bfloat16 Ah[64][72], Al[64][72], Bh[64][72], Bl[64][72];
  const int bm = blockIdx.y * 64;
  const int tid = threadIdx.x, w = tid >> 6, lane = tid & 63;
  const int fr = lane & 15, kq = lane >> 4;
  const f32x4 zf = {0.f, 0.f, 0.f, 0.f};
  f32x4 acc[4] = {zf, zf, zf, zf};
  for (int k0 = 0; k0 < D_; k0 += 64) {
    __syncthreads();
    stage64(ah + (size_t)bm * D_ + k0, D_, Ah, tid);
    stage64(al + (size_t)bm * D_ + k0, D_, Al, tid);
    stage64(bh + k0, D_, Bh, tid);
    stage64(bl + k0, D_, Bl, tid);
    __syncthreads();
    bf16x8 ah0 = ldfrag(Ah, w, 0, fr, kq), ah1 = ldfrag(Ah, w, 1, fr, kq);
    bf16x8 al0 = ldfrag(Al, w, 0, fr, kq), al1 = ldfrag(Al, w, 1, fr, kq);
#pragma unroll
    for (int nb = 0; nb < 4; ++nb) {
      bf16x8 b0 = ldfrag(Bh, nb, 0, fr, kq), b1 = ldfrag(Bh, nb, 1, fr, kq);
      bf16x8 c0 = ldfrag(Bl, nb, 0, fr, kq), c1 = ldfrag(Bl, nb, 1, fr, kq);
      acc[nb] = MFMA_BF16(ah0, b0, acc[nb]); acc[nb] = MFMA_BF16(ah1, b1, acc[nb]);
      acc[nb] = MFMA_BF16(ah0, c0, acc[nb]); acc[nb] = MFMA_BF16(ah1, c1, acc[nb]);
      acc[nb] = MFMA_BF16(al0, b0, acc[nb]); acc[nb] = MFMA_BF16(al1, b1, acc[nb]);
    }
  }
#pragma unroll
  for (int nb = 0; nb < 4; ++nb) {
    int n = nb * 16 + fr;
#pragma unroll
    for (int reg = 0; reg < 4; ++reg) {
      int m = bm + w * 16 + kq * 4 + reg;
      C[(size_t)m * 64 + n] = acc[nb][reg];
    }
  }
}

// ======================= gates: beta, logsigmoid + cumsum =======================
__global__ __launch_bounds__(512) void gate_cumsum(const float* __restrict__ ycat,
                                                   const float* __restrict__ gb,
                                                   float* __restrict__ beta,
                                                   float* __restrict__ G) {
  __shared__ float s[T_];
  int bh = blockIdx.x, b = bh >> 4, h = bh & 15, t = threadIdx.x;
  int bt = b * T_ + t;
  float by = ycat[(size_t)bt * 64 + 32 + h];
  beta[(size_t)bh * T_ + t] = 2.f / (1.f + expf(-by));
  float gy = ycat[(size_t)bt * 64 + 48 + h] + gb[h];
  s[t] = fminf(gy, 0.f) - log1pf(expf(-fabsf(gy)));
  __syncthreads();
  for (int off = 1; off < T_; off <<= 1) {
    float v = (t >= off) ? s[t - off] : 0.f;
    __syncthreads();
    s[t] += v;
    __syncthreads();
  }
  G[(size_t)bh * T_ + t] = s[t];
}

// ======================= w: low-rank expand + conv3 + silu + unit-normalize ===========
__global__ __launch_bounds__(1024) void wdir_k(const float* __restrict__ ycat,
                                               const float* __restrict__ wB,
                                               const float* __restrict__ convw,
                                               float* __restrict__ wT,
                                               __hip_bfloat16* __restrict__ wb16) {
  int bt = blockIdx.x, b = bt / T_, t = bt - b * T_;
  __shared__ float wl[3][R_];
  int tid = threadIdx.x;
  if (tid < 3 * R_) {
    int row = tid / R_, r = tid - row * R_;
    int ts = t - row;
    wl[row][r] = (ts >= 0) ? ycat[(size_t)(b * T_ + ts) * 64 + r] : 0.f;
  }
  __syncthreads();
  float f0 = 0.f, f1 = 0.f, f2 = 0.f;
  for (int r = 0; r < R_; ++r) {
    float wb = wB[(size_t)r * D_ + tid];
    f0 += wl[0][r] * wb; f1 += wl[1][r] * wb; f2 += wl[2][r] * wb;
  }
  float y = f2 * convw[tid * 3 + 0] + f1 * convw[tid * 3 + 1] + f0 * convw[tid * 3 + 2];
  float s = y / (1.f + expf(-y));                       // silu
  float ss = s * s;
#pragma unroll
  for (int m = 32; m >= 1; m >>= 1) ss += __shfl_xor(ss, m);
  float outv = s * rsqrtf(ss + 1e-12f);
  int h = tid >> 6, dd = tid & 63;
  size_t o = (((size_t)(b * H_ + h)) * T_ + t) * DH + dd;
  wT[o] = outv;
  wb16[o] = __float2bfloat16(outv);
}

// ======================= rmsnorm q,k (from unified qk buffer) -> bf16 [B,H,T,dh] ==========
__global__ __launch_bounds__(1024) void rmsT_k(const float* __restrict__ qk,
                                               const float* __restrict__ qnw,
                                               const float* __restrict__ knw,
                                               __hip_bfloat16* __restrict__ qb16,
                                               __hip_bfloat16* __restrict__ kb16) {
  int bt = blockIdx.x, b = bt / T_, t = bt - b * T_;
  int tid = threadIdx.x, h = tid >> 6, dd = tid & 63;
  float qv = qk[(size_t)bt * 2048 + tid];
  float kv = qk[(size_t)bt * 2048 + 1024 + tid];
  float sq = qv * qv, sk = kv * kv;
#pragma unroll
  for (int m = 32; m >= 1; m >>= 1) { sq += __shfl_xor(sq, m); sk += __shfl_xor(sk, m); }
  float qs = qv * rsqrtf(sq * (1.f / DH) + 1e-5f) * qnw[dd];
  float ks = kv * rsqrtf(sk * (1.f / DH) + 1e-5f) * knw[dd];
  size_t o = (((size_t)(b * H_ + h)) * T_ + t) * DH + dd;
  qb16[o] = __float2bfloat16(qs);
  kb16[o] = __float2bfloat16(ks);
}

// ======================= per-block unit-lower-triangular inverse =======================
__global__ __launch_bounds__(256) void linv_k(const float* __restrict__ wT,
                                              const float* __restrict__ beta,
                                              __hip_bfloat16* __restrict__ linv) {
  __shared__ float Wsh[64][68];
  __shared__ float Csh[64][65];
  __shared__ float Li[64][68];
  __shared__ float bI[64];
  const int I = blockIdx.x, bhx = blockIdx.y;
  const int tid = threadIdx.x;
#pragma unroll
  for (int l = 0; l < 4; ++l) {
    int f = tid + l * 256; int r = f >> 4, c = (f & 15) << 2;
    *(float4*)&Wsh[r][c] = *(const float4*)&wT[((size_t)bhx * T_ + I * 64 + r) * DH + c];
  }
  if (tid < 64) bI[tid] = beta[(size_t)bhx * T_ + I * 64 + tid];
#pragma unroll
  for (int l = 0; l < 16; ++l) {
    int e = tid + l * 256; int r = e >> 6, c = e & 63;
    Li[r][c] = (r == c) ? 1.f : 0.f;
  }
  __syncthreads();
  const int tm = (tid >> 4) << 2, tn = (tid & 15) << 2;
  float cc[4][4] = {};
  for (int dd = 0; dd < 64; ++dd) {
    float a0 = Wsh[tm + 0][dd], a1 = Wsh[tm + 1][dd], a2 = Wsh[tm + 2][dd], a3 = Wsh[tm + 3][dd];
    float b0 = Wsh[tn + 0][dd], b1 = Wsh[tn + 1][dd], b2 = Wsh[tn + 2][dd], b3 = Wsh[tn + 3][dd];
    cc[0][0] += a0 * b0; cc[0][1] += a0 * b1; cc[0][2] += a0 * b2; cc[0][3] += a0 * b3;
    cc[1][0] += a1 * b0; cc[1][1] += a1 * b1; cc[1][2] += a1 * b2; cc[1][3] += a1 * b3;
    cc[2][0] += a2 * b0; cc[2][1] += a2 * b1; cc[2][2] += a2 * b2; cc[2][3] += a2 * b3;
    cc[3][0] += a3 * b0; cc[3][1] += a3 * b1; cc[3][2] += a3 * b2; cc[3][3] += a3 * b3;
  }
#pragma unroll
  for (int ii = 0; ii < 4; ++ii)
#pragma unroll
    for (int jj = 0; jj < 4; ++jj)
      Csh[tm + ii][tn + jj] = (tm + ii > tn + jj) ? cc[ii][jj] * bI[tn + jj] : 0.f;
  __syncthreads();
  const int sL = tid & 63, g = tid >> 6;
  for (int r = 0; r < 63; ++r) {
    float lr = Li[r][sL];
    for (int r2 = r + 1 + g; r2 < 64; r2 += 4)
      Li[r2][sL] -= Csh[r2][r] * lr;
    __syncthreads();
  }
#pragma unroll
  for (int l = 0; l < 4; ++l) {
    int f = tid + l * 256; int r = f >> 4, c0 = (f & 15) << 2;
    s16x4 p;
    p.x = bf16s(Li[r][c0 + 0]); p.y = bf16s(Li[r][c0 + 1]);
    p.z = bf16s(Li[r][c0 + 2]); p.w = bf16s(Li[r][c0 + 3]);
    *(s16x4*)&linv[((size_t)(bhx * 8 + I)) * 4096 + r * 64 + c0] = p;
  }
}

// ======================= WY chain: per column-chunk, MFMA recurrence =======================
__global__ __launch_bounds__(256) void chain_k(const __hip_bfloat16* __restrict__ kb,
                                               const __hip_bfloat16* __restrict__ wb,
                                               const __hip_bfloat16* __restrict__ linv,
                                               const float* __restrict__ beta,
                                               __hip_bfloat16* __restrict__ abT) {
  __shared__ __hip_bfloat16 Kb[64][72];   // [j][d]
  __shared__ __hip_bfloat16 Ws[64][72];   // [t][d]
  __shared__ __hip_bfloat16 WsT[64][72];  // [d][t]
  __shared__ __hip_bfloat16 Ls[64][72];   // [t][s]
  __shared__ __hip_bfloat16 Mhi[64][72];  // [j][d] = -M hi
  __shared__ __hip_bfloat16 Mlo[64][72];  // [j][d] = -M lo
  __shared__ __hip_bfloat16 Ps[64][72];   // [j][t] PT, then reused as X
  __shared__ float bI[64];
  const int ch = blockIdx.x, bhx = blockIdx.y;
  const int tid = threadIdx.x, w = tid >> 6, lane = tid & 63;
  const int fr = lane & 15, kq = lane >> 4;
  const size_t hb = (size_t)bhx * T_;
  const f32x4 zf = {0.f, 0.f, 0.f, 0.f};

  stage64(kb + (hb + ch * 64) * DH, DH, Kb, tid);
  for (int f = tid; f < 576; f += 256) {
    ((int4*)Mhi)[f] = make_int4(0, 0, 0, 0);
    ((int4*)Mlo)[f] = make_int4(0, 0, 0, 0);
  }
  f32x4 macc[4] = {zf, zf, zf, zf};

  for (int I = ch; I < 8; ++I) {
    __syncthreads();                                           // B1
    stage64(wb + (hb + I * 64) * DH, DH, Ws, tid);
    stage64(linv + ((size_t)(bhx * 8 + I)) * 4096, 64, Ls, tid);
    if (tid < 64) bI[tid] = beta[hb + I * 64 + tid];
    const int jr = w * 16 + kq * 4;
    if (I > ch) {
#pragma unroll
      for (int nb = 0; nb < 4; ++nb) {
        int d = nb * 16 + fr;
#pragma unroll
        for (int reg = 0; reg < 4; ++reg) {
          float m = -macc[nb][reg];
          __hip_bfloat16 h = __float2bfloat16(m);
          Mhi[jr + reg][d] = h;
          Mlo[jr + reg][d] = __float2bfloat16(m - __bfloat162float(h));
        }
      }
    }
    __syncthreads();                                           // B2
#pragma unroll
    for (int l = 0; l < 16; ++l) {
      int e = tid + l * 256;
      int t = e >> 6, d = e & 63;
      WsT[d][t] = Ws[t][d];
    }
    bf16x8 kb0 = ldfrag(Kb, w, 0, fr, kq), kb1 = ldfrag(Kb, w, 1, fr, kq);
    f32x4 pt[4];
#pragma unroll
    for (int nb = 0; nb < 4; ++nb) {
      bf16x8 b0 = ldfrag(Ws, nb, 0, fr, kq), b1 = ldfrag(Ws, nb, 1, fr, kq);
      pt[nb] = MFMA_BF16(kb0, b0, zf);
      pt[nb] = MFMA_BF16(kb1, b1, pt[nb]);
      if (I > ch) {
        bf16x8 mh0 = ldfrag(Mhi, w, 0, fr, kq), mh1 = ldfrag(Mhi, w, 1, fr, kq);
        bf16x8 ml0 = ldfrag(Mlo, w, 0, fr, kq), ml1 = ldfrag(Mlo, w, 1, fr, kq);
        pt[nb] = MFMA_BF16(mh0, b0, pt[nb]); pt[nb] = MFMA_BF16(mh1, b1, pt[nb]);
        pt[nb] = MFMA_BF16(ml0, b0, pt[nb]); pt[nb] = MFMA_BF16(ml1, b1, pt[nb]);
      }
    }
#pragma unroll
    for (int nb = 0; nb < 4; ++nb) {
      int t = nb * 16 + fr;
#pragma unroll
      for (int reg = 0; reg < 4; ++reg) {
        float v = pt[nb][reg];
        if (I == ch && t <= jr + reg) v = 0.f;
        Ps[jr + reg][t] = __float2bfloat16(v);
      }
    }
    __syncthreads();                                           // B3
    bf16x8 la0 = ldfrag(Ls, w, 0, fr, kq), la1 = ldfrag(Ls, w, 1, fr, kq);
    f32x4 av[4];
#pragma unroll
    for (int nb = 0; nb < 4; ++nb) {
      bf16x8 p0 = ldfrag(Ps, nb, 0, fr, kq), p1 = ldfrag(Ps, nb, 1, fr, kq);
      av[nb] = MFMA_BF16(la0, p0, zf);
      av[nb] = MFMA_BF16(la1, p1, av[nb]);
    }
    __syncthreads();                                           // B4
    const int tr = w * 16 + kq * 4;
#pragma unroll
    for (int nb = 0; nb < 4; ++nb) {
      s16x4 p;
      p.x = bf16s(bI[tr + 0] * av[nb][0]);
      p.y = bf16s(bI[tr + 1] * av[nb][1]);
      p.z = bf16s(bI[tr + 2] * av[nb][2]);
      p.w = bf16s(bI[tr + 3] * av[nb][3]);
      *(s16x4*)&Ps[nb * 16 + fr][tr] = p;
    }
    __syncthreads();                                           // B5
#pragma unroll
    for (int l = 0; l < 2; ++l) {
      int f = tid + l * 256;
      int r = f >> 3, c = (f & 7) << 3;
      *(int4*)&abT[(hb + ch * 64 + r) * T_ + I * 64 + c] = *(const int4*)&Ps[r][c];
    }
    bf16x8 xa0 = ldfrag(Ps, w, 0, fr, kq), xa1 = ldfrag(Ps, w, 1, fr, kq);
#pragma unroll
    for (int nb = 0; nb < 4; ++nb) {
      bf16x8 wt0 = ldfrag(WsT, nb, 0, fr, kq), wt1 = ldfrag(WsT, nb, 1, fr, kq);
      macc[nb] = MFMA_BF16(xa0, wt0, macc[nb]);
      macc[nb] = MFMA_BF16(xa1, wt1, macc[nb]);
    }
  }
}

// ======================= S via MFMA: S = Q K^T - tril(Q W^T) @ (beta A) =======================
__global__ __launch_bounds__(256) void s_mfma(const __hip_bfloat16* __restrict__ qb,
                                              const __hip_bfloat16* __restrict__ kb,
                                              const __hip_bfloat16* __restrict__ wb,
                                              const __hip_bfloat16* __restrict__ abT,
                                              float* __restrict__ S) {
  __shared__ __hip_bfloat16 Qs[64][72];
  __shared__ __hip_bfloat16 Bs[64][72];
  __shared__ __hip_bfloat16 Cs[64][72];
  __shared__ __hip_bfloat16 Ms[64][72];
  int ti = blockIdx.x;
  int it = 0, accum = 0;
  while (accum + it + 1 <= ti) { accum += it + 1; ++it; }
  const int jt = ti - accum;
  const int bh = blockIdx.y;
  const int tid = threadIdx.x, w = tid >> 6, lane = tid & 63;
  const int fr = lane & 15, kq = lane >> 4;
  const size_t hb = (size_t)bh * T_;

  stage64(qb + (hb + it * 64) * DH, DH, Qs, tid);
  stage64(kb + (hb + jt * 64) * DH, DH, Bs, tid);
  __syncthreads();

  const bf16x8 a0 = ldfrag(Qs, w, 0, fr, kq);
  const bf16x8 a1 = ldfrag(Qs, w, 1, fr, kq);

  f32x4 acc[4];
  const f32x4 zero = {0.f, 0.f, 0.f, 0.f};
#pragma unroll
  for (int nb = 0; nb < 4; ++nb) {
    acc[nb] = MFMA_BF16(a0, ldfrag(Bs, nb, 0, fr, kq), zero);
    acc[nb] = MFMA_BF16(a1, ldfrag(Bs, nb, 1, fr, kq), acc[nb]);
  }

  for (int c = jt; c <= it; ++c) {
    __syncthreads();
    stage64(wb + (hb + c * 64) * DH, DH, Bs, tid);
    stage64(abT + (hb + jt * 64) * T_ + c * 64, T_, Cs, tid);
    __syncthreads();
    f32x4 qw[4];
#pragma unroll
    for (int nb = 0; nb < 4; ++nb) {
      qw[nb] = MFMA_BF16(a0, ldfrag(Bs, nb, 0, fr, kq), zero);
      qw[nb] = MFMA_BF16(a1, ldfrag(Bs, nb, 1, fr, kq), qw[nb]);
    }
    const int row0 = w * 16 + kq * 4;
    const bool diag = (c == it);
#pragma unroll
    for (int nb = 0; nb < 4; ++nb) {
      int col = nb * 16 + fr;
#pragma unroll
      for (int reg = 0; reg < 4; ++reg) {
        float v = -qw[nb][reg];
        if (diag && col > row0 + reg) v = 0.f;
        Ms[row0 + reg][col] = __float2bfloat16(v);
      }
    }
    __syncthreads();
    const bf16x8 m0 = ldfrag(Ms, w, 0, fr, kq);
    const bf16x8 m1 = ldfrag(Ms, w, 1, fr, kq);
#pragma unroll
    for (int nb = 0; nb < 4; ++nb) {
      acc[nb] = MFMA_BF16(m0, ldfrag(Cs, nb, 0, fr, kq), acc[nb]);
      acc[nb] = MFMA_BF16(m1, ldfrag(Cs, nb, 1, fr, kq), acc[nb]);
    }
  }
#pragma unroll
  for (int nb = 0; nb < 4; ++nb) {
    int j = jt * 64 + nb * 16 + fr;
#pragma unroll
    for (int reg = 0; reg < 4; ++reg) {
      S[(hb + it * 64 + w * 16 + kq * 4 + reg) * T_ + j] = acc[nb][reg];
    }
  }
}

// ======================= softmax, causal, P written bf16 in place =======================
__global__ __launch_bounds__(64) void softmax_k(float* __restrict__ S, const float* __restrict__ G) {
  int i = blockIdx.x, bh = blockIdx.y;
  int lane = threadIdx.x;
  const float Gi = G[(size_t)bh * T_ + i];
  float* row = S + ((size_t)bh * T_ + i) * T_;
  const float* Gb = G + (size_t)bh * T_;
  float l[8];
  float m = -3e38f;
#pragma unroll
  for (int c = 0; c < 8; ++c) {
    int j = lane + c * 64;
    if (j <= i) { float v = row[j] * 0.125f + Gi - Gb[j]; l[c] = v; m = fmaxf(m, v); }
    else l[c] = -3e38f;
  }
#pragma unroll
  for (int mm = 32; mm >= 1; mm >>= 1) m = fmaxf(m, __shfl_xor(m, mm));
  float ssum = 0.f;
#pragma unroll
  for (int c = 0; c < 8; ++c) {
    int j = lane + c * 64;
    float p = (j <= i) ? expf(l[c] - m) : 0.f;
    l[c] = p; ssum += p;
  }
#pragma unroll
  for (int mm = 32; mm >= 1; mm >>= 1) ssum += __shfl_xor(ssum, mm);
  float inv = 1.f / ssum;
  __hip_bfloat16* prow = (__hip_bfloat16*)row;
#pragma unroll
  for (int c = 0; c < 8; ++c) prow[lane + c * 64] = __float2bfloat16(l[c] * inv);
}

// ======================= o = P @ V via MFMA (P bf16, V hi/lo bf16 transposed) ==========
__global__ __launch_bounds__(256) void pv_mfma(const __hip_bfloat16* __restrict__ pb,  // ld 2*T_
                                               const __hip_bfloat16* __restrict__ vhi, // [BH,dh,T]
                                               const __hip_bfloat16* __restrict__ vlo,
                                               __hip_bfloat16* __restrict__ ohi,
                                               __hip_bfloat16* __restrict__ olo) {
  __shared__ __hip_bfloat16 Ps[64][72];   // [i][t]
  __shared__ __hip_bfloat16 Vh[64][72];   // [dd][t]
  __shared__ __hip_bfloat16 Vl[64][72];   // [dd][t]
  const int it = blockIdx.x, bh = blockIdx.y;
  const int b = bh >> 4, h = bh & 15;
  const int tid = threadIdx.x, w = tid >> 6, lane = tid & 63;
  const int fr = lane & 15, kq = lane >> 4;
  const f32x4 zf = {0.f, 0.f, 0.f, 0.f};
  f32x4 acc[4] = {zf, zf, zf, zf};
  for (int c = 0; c <= it; ++c) {
    __syncthreads();
    stage64(pb + ((size_t)bh * T_ + it * 64) * (2 * T_) + c * 64, 2 * T_, Ps, tid);
    stage64(vhi + ((size_t)bh * DH) * T_ + c * 64, T_, Vh, tid);
    stage64(vlo + ((size_t)bh * DH) * T_ + c * 64, T_, Vl, tid);
    __syncthreads();
    bf16x8 p0 = ldfrag(Ps, w, 0, fr, kq), p1 = ldfrag(Ps, w, 1, fr, kq);
#pragma unroll
    for (int nb = 0; nb < 4; ++nb) {
      acc[nb] = MFMA_BF16(p0, ldfrag(Vh, nb, 0, fr, kq), acc[nb]);
      acc[nb] = MFMA_BF16(p1, ldfrag(Vh, nb, 1, fr, kq), acc[nb]);
      acc[nb] = MFMA_BF16(p0, ldfrag(Vl, nb, 0, fr, kq), acc[nb]);
      acc[nb] = MFMA_BF16(p1, ldfrag(Vl, nb, 1, fr, kq), acc[nb]);
    }
  }
#pragma unroll
  for (int nb = 0; nb < 4; ++nb) {
    int dd = nb * 16 + fr;
#pragma unroll
    for (int reg = 0; reg < 4; ++reg) {
      int i = it * 64 + w * 16 + kq * 4 + reg;
      size_t oi = ((size_t)(b * T_ + i)) * D_ + h * 64 + dd;
      float v = acc[nb][reg];
      __hip_bfloat16 hv = __float2bfloat16(v);
      ohi[oi] = hv;
      olo[oi] = __float2bfloat16(v - __bfloat162float(hv));
    }
  }
}

// ======================= launch =======================
extern "C" void kernel_launch(void* const* d_in, const int* in_sizes, int n_in,
                              void* d_out, int out_size, void* d_ws, size_t ws_size,
                              hipStream_t stream) {
  (void)in_sizes; (void)n_in; (void)out_size; (void)ws_size;
  const float* x     = (const float*)d_in[0];
  const float* Wq    = (const float*)d_in[1];
  const float* Wk    = (const float*)d_in[2];
  const float* Wv    = (const float*)d_in[3];
  const float* Wo    = (const float*)d_in[4];
  const float* wA    = (const float*)d_in[5];
  const float* wB    = (const float*)d_in[6];
  const float* convw = (const float*)d_in[7];
  const float* bw    = (const float*)d_in[8];
  const float* gw    = (const float*)d_in[9];
  const float* gb    = (const float*)d_in[10];
  const float* qnw   = (const float*)d_in[11];
  const float* knw   = (const float*)d_in[12];

  const size_t N1 = (size_t)BT_ * D_;          // 1,048,576
  const size_t NTT = (size_t)BH_ * T_ * T_;    // 8,388,608
  float* ws = (float*)d_ws;
  float* qk   = ws;                        // [BT][2048] fp32 (q | k)
  float* wTb  = qk + (size_t)BT_ * 2048;   // [BH,T,dh] fp32
  float* ycat = wTb + N1;                  // [BT,64] fp32
  float* S    = ycat + (size_t)BT_ * 64;   // [BH,T,T] fp32 (P bf16 aliases rows)
  float* beta = S + NTT;
  float* G    = beta + (size_t)BH_ * T_;
  __hip_bfloat16* qb16  = (__hip_bfloat16*)(G + (size_t)BH_ * T_);
  __hip_bfloat16* kb16  = qb16 + N1;
  __hip_bfloat16* wb16  = kb16 + N1;
  __hip_bfloat16* abT   = wb16 + N1;            // [BH,T(j),T(t)] bf16
  __hip_bfloat16* linvb = abT + NTT;            // [BH,8,64,64] bf16
  __hip_bfloat16* xhi   = linvb + (size_t)BH_ * 8 * 4096;
  __hip_bfloat16* xlo   = xhi + N1;
  __hip_bfloat16* obhi  = xlo + N1;
  __hip_bfloat16* oblo  = obhi + N1;
  __hip_bfloat16* woThi = oblo + N1;
  __hip_bfloat16* woTlo = woThi + N1;
  __hip_bfloat16* vhi   = woTlo + N1;           // [BH,dh,T] bf16
  __hip_bfloat16* vlo   = vhi + N1;
  __hip_bfloat16* wcThi = vlo + N1;             // [64][D]
  __hip_bfloat16* wcTlo = wcThi + (size_t)64 * D_;
  // fused QKV weight [3072][1024] hi/lo aliases S (S written later in stream order)
  __hip_bfloat16* wqkvThi = (__hip_bfloat16*)S;
  __hip_bfloat16* wqkvTlo = wqkvThi + (size_t)3072 * D_;

  dim3 g16(16, 16);
  split_f32<<<1024, 256, 0, stream>>>(x, xhi, xlo);
  splitT_k<<<g16, 256, 0, stream>>>(Wq, wqkvThi, wqkvTlo);
  splitT_k<<<g16, 256, 0, stream>>>(Wk, wqkvThi + (size_t)1024 * D_, wqkvTlo + (size_t)1024 * D_);
  splitT_k<<<g16, 256, 0, stream>>>(Wv, wqkvThi + (size_t)2048 * D_, wqkvTlo + (size_t)2048 * D_);
  splitT_k<<<g16, 256, 0, stream>>>(Wo, woThi, woTlo);
  splitcat_k<<<64, 256, 0, stream>>>(wA, bw, gw, wcThi, wcTlo);
  // fused Q|K|V projection: M=1024, N=3072, virtual K=3072; BM=128 BN=64 -> 384 blocks
  gemm128<0, 128, 64><<<dim3(48, 8), 256, 0, stream>>>(xhi, xlo, wqkvThi, wqkvTlo, qk, vhi, vlo);
  gemm_ycat<<<dim3(1, 16), 256, 0, stream>>>(xhi, xlo, wcThi, wcTlo, ycat);
  gate_cumsum<<<BH_, 512, 0, stream>>>(ycat, gb, beta, G);
  wdir_k<<<BT_, 1024, 0, stream>>>(ycat, wB, convw, wTb, wb16);
  rmsT_k<<<BT_, 1024, 0, stream>>>(qk, qnw, knw, qb16, kb16);
  linv_k<<<dim3(8, BH_), 256, 0, stream>>>(wTb, beta, linvb);
  chain_k<<<dim3(8, BH_), 256, 0, stream>>>(kb16, wb16, linvb, beta, abT);
  s_mfma<<<dim3(36, BH_), 256, 0, stream>>>(qb16, kb16, wb16, abT, S);
  softmax_k<<<dim3(T_, BH_), 64, 0, stream>>>(S, G);
  pv_mfma<<<dim3(8, BH_), 256, 0, stream>>>((const __hip_bfloat16*)S, vhi, vlo, obhi, oblo);
  // output projection: M=1024, N=1024, virtual K=3072; 64x64 tiles -> 256 blocks
  gemm128<1, 64, 64><<<dim3(16, 16), 256, 0, stream>>>(obhi, oblo, woThi, woTlo, (float*)d_out, nullptr, nullptr);
}

// Round 7
// 203.249 us; speedup vs baseline: 1.5162x; 1.2108x over previous
//
#include <hip/hip_runtime.h>
#include <hip/hip_bf16.h>
#include <math.h>

#define B_ 2
#define T_ 512
#define D_ 1024
#define H_ 16
#define R_ 32
#define DH 64
#define BT_ (B_*T_)
#define BH_ (B_*H_)

typedef __attribute__((ext_vector_type(8))) short bf16x8;
typedef __attribute__((ext_vector_type(4))) short s16x4;
typedef __attribute__((ext_vector_type(4))) float f32x4;

#define MFMA_BF16(a, b, c) __builtin_amdgcn_mfma_f32_16x16x32_bf16(a, b, c, 0, 0, 0)

static __device__ __forceinline__ short bf16s(float v) {
  __hip_bfloat16 b = __float2bfloat16(v);
  return *reinterpret_cast<short*>(&b);
}

// ---- shared MFMA helpers (layout verified in R2; [72] pad = 144B stride, conflict-free) ----
__device__ __forceinline__ bf16x8 ldfrag(const __hip_bfloat16 s[][72], int b16, int kb, int fr, int kq) {
  return *(const bf16x8*)&s[b16 * 16 + fr][kb * 32 + kq * 8];
}
__device__ __forceinline__ void stage64(const __hip_bfloat16* __restrict__ g, int ldg,
                                        __hip_bfloat16 s[][72], int tid) {
#pragma unroll
  for (int l = 0; l < 2; ++l) {
    int f = tid + l * 256;
    int r = f >> 3, c = (f & 7) << 3;
    *(int4*)&s[r][c] = *(const int4*)&g[(size_t)r * ldg + c];
  }
}

// ---- global_load_lds 16B direct-to-LDS ----
typedef const __attribute__((address_space(1))) void* as1cv;
typedef __attribute__((address_space(3))) void* as3v;
__device__ __forceinline__ void gl16(const __hip_bfloat16* g, __hip_bfloat16* l) {
  __builtin_amdgcn_global_load_lds((as1cv)g, (as3v)l, 16, 0, 0);
}

// ======================= split fp32 -> bf16 hi/lo =======================
__global__ __launch_bounds__(256) void split_f32(const float* __restrict__ in,
                                                 __hip_bfloat16* __restrict__ hi,
                                                 __hip_bfloat16* __restrict__ lo) {
  int i4 = blockIdx.x * 256 + threadIdx.x;
  float4 v = ((const float4*)in)[i4];
  s16x4 ph, pl;
  float c[4] = {v.x, v.y, v.z, v.w};
#pragma unroll
  for (int u = 0; u < 4; ++u) {
    __hip_bfloat16 h = __float2bfloat16(c[u]);
    ph[u] = *reinterpret_cast<short*>(&h);
    pl[u] = bf16s(c[u] - __bfloat162float(h));
  }
  ((s16x4*)hi)[i4] = ph;
  ((s16x4*)lo)[i4] = pl;
}

// ======================= transpose + split weights: W[K][N] -> WT hi/lo [N][K] ============
__global__ __launch_bounds__(256) void splitT_k(const float* __restrict__ Wm,
                                                __hip_bfloat16* __restrict__ thi,
                                                __hip_bfloat16* __restrict__ tlo) {
  __shared__ float tile[64][65];
  const int bn = blockIdx.x * 64, bk = blockIdx.y * 64;
  const int tid = threadIdx.x;
#pragma unroll
  for (int l = 0; l < 4; ++l) {
    int f = tid + l * 256; int r = f >> 4, c = (f & 15) << 2;
    *(float4*)&tile[r][c] = *(const float4*)&Wm[(size_t)(bk + r) * D_ + bn + c];
  }
  __syncthreads();
#pragma unroll
  for (int l = 0; l < 4; ++l) {
    int f = tid + l * 256; int n = f >> 4, k0 = (f & 15) << 2;
    s16x4 ph, pl;
#pragma unroll
    for (int u = 0; u < 4; ++u) {
      float v = tile[k0 + u][n];
      __hip_bfloat16 h = __float2bfloat16(v);
      ph[u] = *reinterpret_cast<short*>(&h);
      pl[u] = bf16s(v - __bfloat162float(h));
    }
    *(s16x4*)&thi[(size_t)(bn + n) * D_ + bk + k0] = ph;
    *(s16x4*)&tlo[(size_t)(bn + n) * D_ + bk + k0] = pl;
  }
}

// ======================= concat+transpose+split small proj weights [wA|bw|gw] -> [64][D] ==
__global__ __launch_bounds__(256) void splitcat_k(const float* __restrict__ wA,
                                                  const float* __restrict__ bw,
                                                  const float* __restrict__ gw,
                                                  __hip_bfloat16* __restrict__ thi,
                                                  __hip_bfloat16* __restrict__ tlo) {
  int n = blockIdx.x;          // 0..63
  int tid = threadIdx.x;
  for (int k = tid; k < D_; k += 256) {
    float v;
    if (n < 32) v = wA[(size_t)k * R_ + n];
    else if (n < 48) v = bw[(size_t)k * H_ + (n - 32)];
    else v = gw[(size_t)k * H_ + (n - 48)];
    __hip_bfloat16 h = __float2bfloat16(v);
    thi[(size_t)n * D_ + k] = h;
    tlo[(size_t)n * D_ + k] = __float2bfloat16(v - __bfloat162float(h));
  }
}

// ======================= 64x64-tile GEMM, 4 waves (wave tile 16x64), K=1024 ============
// single-buffer LDS (16KB) + swizzle; many-block grids give cross-block latency overlap.
// MODE 0: qk projection (1-pass bf16) with fused rmsnorm epilogue -> qb16/kb16.
// MODE 1: z-pass partial GEMM: z=0 ah*bh, z=1 al*bh, z=2 ah*bl -> C + z*1M fp32.
template<int MODE>
__global__ __launch_bounds__(256) void gemm_t(const __hip_bfloat16* __restrict__ ah,
                                              const __hip_bfloat16* __restrict__ al,
                                              const __hip_bfloat16* __restrict__ bh,
                                              const __hip_bfloat16* __restrict__ bl,
                                              float* __restrict__ Cbase,
                                              __hip_bfloat16* __restrict__ qb,
                                              __hip_bfloat16* __restrict__ kb,
                                              const float* __restrict__ qnw,
                                              const float* __restrict__ knw) {
  __shared__ __hip_bfloat16 As[64][64];
  __shared__ __hip_bfloat16 Bs[64][64];
  const int bm = blockIdx.y * 64, bn = blockIdx.x * 64;
  const int tid = threadIdx.x, w = tid >> 6, lane = tid & 63;
  const int fr = lane & 15, kq = lane >> 4;
  const __hip_bfloat16* a = ah;
  const __hip_bfloat16* b = bh;
  float* C = Cbase;
  if (MODE == 1) {
    int z = blockIdx.z;
    a = (z == 1) ? al : ah;
    b = (z == 2) ? bl : bh;
    C = Cbase + (size_t)z * (1u << 20);
  }
  const f32x4 zf = {0.f, 0.f, 0.f, 0.f};
  f32x4 acc[4] = {zf, zf, zf, zf};
  const __hip_bfloat16* ap = a + (size_t)bm * D_;
  const __hip_bfloat16* bp = b + (size_t)bn * D_;

  for (int t = 0; t < 16; ++t) {
    __syncthreads();                 // previous iter's reads done
#pragma unroll
    for (int i = 0; i < 2; ++i) {
      int chunk = tid + i * 256;
      int row = chunk >> 3, c8 = (chunk & 7) ^ (row & 7);    // source pre-swizzle
      gl16(ap + (size_t)row * D_ + t * 64 + c8 * 8, &As[0][0] + chunk * 8);
      gl16(bp + (size_t)row * D_ + t * 64 + c8 * 8, &Bs[0][0] + chunk * 8);
    }
    __syncthreads();                 // stage complete (vmcnt drained by barrier)
    const int ra = w * 16 + fr, sa = ra & 7;
    bf16x8 a0 = *(const bf16x8*)&As[ra][(kq ^ sa) * 8];
    bf16x8 a1 = *(const bf16x8*)&As[ra][((kq + 4) ^ sa) * 8];
#pragma unroll
    for (int n = 0; n < 4; ++n) {
      int rb = n * 16 + fr, sb = rb & 7;
      bf16x8 b0 = *(const bf16x8*)&Bs[rb][(kq ^ sb) * 8];
      bf16x8 b1 = *(const bf16x8*)&Bs[rb][((kq + 4) ^ sb) * 8];
      acc[n] = MFMA_BF16(a0, b0, acc[n]);
      acc[n] = MFMA_BF16(a1, b1, acc[n]);
    }
  }

  if (MODE == 0) {
    // fused rmsnorm: block owns 64 cols = one head's d; rows in-wave.
    float rs[4];
#pragma unroll
    for (int reg = 0; reg < 4; ++reg) {
      float s = 0.f;
#pragma unroll
      for (int n = 0; n < 4; ++n) s += acc[n][reg] * acc[n][reg];
#pragma unroll
      for (int mm = 1; mm <= 8; mm <<= 1) s += __shfl_xor(s, mm);
      rs[reg] = rsqrtf(s * (1.f / DH) + 1e-5f);
    }
    const bool isq = (bn < 1024);
    __hip_bfloat16* outp = isq ? qb : kb;
#pragma unroll
    for (int n = 0; n < 4; ++n) {
      int gn = bn + n * 16 + fr;
      int dd = gn & 63, h = (gn & 1023) >> 6;
      float nw = (isq ? qnw : knw)[dd];
#pragma unroll
      for (int reg = 0; reg < 4; ++reg) {
        int gm = bm + w * 16 + kq * 4 + reg;
        int bb = gm >> 9, tt = gm & 511;
        outp[(((size_t)(bb * H_ + h)) * T_ + tt) * DH + dd] =
            __float2bfloat16(acc[n][reg] * rs[reg] * nw);
      }
    }
  } else {
#pragma unroll
    for (int n = 0; n < 4; ++n) {
      int gn = bn + n * 16 + fr;
#pragma unroll
      for (int reg = 0; reg < 4; ++reg) {
        int gm = bm + w * 16 + kq * 4 + reg;
        C[(size_t)gm * D_ + gn] = acc[n][reg];
      }
    }
  }
}

// ======================= combine 3 V partials -> transposed hi/lo bf16 [BH,dh,T] ==========
__global__ __launch_bounds__(256) void combine_v(const float* __restrict__ p,
                                                 __hip_bfloat16* __restrict__ vhi,
                                                 __hip_bfloat16* __restrict__ vlo) {
  __shared__ float Ls[64][65];          // [n][m]
  const int n0 = blockIdx.x * 64, m0 = blockIdx.y * 64;
  const int tid = threadIdx.x;
#pragma unroll
  for (int l = 0; l < 4; ++l) {
    int f = tid + l * 256; int r = f >> 4, c = (f & 15) << 2;
    const float* pp = &p[(size_t)(m0 + r) * D_ + n0 + c];
    float4 v0 = *(const float4*)pp;
    float4 v1 = *(const float4*)(pp + (1u << 20));
    float4 v2 = *(const float4*)(pp + (2u << 20));
    Ls[c + 0][r] = v0.x + v1.x + v2.x;
    Ls[c + 1][r] = v0.y + v1.y + v2.y;
    Ls[c + 2][r] = v0.z + v1.z + v2.z;
    Ls[c + 3][r] = v0.w + v1.w + v2.w;
  }
  __syncthreads();
  const int bb = m0 >> 9, t0 = m0 & 511, h = n0 >> 6;
  const size_t base = (((size_t)(bb * H_ + h)) * DH) * T_ + t0;
#pragma unroll
  for (int l = 0; l < 2; ++l) {
    int f = tid + l * 256;
    int dd = f >> 3, tq = (f & 7) * 8;
    bf16x8 ph, pl;
#pragma unroll
    for (int u = 0; u < 8; ++u) {
      float v = Ls[dd][tq + u];
      __hip_bfloat16 hv = __float2bfloat16(v);
      ph[u] = *reinterpret_cast<short*>(&hv);
      pl[u] = bf16s(v - __bfloat162float(hv));
    }
    *(bf16x8*)&vhi[base + (size_t)dd * T_ + tq] = ph;
    *(bf16x8*)&vlo[base + (size_t)dd * T_ + tq] = pl;
  }
}

// ======================= combine 3 O partials -> d_out fp32 =======================
__global__ __launch_bounds__(256) void combine_o(const float* __restrict__ p,
                                                 float* __restrict__ out) {
  int i4 = blockIdx.x * 256 + threadIdx.x;
  const float4* p4 = (const float4*)p;
  float4 a = p4[i4], b = p4[i4 + (1u << 18)], c = p4[i4 + (2u << 18)];
  float4 r;
  r.x = a.x + b.x + c.x; r.y = a.y + b.y + c.y;
  r.z = a.z + b.z + c.z; r.w = a.w + b.w + c.w;
  ((float4*)out)[i4] = r;
}

// ======================= small GEMM for ycat (M=BT, N=64) via 3x bf16 MFMA ============
__global__ __launch_bounds__(256) void gemm_ycat(const __hip_bfloat16* __restrict__ ah,
                                                 const __hip_bfloat16* __restrict__ al,
                                                 const __hip_bfloat16* __restrict__ bh,
                                                 const __hip_bfloat16* __restrict__ bl,
                                                 float* __restrict__ C) {
  __shared__ __hip_bfloat16 Ah[64][72], Al[64][72], Bh[64][72], Bl[64][72];
  const int bm = blockIdx.y * 64;
  const int tid = threadIdx.x, w = tid >> 6, lane = tid & 63;
  const int fr = lane & 15, kq = lane >> 4;
  const f32x4 zf = {0.f, 0.f, 0.f, 0.f};
  f32x4 acc[4] = {zf, zf, zf, zf};
  for (int k0 = 0; k0 < D_; k0 += 64) {
    __syncthreads();
    stage64(ah + (size_t)bm * D_ + k0, D_, Ah, tid);
    stage64(al + (size_t)bm * D_ + k0, D_, Al, tid);
    stage64(bh + k0, D_, Bh, tid);
    stage64(bl + k0, D_, Bl, tid);
    __syncthreads();
    bf16x8 ah0 = ldfrag(Ah, w, 0, fr, kq), ah1 = ldfrag(Ah, w, 1, fr, kq);
    bf16x8 al0 = ldfrag(Al, w, 0, fr, kq), al1 = ldfrag(Al, w, 1, fr, kq);
#pragma unroll
    for (int nb = 0; nb < 4; ++nb) {
      bf16x8 b0 = ldfrag(Bh, nb, 0, fr, kq), b1 = ldfrag(Bh, nb, 1, fr, kq);
      bf16x8 c0 = ldfrag(Bl, nb, 0, fr, kq), c1 = ldfrag(Bl, nb, 1, fr, kq);
      acc[nb] = MFMA_BF16(ah0, b0, acc[nb]); acc[nb] = MFMA_BF16(ah1, b1, acc[nb]);
      acc[nb] = MFMA_BF16(ah0, c0, acc[nb]); acc[nb] = MFMA_BF16(ah1, c1, acc[nb]);
      acc[nb] = MFMA_BF16(al0, b0, acc[nb]); acc[nb] = MFMA_BF16(al1, b1, acc[nb]);
    }
  }
#pragma unroll
  for (int nb = 0; nb < 4; ++nb) {
    int n = nb * 16 + fr;
#pragma unroll
    for (int reg = 0; reg < 4; ++reg) {
      int m = bm + w * 16 + kq * 4 + reg;
      C[(size_t)m * 64 + n] = acc[nb][reg];
    }
  }
}

// ======================= gates: beta, logsigmoid + cumsum =======================
__global__ __launch_bounds__(512) void gate_cumsum(const float* __restrict__ ycat,
                                                   const float* __restrict__ gb,
                                                   float* __restrict__ beta,
                                                   float* __restrict__ G) {
  __shared__ float s[T_];
  int bh = blockIdx.x, b = bh >> 4, h = bh & 15, t = threadIdx.x;
  int bt = b * T_ + t;
  float by = ycat[(size_t)bt * 64 + 32 + h];
  beta[(size_t)bh * T_ + t] = 2.f / (1.f + expf(-by));
  float gy = ycat[(size_t)bt * 64 + 48 + h] + gb[h];
  s[t] = fminf(gy, 0.f) - log1pf(expf(-fabsf(gy)));
  __syncthreads();
  for (int off = 1; off < T_; off <<= 1) {
    float v = (t >= off) ? s[t - off] : 0.f;
    __syncthreads();
    s[t] += v;
    __syncthreads();
  }
  G[(size_t)bh * T_ + t] = s[t];
}

// ======================= w: low-rank expand + conv3 + silu + unit-normalize ===========
__global__ __launch_bounds__(1024) void wdir_k(const float* __restrict__ ycat,
                                               const float* __restrict__ wB,
                                               const float* __restrict__ convw,
                                               float* __restrict__ wT,
                                               __hip_bfloat16* __restrict__ wb16) {
  int bt = blockIdx.x, b = bt / T_, t = bt - b * T_;
  __shared__ float wl[3][R_];
  int tid = threadIdx.x;
  if (tid < 3 * R_) {
    int row = tid / R_, r = tid - row * R_;
    int ts = t - row;
    wl[row][r] = (ts >= 0) ? ycat[(size_t)(b * T_ + ts) * 64 + r] : 0.f;
  }
  __syncthreads();
  float f0 = 0.f, f1 = 0.f, f2 = 0.f;
  for (int r = 0; r < R_; ++r) {
    float wb = wB[(size_t)r * D_ + tid];
    f0 += wl[0][r] * wb; f1 += wl[1][r] * wb; f2 += wl[2][r] * wb;
  }
  float y = f2 * convw[tid * 3 + 0] + f1 * convw[tid * 3 + 1] + f0 * convw[tid * 3 + 2];
  float s = y / (1.f + expf(-y));                       // silu
  float ss = s * s;
#pragma unroll
  for (int m = 32; m >= 1; m >>= 1) ss += __shfl_xor(ss, m);
  float outv = s * rsqrtf(ss + 1e-12f);
  int h = tid >> 6, dd = tid & 63;
  size_t o = (((size_t)(b * H_ + h)) * T_ + t) * DH + dd;
  wT[o] = outv;
  wb16[o] = __float2bfloat16(outv);
}

// ======================= per-block unit-lower-triangular inverse =======================
__global__ __launch_bounds__(256) void linv_k(const float* __restrict__ wT,
                                              const float* __restrict__ beta,
                                              __hip_bfloat16* __restrict__ linv) {
  __shared__ float Wsh[64][68];
  __shared__ float Csh[64][65];
  __shared__ float Li[64][68];
  __shared__ float bI[64];
  const int I = blockIdx.x, bhx = blockIdx.y;
  const int tid = threadIdx.x;
#pragma unroll
  for (int l = 0; l < 4; ++l) {
    int f = tid + l * 256; int r = f >> 4, c = (f & 15) << 2;
    *(float4*)&Wsh[r][c] = *(const float4*)&wT[((size_t)bhx * T_ + I * 64 + r) * DH + c];
  }
  if (tid < 64) bI[tid] = beta[(size_t)bhx * T_ + I * 64 + tid];
#pragma unroll
  for (int l = 0; l < 16; ++l) {
    int e = tid + l * 256; int r = e >> 6, c = e & 63;
    Li[r][c] = (r == c) ? 1.f : 0.f;
  }
  __syncthreads();
  const int tm = (tid >> 4) << 2, tn = (tid & 15) << 2;
  float cc[4][4] = {};
  for (int dd = 0; dd < 64; ++dd) {
    float a0 = Wsh[tm + 0][dd], a1 = Wsh[tm + 1][dd], a2 = Wsh[tm + 2][dd], a3 = Wsh[tm + 3][dd];
    float b0 = Wsh[tn + 0][dd], b1 = Wsh[tn + 1][dd], b2 = Wsh[tn + 2][dd], b3 = Wsh[tn + 3][dd];
    cc[0][0] += a0 * b0; cc[0][1] += a0 * b1; cc[0][2] += a0 * b2; cc[0][3] += a0 * b3;
    cc[1][0] += a1 * b0; cc[1][1] += a1 * b1; cc[1][2] += a1 * b2; cc[1][3] += a1 * b3;
    cc[2][0] += a2 * b0; cc[2][1] += a2 * b1; cc[2][2] += a2 * b2; cc[2][3] += a2 * b3;
    cc[3][0] += a3 * b0; cc[3][1] += a3 * b1; cc[3][2] += a3 * b2; cc[3][3] += a3 * b3;
  }
#pragma unroll
  for (int ii = 0; ii < 4; ++ii)
#pragma unroll
    for (int jj = 0; jj < 4; ++jj)
      Csh[tm + ii][tn + jj] = (tm + ii > tn + jj) ? cc[ii][jj] * bI[tn + jj] : 0.f;
  __syncthreads();
  const int sL = tid & 63, g = tid >> 6;
  for (int r = 0; r < 63; ++r) {
    float lr = Li[r][sL];
    for (int r2 = r + 1 + g; r2 < 64; r2 += 4)
      Li[r2][sL] -= Csh[r2][r] * lr;
    __syncthreads();
  }
#pragma unroll
  for (int l = 0; l < 4; ++l) {
    int f = tid + l * 256; int r = f >> 4, c0 = (f & 15) << 2;
    s16x4 p;
    p.x = bf16s(Li[r][c0 + 0]); p.y = bf16s(Li[r][c0 + 1]);
    p.z = bf16s(Li[r][c0 + 2]); p.w = bf16s(Li[r][c0 + 3]);
    *(s16x4*)&linv[((size_t)(bhx * 8 + I)) * 4096 + r * 64 + c0] = p;
  }
}

// ======================= WY chain: per column-chunk, MFMA recurrence =======================
__global__ __launch_bounds__(256) void chain_k(const __hip_bfloat16* __restrict__ kb,
                                               const __hip_bfloat16* __restrict__ wb,
                                               const __hip_bfloat16* __restrict__ linv,
                                               const float* __restrict__ beta,
                                               __hip_bfloat16* __restrict__ abT) {
  __shared__ __hip_bfloat16 Kb[64][72];   // [j][d]
  __shared__ __hip_bfloat16 Ws[64][72];   // [t][d]
  __shared__ __hip_bfloat16 WsT[64][72];  // [d][t]
  __shared__ __hip_bfloat16 Ls[64][72];   // [t][s]
  __shared__ __hip_bfloat16 Mhi[64][72];  // [j][d] = -M hi
  __shared__ __hip_bfloat16 Mlo[64][72];  // [j][d] = -M lo
  __shared__ __hip_bfloat16 Ps[64][72];   // [j][t] PT, then reused as X
  __shared__ float bI[64];
  const int ch = blockIdx.x, bhx = blockIdx.y;
  const int tid = threadIdx.x, w = tid >> 6, lane = tid & 63;
  const int fr = lane & 15, kq = lane >> 4;
  const size_t hb = (size_t)bhx * T_;
  const f32x4 zf = {0.f, 0.f, 0.f, 0.f};

  stage64(kb + (hb + ch * 64) * DH, DH, Kb, tid);
  for (int f = tid; f < 576; f += 256) {
    ((int4*)Mhi)[f] = make_int4(0, 0, 0, 0);
    ((int4*)Mlo)[f] = make_int4(0, 0, 0, 0);
  }
  f32x4 macc[4] = {zf, zf, zf, zf};

  for (int I = ch; I < 8; ++I) {
    __syncthreads();                                           // B1
    stage64(wb + (hb + I * 64) * DH, DH, Ws, tid);
    stage64(linv + ((size_t)(bhx * 8 + I)) * 4096, 64, Ls, tid);
    if (tid < 64) bI[tid] = beta[hb + I * 64 + tid];
    const int jr = w * 16 + kq * 4;
    if (I > ch) {
#pragma unroll
      for (int nb = 0; nb < 4; ++nb) {
        int d = nb * 16 + fr;
#pragma unroll
        for (int reg = 0; reg < 4; ++reg) {
          float m = -macc[nb][reg];
          __hip_bfloat16 h = __float2bfloat16(m);
          Mhi[jr + reg][d] = h;
          Mlo[jr + reg][d] = __float2bfloat16(m - __bfloat162float(h));
        }
      }
    }
    __syncthreads();                                           // B2
#pragma unroll
    for (int l = 0; l < 16; ++l) {
      int e = tid + l * 256;
      int t = e >> 6, d = e & 63;
      WsT[d][t] = Ws[t][d];
    }
    bf16x8 kb0 = ldfrag(Kb, w, 0, fr, kq), kb1 = ldfrag(Kb, w, 1, fr, kq);
    f32x4 pt[4];
#pragma unroll
    for (int nb = 0; nb < 4; ++nb) {
      bf16x8 b0 = ldfrag(Ws, nb, 0, fr, kq), b1 = ldfrag(Ws, nb, 1, fr, kq);
      pt[nb] = MFMA_BF16(kb0, b0, zf);
      pt[nb] = MFMA_BF16(kb1, b1, pt[nb]);
      if (I > ch) {
        bf16x8 mh0 = ldfrag(Mhi, w, 0, fr, kq), mh1 = ldfrag(Mhi, w, 1, fr, kq);
        bf16x8 ml0 = ldfrag(Mlo, w, 0, fr, kq), ml1 = ldfrag(Mlo, w, 1, fr, kq);
        pt[nb] = MFMA_BF16(mh0, b0, pt[nb]); pt[nb] = MFMA_BF16(mh1, b1, pt[nb]);
        pt[nb] = MFMA_BF16(ml0, b0, pt[nb]); pt[nb] = MFMA_BF16(ml1, b1, pt[nb]);
      }
    }
#pragma unroll
    for (int nb = 0; nb < 4; ++nb) {
      int t = nb * 16 + fr;
#pragma unroll
      for (int reg = 0; reg < 4; ++reg) {
        float v = pt[nb][reg];
        if (I == ch && t <= jr + reg) v = 0.f;
        Ps[jr + reg][t] = __float2bfloat16(v);
      }
    }
    __syncthreads();                                           // B3
    bf16x8 la0 = ldfrag(Ls, w, 0, fr, kq), la1 = ldfrag(Ls, w, 1, fr, kq);
    f32x4 av[4];
#pragma unroll
    for (int nb = 0; nb < 4; ++nb) {
      bf16x8 p0 = ldfrag(Ps, nb, 0, fr, kq), p1 = ldfrag(Ps, nb, 1, fr, kq);
      av[nb] = MFMA_BF16(la0, p0, zf);
      av[nb] = MFMA_BF16(la1, p1, av[nb]);
    }
    __syncthreads();                                           // B4
    const int tr = w * 16 + kq * 4;
#pragma unroll
    for (int nb = 0; nb < 4; ++nb) {
      s16x4 p;
      p.x = bf16s(bI[tr + 0] * av[nb][0]);
      p.y = bf16s(bI[tr + 1] * av[nb][1]);
      p.z = bf16s(bI[tr + 2] * av[nb][2]);
      p.w = bf16s(bI[tr + 3] * av[nb][3]);
      *(s16x4*)&Ps[nb * 16 + fr][tr] = p;
    }
    __syncthreads();                                           // B5
#pragma unroll
    for (int l = 0; l < 2; ++l) {
      int f = tid + l * 256;
      int r = f >> 3, c = (f & 7) << 3;
      *(int4*)&abT[(hb + ch * 64 + r) * T_ + I * 64 + c] = *(const int4*)&Ps[r][c];
    }
    bf16x8 xa0 = ldfrag(Ps, w, 0, fr, kq), xa1 = ldfrag(Ps, w, 1, fr, kq);
#pragma unroll
    for (int nb = 0; nb < 4; ++nb) {
      bf16x8 wt0 = ldfrag(WsT, nb, 0, fr, kq), wt1 = ldfrag(WsT, nb, 1, fr, kq);
      macc[nb] = MFMA_BF16(xa0, wt0, macc[nb]);
      macc[nb] = MFMA_BF16(xa1, wt1, macc[nb]);
    }
  }
}

// ======================= S via MFMA: S = Q K^T - tril(Q W^T) @ (beta A) =======================
__global__ __launch_bounds__(256) void s_mfma(const __hip_bfloat16* __restrict__ qb,
                                              const __hip_bfloat16* __restrict__ kb,
                                              const __hip_bfloat16* __restrict__ wb,
                                              const __hip_bfloat16* __restrict__ abT,
                                              float* __restrict__ S) {
  __shared__ __hip_bfloat16 Qs[64][72];
  __shared__ __hip_bfloat16 Bs[64][72];
  __shared__ __hip_bfloat16 Cs[64][72];
  __shared__ __hip_bfloat16 Ms[64][72];
  int ti = blockIdx.x;
  int it = 0, accum = 0;
  while (accum + it + 1 <= ti) { accum += it + 1; ++it; }
  const int jt = ti - accum;
  const int bh = blockIdx.y;
  const int tid = threadIdx.x, w = tid >> 6, lane = tid & 63;
  const int fr = lane & 15, kq = lane >> 4;
  const size_t hb = (size_t)bh * T_;

  stage64(qb + (hb + it * 64) * DH, DH, Qs, tid);
  stage64(kb + (hb + jt * 64) * DH, DH, Bs, tid);
  __syncthreads();

  const bf16x8 a0 = ldfrag(Qs, w, 0, fr, kq);
  const bf16x8 a1 = ldfrag(Qs, w, 1, fr, kq);

  f32x4 acc[4];
  const f32x4 zero = {0.f, 0.f, 0.f, 0.f};
#pragma unroll
  for (int nb = 0; nb < 4; ++nb) {
    acc[nb] = MFMA_BF16(a0, ldfrag(Bs, nb, 0, fr, kq), zero);
    acc[nb] = MFMA_BF16(a1, ldfrag(Bs, nb, 1, fr, kq), acc[nb]);
  }

  for (int c = jt; c <= it; ++c) {
    __syncthreads();
    stage64(wb + (hb + c * 64) * DH, DH, Bs, tid);
    stage64(abT + (hb + jt * 64) * T_ + c * 64, T_, Cs, tid);
    __syncthreads();
    f32x4 qw[4];
#pragma unroll
    for (int nb = 0; nb < 4; ++nb) {
      qw[nb] = MFMA_BF16(a0, ldfrag(Bs, nb, 0, fr, kq), zero);
      qw[nb] = MFMA_BF16(a1, ldfrag(Bs, nb, 1, fr, kq), qw[nb]);
    }
    const int row0 = w * 16 + kq * 4;
    const bool diag = (c == it);
#pragma unroll
    for (int nb = 0; nb < 4; ++nb) {
      int col = nb * 16 + fr;
#pragma unroll
      for (int reg = 0; reg < 4; ++reg) {
        float v = -qw[nb][reg];
        if (diag && col > row0 + reg) v = 0.f;
        Ms[row0 + reg][col] = __float2bfloat16(v);
      }
    }
    __syncthreads();
    const bf16x8 m0 = ldfrag(Ms, w, 0, fr, kq);
    const bf16x8 m1 = ldfrag(Ms, w, 1, fr, kq);
#pragma unroll
    for (int nb = 0; nb < 4; ++nb) {
      acc[nb] = MFMA_BF16(m0, ldfrag(Cs, nb, 0, fr, kq), acc[nb]);
      acc[nb] = MFMA_BF16(m1, ldfrag(Cs, nb, 1, fr, kq), acc[nb]);
    }
  }
#pragma unroll
  for (int nb = 0; nb < 4; ++nb) {
    int j = jt * 64 + nb * 16 + fr;
#pragma unroll
    for (int reg = 0; reg < 4; ++reg) {
      S[(hb + it * 64 + w * 16 + kq * 4 + reg) * T_ + j] = acc[nb][reg];
    }
  }
}

// ======================= softmax, causal, P written bf16 in place =======================
__global__ __launch_bounds__(64) void softmax_k(float* __restrict__ S, const float* __restrict__ G) {
  int i = blockIdx.x, bh = blockIdx.y;
  int lane = threadIdx.x;
  const float Gi = G[(size_t)bh * T_ + i];
  float* row = S + ((size_t)bh * T_ + i) * T_;
  const float* Gb = G + (size_t)bh * T_;
  float l[8];
  float m = -3e38f;
#pragma unroll
  for (int c = 0; c < 8; ++c) {
    int j = lane + c * 64;
    if (j <= i) { float v = row[j] * 0.125f + Gi - Gb[j]; l[c] = v; m = fmaxf(m, v); }
    else l[c] = -3e38f;
  }
#pragma unroll
  for (int mm = 32; mm >= 1; mm >>= 1) m = fmaxf(m, __shfl_xor(m, mm));
  float ssum = 0.f;
#pragma unroll
  for (int c = 0; c < 8; ++c) {
    int j = lane + c * 64;
    float p = (j <= i) ? expf(l[c] - m) : 0.f;
    l[c] = p; ssum += p;
  }
#pragma unroll
  for (int mm = 32; mm >= 1; mm >>= 1) ssum += __shfl_xor(ssum, mm);
  float inv = 1.f / ssum;
  __hip_bfloat16* prow = (__hip_bfloat16*)row;
#pragma unroll
  for (int c = 0; c < 8; ++c) prow[lane + c * 64] = __float2bfloat16(l[c] * inv);
}

// ======================= o = P @ V via MFMA (P bf16, V hi/lo bf16 transposed) ==========
__global__ __launch_bounds__(256) void pv_mfma(const __hip_bfloat16* __restrict__ pb,  // ld 2*T_
                                               const __hip_bfloat16* __restrict__ vhi, // [BH,dh,T]
                                               const __hip_bfloat16* __restrict__ vlo,
                                               __hip_bfloat16* __restrict__ ohi,
                                               __hip_bfloat16* __restrict__ olo) {
  __shared__ __hip_bfloat16 Ps[64][72];   // [i][t]
  __shared__ __hip_bfloat16 Vh[64][72];   // [dd][t]
  __shared__ __hip_bfloat16 Vl[64][72];   // [dd][t]
  const int it = blockIdx.x, bh = blockIdx.y;
  const int b = bh >> 4, h = bh & 15;
  const int tid = threadIdx.x, w = tid >> 6, lane = tid & 63;
  const int fr = lane & 15, kq = lane >> 4;
  const f32x4 zf = {0.f, 0.f, 0.f, 0.f};
  f32x4 acc[4] = {zf, zf, zf, zf};
  for (int c = 0; c <= it; ++c) {
    __syncthreads();
    stage64(pb + ((size_t)bh * T_ + it * 64) * (2 * T_) + c * 64, 2 * T_, Ps, tid);
    stage64(vhi + ((size_t)bh * DH) * T_ + c * 64, T_, Vh, tid);
    stage64(vlo + ((size_t)bh * DH) * T_ + c * 64, T_, Vl, tid);
    __syncthreads();
    bf16x8 p0 = ldfrag(Ps, w, 0, fr, kq), p1 = ldfrag(Ps, w, 1, fr, kq);
#pragma unroll
    for (int nb = 0; nb < 4; ++nb) {
      acc[nb] = MFMA_BF16(p0, ldfrag(Vh, nb, 0, fr, kq), acc[nb]);
      acc[nb] = MFMA_BF16(p1, ldfrag(Vh, nb, 1, fr, kq), acc[nb]);
      acc[nb] = MFMA_BF16(p0, ldfrag(Vl, nb, 0, fr, kq), acc[nb]);
      acc[nb] = MFMA_BF16(p1, ldfrag(Vl, nb, 1, fr, kq), acc[nb]);
    }
  }
#pragma unroll
  for (int nb = 0; nb < 4; ++nb) {
    int dd = nb * 16 + fr;
#pragma unroll
    for (int reg = 0; reg < 4; ++reg) {
      int i = it * 64 + w * 16 + kq * 4 + reg;
      size_t oi = ((size_t)(b * T_ + i)) * D_ + h * 64 + dd;
      float v = acc[nb][reg];
      __hip_bfloat16 hv = __float2bfloat16(v);
      ohi[oi] = hv;
      olo[oi] = __float2bfloat16(v - __bfloat162float(hv));
    }
  }
}

// ======================= launch =======================
extern "C" void kernel_launch(void* const* d_in, const int* in_sizes, int n_in,
                              void* d_out, int out_size, void* d_ws, size_t ws_size,
                              hipStream_t stream) {
  (void)in_sizes; (void)n_in; (void)out_size; (void)ws_size;
  const float* x     = (const float*)d_in[0];
  const float* Wq    = (const float*)d_in[1];
  const float* Wk    = (const float*)d_in[2];
  const float* Wv    = (const float*)d_in[3];
  const float* Wo    = (const float*)d_in[4];
  const float* wA    = (const float*)d_in[5];
  const float* wB    = (const float*)d_in[6];
  const float* convw = (const float*)d_in[7];
  const float* bw    = (const float*)d_in[8];
  const float* gw    = (const float*)d_in[9];
  const float* gb    = (const float*)d_in[10];
  const float* qnw   = (const float*)d_in[11];
  const float* knw   = (const float*)d_in[12];

  const size_t N1 = (size_t)BT_ * D_;          // 1,048,576
  const size_t NTT = (size_t)BH_ * T_ * T_;    // 8,388,608
  float* ws = (float*)d_ws;
  float* wTb   = ws;                       // [BH,T,dh] fp32
  float* ycat  = wTb + N1;                 // [BT,64] fp32
  float* S     = ycat + (size_t)BT_ * 64;  // [BH,T,T] fp32 (P bf16 aliases rows)
  float* beta  = S + NTT;
  float* G     = beta + (size_t)BH_ * T_;
  float* vpart = G + (size_t)BH_ * T_;     // [3][1024][1024] fp32
  float* opart = vpart + 3 * N1;           // [3][1024][1024] fp32
  __hip_bfloat16* qb16  = (__hip_bfloat16*)(opart + 3 * N1);
  __hip_bfloat16* kb16  = qb16 + N1;
  __hip_bfloat16* wb16  = kb16 + N1;
  __hip_bfloat16* abT   = wb16 + N1;            // [BH,T(j),T(t)] bf16
  __hip_bfloat16* linvb = abT + NTT;            // [BH,8,64,64] bf16
  __hip_bfloat16* xhi   = linvb + (size_t)BH_ * 8 * 4096;
  __hip_bfloat16* xlo   = xhi + N1;
  __hip_bfloat16* obhi  = xlo + N1;
  __hip_bfloat16* oblo  = obhi + N1;
  __hip_bfloat16* woThi = oblo + N1;
  __hip_bfloat16* woTlo = woThi + N1;
  __hip_bfloat16* vhi   = woTlo + N1;           // [BH,dh,T] bf16
  __hip_bfloat16* vlo   = vhi + N1;
  __hip_bfloat16* wcThi = vlo + N1;             // [64][D]
  __hip_bfloat16* wcTlo = wcThi + (size_t)64 * D_;
  // fused QKV weight [3072][1024] hi/lo aliases S (S written later in stream order)
  __hip_bfloat16* wqkvThi = (__hip_bfloat16*)S;
  __hip_bfloat16* wqkvTlo = wqkvThi + (size_t)3072 * D_;
  __hip_bfloat16* wvThi = wqkvThi + (size_t)2048 * D_;
  __hip_bfloat16* wvTlo = wqkvTlo + (size_t)2048 * D_;

  dim3 g16(16, 16);
  split_f32<<<1024, 256, 0, stream>>>(x, xhi, xlo);
  splitT_k<<<g16, 256, 0, stream>>>(Wq, wqkvThi, wqkvTlo);
  splitT_k<<<g16, 256, 0, stream>>>(Wk, wqkvThi + (size_t)1024 * D_, wqkvTlo + (size_t)1024 * D_);
  splitT_k<<<g16, 256, 0, stream>>>(Wv, wvThi, wvTlo);
  splitT_k<<<g16, 256, 0, stream>>>(Wo, woThi, woTlo);
  splitcat_k<<<64, 256, 0, stream>>>(wA, bw, gw, wcThi, wcTlo);
  gemm_ycat<<<dim3(1, 16), 256, 0, stream>>>(xhi, xlo, wcThi, wcTlo, ycat);
  // qk projection: 1-pass bf16 + fused rmsnorm -> qb16/kb16 (512 blocks)
  gemm_t<0><<<dim3(32, 16), 256, 0, stream>>>(xhi, nullptr, wqkvThi, nullptr,
                                              nullptr, qb16, kb16, qnw, knw);
  // V projection: 3 z-passes -> fp32 partials (768 blocks)
  gemm_t<1><<<dim3(16, 16, 3), 256, 0, stream>>>(xhi, xlo, wvThi, wvTlo,
                                                 vpart, nullptr, nullptr, nullptr, nullptr);
  combine_v<<<g16, 256, 0, stream>>>(vpart, vhi, vlo);
  gate_cumsum<<<BH_, 512, 0, stream>>>(ycat, gb, beta, G);
  wdir_k<<<BT_, 1024, 0, stream>>>(ycat, wB, convw, wTb, wb16);
  linv_k<<<dim3(8, BH_), 256, 0, stream>>>(wTb, beta, linvb);
  chain_k<<<dim3(8, BH_), 256, 0, stream>>>(kb16, wb16, linvb, beta, abT);
  s_mfma<<<dim3(36, BH_), 256, 0, stream>>>(qb16, kb16, wb16, abT, S);
  softmax_k<<<dim3(T_, BH_), 64, 0, stream>>>(S, G);
  pv_mfma<<<dim3(8, BH_), 256, 0, stream>>>((const __hip_bfloat16*)S, vhi, vlo, obhi, oblo);
  // output projection: 3 z-passes -> fp32 partials (768 blocks), then sum -> d_out
  gemm_t<1><<<dim3(16, 16, 3), 256, 0, stream>>>(obhi, oblo, woThi, woTlo,
                                                 opart, nullptr, nullptr, nullptr, nullptr);
  combine_o<<<1024, 256, 0, stream>>>(opart, (float*)d_out);
}

// Round 8
// 191.235 us; speedup vs baseline: 1.6114x; 1.0628x over previous
//
#include <hip/hip_runtime.h>
#include <hip/hip_bf16.h>
#include <math.h>

#define B_ 2
#define T_ 512
#define D_ 1024
#define H_ 16
#define R_ 32
#define DH 64
#define BT_ (B_*T_)
#define BH_ (B_*H_)

typedef __attribute__((ext_vector_type(8))) short bf16x8;
typedef __attribute__((ext_vector_type(4))) short s16x4;
typedef __attribute__((ext_vector_type(4))) float f32x4;

#define MFMA_BF16(a, b, c) __builtin_amdgcn_mfma_f32_16x16x32_bf16(a, b, c, 0, 0, 0)

static __device__ __forceinline__ short bf16s(float v) {
  __hip_bfloat16 b = __float2bfloat16(v);
  return *reinterpret_cast<short*>(&b);
}
static __device__ __forceinline__ float b2f(short s) {
  __hip_bfloat16 h; *reinterpret_cast<short*>(&h) = s; return __bfloat162float(h);
}

// ---- shared MFMA helpers (layout verified in R2; [72] pad = 144B stride, conflict-free) ----
__device__ __forceinline__ bf16x8 ldfrag(const __hip_bfloat16 s[][72], int b16, int kb, int fr, int kq) {
  return *(const bf16x8*)&s[b16 * 16 + fr][kb * 32 + kq * 8];
}
__device__ __forceinline__ void stage64(const __hip_bfloat16* __restrict__ g, int ldg,
                                        __hip_bfloat16 s[][72], int tid) {
#pragma unroll
  for (int l = 0; l < 2; ++l) {
    int f = tid + l * 256;
    int r = f >> 3, c = (f & 7) << 3;
    *(int4*)&s[r][c] = *(const int4*)&g[(size_t)r * ldg + c];
  }
}

// ---- global_load_lds 16B direct-to-LDS ----
typedef const __attribute__((address_space(1))) void* as1cv;
typedef __attribute__((address_space(3))) void* as3v;
__device__ __forceinline__ void gl16(const __hip_bfloat16* g, __hip_bfloat16* l) {
  __builtin_amdgcn_global_load_lds((as1cv)g, (as3v)l, 16, 0, 0);
}

// ======================= split fp32 -> bf16 hi/lo =======================
__global__ __launch_bounds__(256) void split_f32(const float* __restrict__ in,
                                                 __hip_bfloat16* __restrict__ hi,
                                                 __hip_bfloat16* __restrict__ lo) {
  int i4 = blockIdx.x * 256 + threadIdx.x;
  float4 v = ((const float4*)in)[i4];
  s16x4 ph, pl;
  float c[4] = {v.x, v.y, v.z, v.w};
#pragma unroll
  for (int u = 0; u < 4; ++u) {
    __hip_bfloat16 h = __float2bfloat16(c[u]);
    ph[u] = *reinterpret_cast<short*>(&h);
    pl[u] = bf16s(c[u] - __bfloat162float(h));
  }
  ((s16x4*)hi)[i4] = ph;
  ((s16x4*)lo)[i4] = pl;
}

// ======================= transpose + split 4 weights (z-select): W[K][N] -> WT hi/lo [N][K] ==
__global__ __launch_bounds__(256) void splitT4_k(const float* __restrict__ W0,
                                                 const float* __restrict__ W1,
                                                 const float* __restrict__ W2,
                                                 const float* __restrict__ W3,
                                                 __hip_bfloat16* __restrict__ t0h, __hip_bfloat16* __restrict__ t0l,
                                                 __hip_bfloat16* __restrict__ t1h, __hip_bfloat16* __restrict__ t1l,
                                                 __hip_bfloat16* __restrict__ t2h, __hip_bfloat16* __restrict__ t2l,
                                                 __hip_bfloat16* __restrict__ t3h, __hip_bfloat16* __restrict__ t3l) {
  __shared__ float tile[64][65];
  const int z = blockIdx.z;
  const float* Wm = (z == 0) ? W0 : (z == 1) ? W1 : (z == 2) ? W2 : W3;
  __hip_bfloat16* thi = (z == 0) ? t0h : (z == 1) ? t1h : (z == 2) ? t2h : t3h;
  __hip_bfloat16* tlo = (z == 0) ? t0l : (z == 1) ? t1l : (z == 2) ? t2l : t3l;
  const int bn = blockIdx.x * 64, bk = blockIdx.y * 64;
  const int tid = threadIdx.x;
#pragma unroll
  for (int l = 0; l < 4; ++l) {
    int f = tid + l * 256; int r = f >> 4, c = (f & 15) << 2;
    *(float4*)&tile[r][c] = *(const float4*)&Wm[(size_t)(bk + r) * D_ + bn + c];
  }
  __syncthreads();
#pragma unroll
  for (int l = 0; l < 4; ++l) {
    int f = tid + l * 256; int n = f >> 4, k0 = (f & 15) << 2;
    s16x4 ph, pl;
#pragma unroll
    for (int u = 0; u < 4; ++u) {
      float v = tile[k0 + u][n];
      __hip_bfloat16 h = __float2bfloat16(v);
      ph[u] = *reinterpret_cast<short*>(&h);
      pl[u] = bf16s(v - __bfloat162float(h));
    }
    *(s16x4*)&thi[(size_t)(bn + n) * D_ + bk + k0] = ph;
    *(s16x4*)&tlo[(size_t)(bn + n) * D_ + bk + k0] = pl;
  }
}

// ======================= concat+transpose+split small proj weights [wA|bw|gw] -> [64][D] ==
__global__ __launch_bounds__(256) void splitcat_k(const float* __restrict__ wA,
                                                  const float* __restrict__ bw,
                                                  const float* __restrict__ gw,
                                                  __hip_bfloat16* __restrict__ thi,
                                                  __hip_bfloat16* __restrict__ tlo) {
  int n = blockIdx.x;          // 0..63
  int tid = threadIdx.x;
  for (int k = tid; k < D_; k += 256) {
    float v;
    if (n < 32) v = wA[(size_t)k * R_ + n];
    else if (n < 48) v = bw[(size_t)k * H_ + (n - 32)];
    else v = gw[(size_t)k * H_ + (n - 48)];
    __hip_bfloat16 h = __float2bfloat16(v);
    thi[(size_t)n * D_ + k] = h;
    tlo[(size_t)n * D_ + k] = __float2bfloat16(v - __bfloat162float(h));
  }
}

// ======================= 64x64-tile GEMM, 4 waves (wave tile 16x64), K=1024 ============
// MODE 0: qk projection (1-pass bf16) with fused rmsnorm epilogue -> qb16/kb16.
// MODE 1: z-pass partial GEMM: z=0 ah*bh, z=1 al*bh, z=2 ah*bl -> C + z*1M fp32.
template<int MODE>
__global__ __launch_bounds__(256) void gemm_t(const __hip_bfloat16* __restrict__ ah,
                                              const __hip_bfloat16* __restrict__ al,
                                              const __hip_bfloat16* __restrict__ bh,
                                              const __hip_bfloat16* __restrict__ bl,
                                              float* __restrict__ Cbase,
                                              __hip_bfloat16* __restrict__ qb,
                                              __hip_bfloat16* __restrict__ kb,
                                              const float* __restrict__ qnw,
                                              const float* __restrict__ knw) {
  __shared__ __hip_bfloat16 As[64][64];
  __shared__ __hip_bfloat16 Bs[64][64];
  const int bm = blockIdx.y * 64, bn = blockIdx.x * 64;
  const int tid = threadIdx.x, w = tid >> 6, lane = tid & 63;
  const int fr = lane & 15, kq = lane >> 4;
  const __hip_bfloat16* a = ah;
  const __hip_bfloat16* b = bh;
  float* C = Cbase;
  if (MODE == 1) {
    int z = blockIdx.z;
    a = (z == 1) ? al : ah;
    b = (z == 2) ? bl : bh;
    C = Cbase + (size_t)z * (1u << 20);
  }
  const f32x4 zf = {0.f, 0.f, 0.f, 0.f};
  f32x4 acc[4] = {zf, zf, zf, zf};
  const __hip_bfloat16* ap = a + (size_t)bm * D_;
  const __hip_bfloat16* bp = b + (size_t)bn * D_;

  for (int t = 0; t < 16; ++t) {
    __syncthreads();
#pragma unroll
    for (int i = 0; i < 2; ++i) {
      int chunk = tid + i * 256;
      int row = chunk >> 3, c8 = (chunk & 7) ^ (row & 7);    // source pre-swizzle
      gl16(ap + (size_t)row * D_ + t * 64 + c8 * 8, &As[0][0] + chunk * 8);
      gl16(bp + (size_t)row * D_ + t * 64 + c8 * 8, &Bs[0][0] + chunk * 8);
    }
    __syncthreads();
    const int ra = w * 16 + fr, sa = ra & 7;
    bf16x8 a0 = *(const bf16x8*)&As[ra][(kq ^ sa) * 8];
    bf16x8 a1 = *(const bf16x8*)&As[ra][((kq + 4) ^ sa) * 8];
#pragma unroll
    for (int n = 0; n < 4; ++n) {
      int rb = n * 16 + fr, sb = rb & 7;
      bf16x8 b0 = *(const bf16x8*)&Bs[rb][(kq ^ sb) * 8];
      bf16x8 b1 = *(const bf16x8*)&Bs[rb][((kq + 4) ^ sb) * 8];
      acc[n] = MFMA_BF16(a0, b0, acc[n]);
      acc[n] = MFMA_BF16(a1, b1, acc[n]);
    }
  }

  if (MODE == 0) {
    float rs[4];
#pragma unroll
    for (int reg = 0; reg < 4; ++reg) {
      float s = 0.f;
#pragma unroll
      for (int n = 0; n < 4; ++n) s += acc[n][reg] * acc[n][reg];
#pragma unroll
      for (int mm = 1; mm <= 8; mm <<= 1) s += __shfl_xor(s, mm);
      rs[reg] = rsqrtf(s * (1.f / DH) + 1e-5f);
    }
    const bool isq = (bn < 1024);
    __hip_bfloat16* outp = isq ? qb : kb;
#pragma unroll
    for (int n = 0; n < 4; ++n) {
      int gn = bn + n * 16 + fr;
      int dd = gn & 63, h = (gn & 1023) >> 6;
      float nw = (isq ? qnw : knw)[dd];
#pragma unroll
      for (int reg = 0; reg < 4; ++reg) {
        int gm = bm + w * 16 + kq * 4 + reg;
        int bb = gm >> 9, tt = gm & 511;
        outp[(((size_t)(bb * H_ + h)) * T_ + tt) * DH + dd] =
            __float2bfloat16(acc[n][reg] * rs[reg] * nw);
      }
    }
  } else {
#pragma unroll
    for (int n = 0; n < 4; ++n) {
      int gn = bn + n * 16 + fr;
#pragma unroll
      for (int reg = 0; reg < 4; ++reg) {
        int gm = bm + w * 16 + kq * 4 + reg;
        C[(size_t)gm * D_ + gn] = acc[n][reg];
      }
    }
  }
}

// ======================= combine 3 V partials -> transposed hi/lo bf16 [BH,dh,T] ==========
__global__ __launch_bounds__(256) void combine_v(const float* __restrict__ p,
                                                 __hip_bfloat16* __restrict__ vhi,
                                                 __hip_bfloat16* __restrict__ vlo) {
  __shared__ float Ls[64][65];          // [n][m]
  const int n0 = blockIdx.x * 64, m0 = blockIdx.y * 64;
  const int tid = threadIdx.x;
#pragma unroll
  for (int l = 0; l < 4; ++l) {
    int f = tid + l * 256; int r = f >> 4, c = (f & 15) << 2;
    const float* pp = &p[(size_t)(m0 + r) * D_ + n0 + c];
    float4 v0 = *(const float4*)pp;
    float4 v1 = *(const float4*)(pp + (1u << 20));
    float4 v2 = *(const float4*)(pp + (2u << 20));
    Ls[c + 0][r] = v0.x + v1.x + v2.x;
    Ls[c + 1][r] = v0.y + v1.y + v2.y;
    Ls[c + 2][r] = v0.z + v1.z + v2.z;
    Ls[c + 3][r] = v0.w + v1.w + v2.w;
  }
  __syncthreads();
  const int bb = m0 >> 9, t0 = m0 & 511, h = n0 >> 6;
  const size_t base = (((size_t)(bb * H_ + h)) * DH) * T_ + t0;
#pragma unroll
  for (int l = 0; l < 2; ++l) {
    int f = tid + l * 256;
    int dd = f >> 3, tq = (f & 7) * 8;
    bf16x8 ph, pl;
#pragma unroll
    for (int u = 0; u < 8; ++u) {
      float v = Ls[dd][tq + u];
      __hip_bfloat16 hv = __float2bfloat16(v);
      ph[u] = *reinterpret_cast<short*>(&hv);
      pl[u] = bf16s(v - __bfloat162float(hv));
    }
    *(bf16x8*)&vhi[base + (size_t)dd * T_ + tq] = ph;
    *(bf16x8*)&vlo[base + (size_t)dd * T_ + tq] = pl;
  }
}

// ======================= combine 3 O partials -> d_out fp32 =======================
__global__ __launch_bounds__(256) void combine_o(const float* __restrict__ p,
                                                 float* __restrict__ out) {
  int i4 = blockIdx.x * 256 + threadIdx.x;
  const float4* p4 = (const float4*)p;
  float4 a = p4[i4], b = p4[i4 + (1u << 18)], c = p4[i4 + (2u << 18)];
  float4 r;
  r.x = a.x + b.x + c.x; r.y = a.y + b.y + c.y;
  r.z = a.z + b.z + c.z; r.w = a.w + b.w + c.w;
  ((float4*)out)[i4] = r;
}

// ======================= small GEMM for ycat (M=BT, N=64) via 3x bf16 MFMA ============
__global__ __launch_bounds__(256) void gemm_ycat(const __hip_bfloat16* __restrict__ ah,
                                                 const __hip_bfloat16* __restrict__ al,
                                                 const __hip_bfloat16* __restrict__ bh,
                                                 const __hip_bfloat16* __restrict__ bl,
                                                 float* __restrict__ C) {
  __shared__ __hip_bfloat16 Ah[64][72], Al[64][72], Bh[64][72], Bl[64][72];
  const int bm = blockIdx.y * 64;
  const int tid = threadIdx.x, w = tid >> 6, lane = tid & 63;
  const int fr = lane & 15, kq = lane >> 4;
  const f32x4 zf = {0.f, 0.f, 0.f, 0.f};
  f32x4 acc[4] = {zf, zf, zf, zf};
  for (int k0 = 0; k0 < D_; k0 += 64) {
    __syncthreads();
    stage64(ah + (size_t)bm * D_ + k0, D_, Ah, tid);
    stage64(al + (size_t)bm * D_ + k0, D_, Al, tid);
    stage64(bh + k0, D_, Bh, tid);
    stage64(bl + k0, D_, Bl, tid);
    __syncthreads();
    bf16x8 ah0 = ldfrag(Ah, w, 0, fr, kq), ah1 = ldfrag(Ah, w, 1, fr, kq);
    bf16x8 al0 = ldfrag(Al, w, 0, fr, kq), al1 = ldfrag(Al, w, 1, fr, kq);
#pragma unroll
    for (int nb = 0; nb < 4; ++nb) {
      bf16x8 b0 = ldfrag(Bh, nb, 0, fr, kq), b1 = ldfrag(Bh, nb, 1, fr, kq);
      bf16x8 c0 = ldfrag(Bl, nb, 0, fr, kq), c1 = ldfrag(Bl, nb, 1, fr, kq);
      acc[nb] = MFMA_BF16(ah0, b0, acc[nb]); acc[nb] = MFMA_BF16(ah1, b1, acc[nb]);
      acc[nb] = MFMA_BF16(ah0, c0, acc[nb]); acc[nb] = MFMA_BF16(ah1, c1, acc[nb]);
      acc[nb] = MFMA_BF16(al0, b0, acc[nb]); acc[nb] = MFMA_BF16(al1, b1, acc[nb]);
    }
  }
#pragma unroll
  for (int nb = 0; nb < 4; ++nb) {
    int n = nb * 16 + fr;
#pragma unroll
    for (int reg = 0; reg < 4; ++reg) {
      int m = bm + w * 16 + kq * 4 + reg;
      C[(size_t)m * 64 + n] = acc[nb][reg];
    }
  }
}

// ======================= gates: beta, logsigmoid + cumsum =======================
__global__ __launch_bounds__(512) void gate_cumsum(const float* __restrict__ ycat,
                                                   const float* __restrict__ gb,
                                                   float* __restrict__ beta,
                                                   float* __restrict__ G) {
  __shared__ float s[T_];
  int bh = blockIdx.x, b = bh >> 4, h = bh & 15, t = threadIdx.x;
  int bt = b * T_ + t;
  float by = ycat[(size_t)bt * 64 + 32 + h];
  beta[(size_t)bh * T_ + t] = 2.f / (1.f + expf(-by));
  float gy = ycat[(size_t)bt * 64 + 48 + h] + gb[h];
  s[t] = fminf(gy, 0.f) - log1pf(expf(-fabsf(gy)));
  __syncthreads();
  for (int off = 1; off < T_; off <<= 1) {
    float v = (t >= off) ? s[t - off] : 0.f;
    __syncthreads();
    s[t] += v;
    __syncthreads();
  }
  G[(size_t)bh * T_ + t] = s[t];
}

// ======================= w: low-rank expand + conv3 + silu + unit-normalize ===========
__global__ __launch_bounds__(1024) void wdir_k(const float* __restrict__ ycat,
                                               const float* __restrict__ wB,
                                               const float* __restrict__ convw,
                                               float* __restrict__ wT,
                                               __hip_bfloat16* __restrict__ wb16) {
  int bt = blockIdx.x, b = bt / T_, t = bt - b * T_;
  __shared__ float wl[3][R_];
  int tid = threadIdx.x;
  if (tid < 3 * R_) {
    int row = tid / R_, r = tid - row * R_;
    int ts = t - row;
    wl[row][r] = (ts >= 0) ? ycat[(size_t)(b * T_ + ts) * 64 + r] : 0.f;
  }
  __syncthreads();
  float f0 = 0.f, f1 = 0.f, f2 = 0.f;
  for (int r = 0; r < R_; ++r) {
    float wb = wB[(size_t)r * D_ + tid];
    f0 += wl[0][r] * wb; f1 += wl[1][r] * wb; f2 += wl[2][r] * wb;
  }
  float y = f2 * convw[tid * 3 + 0] + f1 * convw[tid * 3 + 1] + f0 * convw[tid * 3 + 2];
  float s = y / (1.f + expf(-y));                       // silu
  float ss = s * s;
#pragma unroll
  for (int m = 32; m >= 1; m >>= 1) ss += __shfl_xor(ss, m);
  float outv = s * rsqrtf(ss + 1e-12f);
  int h = tid >> 6, dd = tid & 63;
  size_t o = (((size_t)(b * H_ + h)) * T_ + t) * DH + dd;
  wT[o] = outv;
  wb16[o] = __float2bfloat16(outv);
}

// ======================= per-block unit-lower-triangular inverse =======================
__global__ __launch_bounds__(256) void linv_k(const float* __restrict__ wT,
                                              const float* __restrict__ beta,
                                              __hip_bfloat16* __restrict__ linv) {
  __shared__ float Wsh[64][68];
  __shared__ float Csh[64][65];
  __shared__ float Li[64][68];
  __shared__ float bI[64];
  const int I = blockIdx.x, bhx = blockIdx.y;
  const int tid = threadIdx.x;
#pragma unroll
  for (int l = 0; l < 4; ++l) {
    int f = tid + l * 256; int r = f >> 4, c = (f & 15) << 2;
    *(float4*)&Wsh[r][c] = *(const float4*)&wT[((size_t)bhx * T_ + I * 64 + r) * DH + c];
  }
  if (tid < 64) bI[tid] = beta[(size_t)bhx * T_ + I * 64 + tid];
#pragma unroll
  for (int l = 0; l < 16; ++l) {
    int e = tid + l * 256; int r = e >> 6, c = e & 63;
    Li[r][c] = (r == c) ? 1.f : 0.f;
  }
  __syncthreads();
  const int tm = (tid >> 4) << 2, tn = (tid & 15) << 2;
  float cc[4][4] = {};
  for (int dd = 0; dd < 64; ++dd) {
    float a0 = Wsh[tm + 0][dd], a1 = Wsh[tm + 1][dd], a2 = Wsh[tm + 2][dd], a3 = Wsh[tm + 3][dd];
    float b0 = Wsh[tn + 0][dd], b1 = Wsh[tn + 1][dd], b2 = Wsh[tn + 2][dd], b3 = Wsh[tn + 3][dd];
    cc[0][0] += a0 * b0; cc[0][1] += a0 * b1; cc[0][2] += a0 * b2; cc[0][3] += a0 * b3;
    cc[1][0] += a1 * b0; cc[1][1] += a1 * b1; cc[1][2] += a1 * b2; cc[1][3] += a1 * b3;
    cc[2][0] += a2 * b0; cc[2][1] += a2 * b1; cc[2][2] += a2 * b2; cc[2][3] += a2 * b3;
    cc[3][0] += a3 * b0; cc[3][1] += a3 * b1; cc[3][2] += a3 * b2; cc[3][3] += a3 * b3;
  }
#pragma unroll
  for (int ii = 0; ii < 4; ++ii)
#pragma unroll
    for (int jj = 0; jj < 4; ++jj)
      Csh[tm + ii][tn + jj] = (tm + ii > tn + jj) ? cc[ii][jj] * bI[tn + jj] : 0.f;
  __syncthreads();
  const int sL = tid & 63, g = tid >> 6;
  for (int r = 0; r < 63; ++r) {
    float lr = Li[r][sL];
    for (int r2 = r + 1 + g; r2 < 64; r2 += 4)
      Li[r2][sL] -= Csh[r2][r] * lr;
    __syncthreads();
  }
#pragma unroll
  for (int l = 0; l < 4; ++l) {
    int f = tid + l * 256; int r = f >> 4, c0 = (f & 15) << 2;
    s16x4 p;
    p.x = bf16s(Li[r][c0 + 0]); p.y = bf16s(Li[r][c0 + 1]);
    p.z = bf16s(Li[r][c0 + 2]); p.w = bf16s(Li[r][c0 + 3]);
    *(s16x4*)&linv[((size_t)(bhx * 8 + I)) * 4096 + r * 64 + c0] = p;
  }
}

// ======================= WY chain + khat checkpoints =======================
// khat[bh][I][j][d] = k_j - sum_{t < I*64, t>j} beta_t A_{t,j} w_t  (written for j-chunk ch at each I)
__global__ __launch_bounds__(256) void chain_k(const __hip_bfloat16* __restrict__ kb,
                                               const __hip_bfloat16* __restrict__ wb,
                                               const __hip_bfloat16* __restrict__ linv,
                                               const float* __restrict__ beta,
                                               __hip_bfloat16* __restrict__ abT,
                                               __hip_bfloat16* __restrict__ khat) {
  __shared__ __hip_bfloat16 Kb[64][72];   // [j][d]
  __shared__ __hip_bfloat16 Ws[64][72];   // [t][d]
  __shared__ __hip_bfloat16 WsT[64][72];  // [d][t]
  __shared__ __hip_bfloat16 Ls[64][72];   // [t][s]
  __shared__ __hip_bfloat16 Mhi[64][72];  // [j][d] = -M hi
  __shared__ __hip_bfloat16 Mlo[64][72];  // [j][d] = -M lo
  __shared__ __hip_bfloat16 Ps[64][72];   // [j][t] PT, then reused as X
  __shared__ float bI[64];
  const int ch = blockIdx.x, bhx = blockIdx.y;
  const int tid = threadIdx.x, w = tid >> 6, lane = tid & 63;
  const int fr = lane & 15, kq = lane >> 4;
  const size_t hb = (size_t)bhx * T_;
  const f32x4 zf = {0.f, 0.f, 0.f, 0.f};

  stage64(kb + (hb + ch * 64) * DH, DH, Kb, tid);
  for (int f = tid; f < 576; f += 256) {
    ((int4*)Mhi)[f] = make_int4(0, 0, 0, 0);
    ((int4*)Mlo)[f] = make_int4(0, 0, 0, 0);
  }
  f32x4 macc[4] = {zf, zf, zf, zf};

  for (int I = ch; I < 8; ++I) {
    __syncthreads();                                           // B1
    stage64(wb + (hb + I * 64) * DH, DH, Ws, tid);
    stage64(linv + ((size_t)(bhx * 8 + I)) * 4096, 64, Ls, tid);
    if (tid < 64) bI[tid] = beta[hb + I * 64 + tid];
    const int jr = w * 16 + kq * 4;
    if (I > ch) {
#pragma unroll
      for (int nb = 0; nb < 4; ++nb) {
        int d = nb * 16 + fr;
#pragma unroll
        for (int reg = 0; reg < 4; ++reg) {
          float m = -macc[nb][reg];
          __hip_bfloat16 h = __float2bfloat16(m);
          Mhi[jr + reg][d] = h;
          Mlo[jr + reg][d] = __float2bfloat16(m - __bfloat162float(h));
        }
      }
    }
    __syncthreads();                                           // B2
    // khat checkpoint: khat^{(I)} = Kb + (-M)hi + (-M)lo, coalesced bf16 write
#pragma unroll
    for (int l = 0; l < 2; ++l) {
      int f = tid + l * 256;
      int r = f >> 3, c = (f & 7) << 3;
      bf16x8 kv = *(const bf16x8*)&Kb[r][c];
      bf16x8 mh = *(const bf16x8*)&Mhi[r][c];
      bf16x8 ml = *(const bf16x8*)&Mlo[r][c];
      bf16x8 o;
#pragma unroll
      for (int u = 0; u < 8; ++u) o[u] = bf16s(b2f(kv[u]) + b2f(mh[u]) + b2f(ml[u]));
      *(bf16x8*)&khat[(((size_t)(bhx * 8 + I)) * T_ + ch * 64 + r) * DH + c] = o;
    }
#pragma unroll
    for (int l = 0; l < 16; ++l) {
      int e = tid + l * 256;
      int t = e >> 6, d = e & 63;
      WsT[d][t] = Ws[t][d];
    }
    bf16x8 kb0 = ldfrag(Kb, w, 0, fr, kq), kb1 = ldfrag(Kb, w, 1, fr, kq);
    f32x4 pt[4];
#pragma unroll
    for (int nb = 0; nb < 4; ++nb) {
      bf16x8 b0 = ldfrag(Ws, nb, 0, fr, kq), b1 = ldfrag(Ws, nb, 1, fr, kq);
      pt[nb] = MFMA_BF16(kb0, b0, zf);
      pt[nb] = MFMA_BF16(kb1, b1, pt[nb]);
      if (I > ch) {
        bf16x8 mh0 = ldfrag(Mhi, w, 0, fr, kq), mh1 = ldfrag(Mhi, w, 1, fr, kq);
        bf16x8 ml0 = ldfrag(Mlo, w, 0, fr, kq), ml1 = ldfrag(Mlo, w, 1, fr, kq);
        pt[nb] = MFMA_BF16(mh0, b0, pt[nb]); pt[nb] = MFMA_BF16(mh1, b1, pt[nb]);
        pt[nb] = MFMA_BF16(ml0, b0, pt[nb]); pt[nb] = MFMA_BF16(ml1, b1, pt[nb]);
      }
    }
#pragma unroll
    for (int nb = 0; nb < 4; ++nb) {
      int t = nb * 16 + fr;
#pragma unroll
      for (int reg = 0; reg < 4; ++reg) {
        float v = pt[nb][reg];
        if (I == ch && t <= jr + reg) v = 0.f;
        Ps[jr + reg][t] = __float2bfloat16(v);
      }
    }
    __syncthreads();                                           // B3
    bf16x8 la0 = ldfrag(Ls, w, 0, fr, kq), la1 = ldfrag(Ls, w, 1, fr, kq);
    f32x4 av[4];
#pragma unroll
    for (int nb = 0; nb < 4; ++nb) {
      bf16x8 p0 = ldfrag(Ps, nb, 0, fr, kq), p1 = ldfrag(Ps, nb, 1, fr, kq);
      av[nb] = MFMA_BF16(la0, p0, zf);
      av[nb] = MFMA_BF16(la1, p1, av[nb]);
    }
    __syncthreads();                                           // B4
    const int tr = w * 16 + kq * 4;
#pragma unroll
    for (int nb = 0; nb < 4; ++nb) {
      s16x4 p;
      p.x = bf16s(bI[tr + 0] * av[nb][0]);
      p.y = bf16s(bI[tr + 1] * av[nb][1]);
      p.z = bf16s(bI[tr + 2] * av[nb][2]);
      p.w = bf16s(bI[tr + 3] * av[nb][3]);
      *(s16x4*)&Ps[nb * 16 + fr][tr] = p;
    }
    __syncthreads();                                           // B5
#pragma unroll
    for (int l = 0; l < 2; ++l) {
      int f = tid + l * 256;
      int r = f >> 3, c = (f & 7) << 3;
      *(int4*)&abT[(hb + ch * 64 + r) * T_ + I * 64 + c] = *(const int4*)&Ps[r][c];
    }
    bf16x8 xa0 = ldfrag(Ps, w, 0, fr, kq), xa1 = ldfrag(Ps, w, 1, fr, kq);
#pragma unroll
    for (int nb = 0; nb < 4; ++nb) {
      bf16x8 wt0 = ldfrag(WsT, nb, 0, fr, kq), wt1 = ldfrag(WsT, nb, 1, fr, kq);
      macc[nb] = MFMA_BF16(xa0, wt0, macc[nb]);
      macc[nb] = MFMA_BF16(xa1, wt1, macc[nb]);
    }
  }
}

// ======================= S row-panel: S = Q khat^T - tril(Q W^T) @ Ab[it-block] ==========
// grid (it=8, bh). qw/Ms computed ONCE per row panel; per jt-tile: 2 stages + 16 MFMA.
__global__ __launch_bounds__(256) void s_row(const __hip_bfloat16* __restrict__ qb,
                                             const __hip_bfloat16* __restrict__ wb,
                                             const __hip_bfloat16* __restrict__ khat,
                                             const __hip_bfloat16* __restrict__ abT,
                                             float* __restrict__ S) {
  __shared__ __hip_bfloat16 Qs[64][72];
  __shared__ __hip_bfloat16 Ws[64][72];
  __shared__ __hip_bfloat16 Ms[64][72];   // masked -(Q W^T) [i][t]
  __shared__ __hip_bfloat16 Ks[64][72];   // khat tile [j][d]
  __shared__ __hip_bfloat16 Cs[64][72];   // abT tile [j][t]
  const int it = blockIdx.x, bh = blockIdx.y;
  const int tid = threadIdx.x, w = tid >> 6, lane = tid & 63;
  const int fr = lane & 15, kq = lane >> 4;
  const size_t hb = (size_t)bh * T_;
  const f32x4 zero = {0.f, 0.f, 0.f, 0.f};

  stage64(qb + (hb + it * 64) * DH, DH, Qs, tid);
  stage64(wb + (hb + it * 64) * DH, DH, Ws, tid);
  __syncthreads();
  const bf16x8 a0 = ldfrag(Qs, w, 0, fr, kq);
  const bf16x8 a1 = ldfrag(Qs, w, 1, fr, kq);
  // qw = Q . W^T, masked t<=i, negated
  f32x4 qw[4];
#pragma unroll
  for (int nb = 0; nb < 4; ++nb) {
    qw[nb] = MFMA_BF16(a0, ldfrag(Ws, nb, 0, fr, kq), zero);
    qw[nb] = MFMA_BF16(a1, ldfrag(Ws, nb, 1, fr, kq), qw[nb]);
  }
  const int row0 = w * 16 + kq * 4;
#pragma unroll
  for (int nb = 0; nb < 4; ++nb) {
    int col = nb * 16 + fr;
#pragma unroll
    for (int reg = 0; reg < 4; ++reg) {
      float v = -qw[nb][reg];
      if (col > row0 + reg) v = 0.f;
      Ms[row0 + reg][col] = __float2bfloat16(v);
    }
  }
  __syncthreads();
  const bf16x8 m0 = ldfrag(Ms, w, 0, fr, kq);
  const bf16x8 m1 = ldfrag(Ms, w, 1, fr, kq);
  const __hip_bfloat16* kh = khat + ((size_t)(bh * 8 + it)) * T_ * DH;

  for (int jt = 0; jt <= it; ++jt) {
    __syncthreads();               // prior iter's reads done
    stage64(kh + (size_t)(jt * 64) * DH, DH, Ks, tid);
    stage64(abT + (hb + jt * 64) * T_ + it * 64, T_, Cs, tid);
    __syncthreads();
    f32x4 acc[4];
#pragma unroll
    for (int nb = 0; nb < 4; ++nb) {
      acc[nb] = MFMA_BF16(a0, ldfrag(Ks, nb, 0, fr, kq), zero);
      acc[nb] = MFMA_BF16(a1, ldfrag(Ks, nb, 1, fr, kq), acc[nb]);
      acc[nb] = MFMA_BF16(m0, ldfrag(Cs, nb, 0, fr, kq), acc[nb]);
      acc[nb] = MFMA_BF16(m1, ldfrag(Cs, nb, 1, fr, kq), acc[nb]);
    }
#pragma unroll
    for (int nb = 0; nb < 4; ++nb) {
      int j = jt * 64 + nb * 16 + fr;
#pragma unroll
      for (int reg = 0; reg < 4; ++reg) {
        S[(hb + it * 64 + row0 + reg) * T_ + j] = acc[nb][reg];
      }
    }
  }
}

// ======================= softmax, causal, P written bf16 in place =======================
__global__ __launch_bounds__(64) void softmax_k(float* __restrict__ S, const float* __restrict__ G) {
  int i = blockIdx.x, bh = blockIdx.y;
  int lane = threadIdx.x;
  const float Gi = G[(size_t)bh * T_ + i];
  float* row = S + ((size_t)bh * T_ + i) * T_;
  const float* Gb = G + (size_t)bh * T_;
  float l[8];
  float m = -3e38f;
#pragma unroll
  for (int c = 0; c < 8; ++c) {
    int j = lane + c * 64;
    if (j <= i) { float v = row[j] * 0.125f + Gi - Gb[j]; l[c] = v; m = fmaxf(m, v); }
    else l[c] = -3e38f;
  }
#pragma unroll
  for (int mm = 32; mm >= 1; mm >>= 1) m = fmaxf(m, __shfl_xor(m, mm));
  float ssum = 0.f;
#pragma unroll
  for (int c = 0; c < 8; ++c) {
    int j = lane + c * 64;
    float p = (j <= i) ? expf(l[c] - m) : 0.f;
    l[c] = p; ssum += p;
  }
#pragma unroll
  for (int mm = 32; mm >= 1; mm >>= 1) ssum += __shfl_xor(ssum, mm);
  float inv = 1.f / ssum;
  __hip_bfloat16* prow = (__hip_bfloat16*)row;
#pragma unroll
  for (int c = 0; c < 8; ++c) prow[lane + c * 64] = __float2bfloat16(l[c] * inv);
}

// ======================= o = P @ V via MFMA (P bf16, V hi/lo bf16 transposed) ==========
__global__ __launch_bounds__(256) void pv_mfma(const __hip_bfloat16* __restrict__ pb,  // ld 2*T_
                                               const __hip_bfloat16* __restrict__ vhi, // [BH,dh,T]
                                               const __hip_bfloat16* __restrict__ vlo,
                                               __hip_bfloat16* __restrict__ ohi,
                                               __hip_bfloat16* __restrict__ olo) {
  __shared__ __hip_bfloat16 Ps[64][72];   // [i][t]
  __shared__ __hip_bfloat16 Vh[64][72];   // [dd][t]
  __shared__ __hip_bfloat16 Vl[64][72];   // [dd][t]
  const int it = blockIdx.x, bh = blockIdx.y;
  const int b = bh >> 4, h = bh & 15;
  const int tid = threadIdx.x, w = tid >> 6, lane = tid & 63;
  const int fr = lane & 15, kq = lane >> 4;
  const f32x4 zf = {0.f, 0.f, 0.f, 0.f};
  f32x4 acc[4] = {zf, zf, zf, zf};
  for (int c = 0; c <= it; ++c) {
    __syncthreads();
    stage64(pb + ((size_t)bh * T_ + it * 64) * (2 * T_) + c * 64, 2 * T_, Ps, tid);
    stage64(vhi + ((size_t)bh * DH) * T_ + c * 64, T_, Vh, tid);
    stage64(vlo + ((size_t)bh * DH) * T_ + c * 64, T_, Vl, tid);
    __syncthreads();
    bf16x8 p0 = ldfrag(Ps, w, 0, fr, kq), p1 = ldfrag(Ps, w, 1, fr, kq);
#pragma unroll
    for (int nb = 0; nb < 4; ++nb) {
      acc[nb] = MFMA_BF16(p0, ldfrag(Vh, nb, 0, fr, kq), acc[nb]);
      acc[nb] = MFMA_BF16(p1, ldfrag(Vh, nb, 1, fr, kq), acc[nb]);
      acc[nb] = MFMA_BF16(p0, ldfrag(Vl, nb, 0, fr, kq), acc[nb]);
      acc[nb] = MFMA_BF16(p1, ldfrag(Vl, nb, 1, fr, kq), acc[nb]);
    }
  }
#pragma unroll
  for (int nb = 0; nb < 4; ++nb) {
    int dd = nb * 16 + fr;
#pragma unroll
    for (int reg = 0; reg < 4; ++reg) {
      int i = it * 64 + w * 16 + kq * 4 + reg;
      size_t oi = ((size_t)(b * T_ + i)) * D_ + h * 64 + dd;
      float v = acc[nb][reg];
      __hip_bfloat16 hv = __float2bfloat16(v);
      ohi[oi] = hv;
      olo[oi] = __float2bfloat16(v - __bfloat162float(hv));
    }
  }
}

// ======================= launch =======================
extern "C" void kernel_launch(void* const* d_in, const int* in_sizes, int n_in,
                              void* d_out, int out_size, void* d_ws, size_t ws_size,
                              hipStream_t stream) {
  (void)in_sizes; (void)n_in; (void)out_size; (void)ws_size;
  const float* x     = (const float*)d_in[0];
  const float* Wq    = (const float*)d_in[1];
  const float* Wk    = (const float*)d_in[2];
  const float* Wv    = (const float*)d_in[3];
  const float* Wo    = (const float*)d_in[4];
  const float* wA    = (const float*)d_in[5];
  const float* wB    = (const float*)d_in[6];
  const float* convw = (const float*)d_in[7];
  const float* bw    = (const float*)d_in[8];
  const float* gw    = (const float*)d_in[9];
  const float* gb    = (const float*)d_in[10];
  const float* qnw   = (const float*)d_in[11];
  const float* knw   = (const float*)d_in[12];

  const size_t N1 = (size_t)BT_ * D_;          // 1,048,576
  const size_t NTT = (size_t)BH_ * T_ * T_;    // 8,388,608
  float* ws = (float*)d_ws;
  float* wTb   = ws;                       // [BH,T,dh] fp32
  float* ycat  = wTb + N1;                 // [BT,64] fp32
  float* S     = ycat + (size_t)BT_ * 64;  // [BH,T,T] fp32 (P bf16 aliases rows)
  float* beta  = S + NTT;
  float* G     = beta + (size_t)BH_ * T_;
  float* vpart = G + (size_t)BH_ * T_;     // [3][1024][1024] fp32
  float* opart = vpart + 3 * N1;           // [3][1024][1024] fp32
  __hip_bfloat16* qb16  = (__hip_bfloat16*)(opart + 3 * N1);
  __hip_bfloat16* kb16  = qb16 + N1;
  __hip_bfloat16* wb16  = kb16 + N1;
  __hip_bfloat16* abT   = wb16 + N1;            // [BH,T(j),T(t)] bf16
  __hip_bfloat16* linvb = abT + NTT;            // [BH,8,64,64] bf16
  __hip_bfloat16* xhi   = linvb + (size_t)BH_ * 8 * 4096;
  __hip_bfloat16* xlo   = xhi + N1;
  __hip_bfloat16* obhi  = xlo + N1;
  __hip_bfloat16* oblo  = obhi + N1;
  __hip_bfloat16* woThi = oblo + N1;
  __hip_bfloat16* woTlo = woThi + N1;
  __hip_bfloat16* vhi   = woTlo + N1;           // [BH,dh,T] bf16
  __hip_bfloat16* vlo   = vhi + N1;
  __hip_bfloat16* wcThi = vlo + N1;             // [64][D]
  __hip_bfloat16* wcTlo = wcThi + (size_t)64 * D_;
  __hip_bfloat16* khat  = wcTlo + (size_t)64 * D_;  // [BH,8,T,dh] bf16 = 16.8 MB
  // fused QKV weight [3072][1024] hi/lo aliases S (S written later in stream order)
  __hip_bfloat16* wqkvThi = (__hip_bfloat16*)S;
  __hip_bfloat16* wqkvTlo = wqkvThi + (size_t)3072 * D_;
  __hip_bfloat16* wvThi = wqkvThi + (size_t)2048 * D_;
  __hip_bfloat16* wvTlo = wqkvTlo + (size_t)2048 * D_;

  dim3 g16(16, 16);
  split_f32<<<1024, 256, 0, stream>>>(x, xhi, xlo);
  splitT4_k<<<dim3(16, 16, 4), 256, 0, stream>>>(
      Wq, Wk, Wv, Wo,
      wqkvThi, wqkvTlo,
      wqkvThi + (size_t)1024 * D_, wqkvTlo + (size_t)1024 * D_,
      wvThi, wvTlo,
      woThi, woTlo);
  splitcat_k<<<64, 256, 0, stream>>>(wA, bw, gw, wcThi, wcTlo);
  gemm_ycat<<<dim3(1, 16), 256, 0, stream>>>(xhi, xlo, wcThi, wcTlo, ycat);
  // qk projection: 1-pass bf16 + fused rmsnorm -> qb16/kb16 (512 blocks)
  gemm_t<0><<<dim3(32, 16), 256, 0, stream>>>(xhi, nullptr, wqkvThi, nullptr,
                                              nullptr, qb16, kb16, qnw, knw);
  // V projection: 3 z-passes -> fp32 partials (768 blocks)
  gemm_t<1><<<dim3(16, 16, 3), 256, 0, stream>>>(xhi, xlo, wvThi, wvTlo,
                                                 vpart, nullptr, nullptr, nullptr, nullptr);
  combine_v<<<g16, 256, 0, stream>>>(vpart, vhi, vlo);
  gate_cumsum<<<BH_, 512, 0, stream>>>(ycat, gb, beta, G);
  wdir_k<<<BT_, 1024, 0, stream>>>(ycat, wB, convw, wTb, wb16);
  linv_k<<<dim3(8, BH_), 256, 0, stream>>>(wTb, beta, linvb);
  chain_k<<<dim3(8, BH_), 256, 0, stream>>>(kb16, wb16, linvb, beta, abT, khat);
  s_row<<<dim3(8, BH_), 256, 0, stream>>>(qb16, wb16, khat, abT, S);
  softmax_k<<<dim3(T_, BH_), 64, 0, stream>>>(S, G);
  pv_mfma<<<dim3(8, BH_), 256, 0, stream>>>((const __hip_bfloat16*)S, vhi, vlo, obhi, oblo);
  // output projection: 3 z-passes -> fp32 partials (768 blocks), then sum -> d_out
  gemm_t<1><<<dim3(16, 16, 3), 256, 0, stream>>>(obhi, oblo, woThi, woTlo,
                                                 opart, nullptr, nullptr, nullptr, nullptr);
  combine_o<<<1024, 256, 0, stream>>>(opart, (float*)d_out);
}

// Round 9
// 179.294 us; speedup vs baseline: 1.7188x; 1.0666x over previous
//
#include <hip/hip_runtime.h>
#include <hip/hip_bf16.h>
#include <math.h>

#define B_ 2
#define T_ 512
#define D_ 1024
#define H_ 16
#define R_ 32
#define DH 64
#define BT_ (B_*T_)
#define BH_ (B_*H_)

typedef __attribute__((ext_vector_type(8))) short bf16x8;
typedef __attribute__((ext_vector_type(4))) short s16x4;
typedef __attribute__((ext_vector_type(4))) float f32x4;

#define MFMA_BF16(a, b, c) __builtin_amdgcn_mfma_f32_16x16x32_bf16(a, b, c, 0, 0, 0)

static __device__ __forceinline__ short bf16s(float v) {
  __hip_bfloat16 b = __float2bfloat16(v);
  return *reinterpret_cast<short*>(&b);
}
static __device__ __forceinline__ float b2f(short s) {
  __hip_bfloat16 h; *reinterpret_cast<short*>(&h) = s; return __bfloat162float(h);
}

// ---- shared MFMA helpers ([72] pad = 144B stride, conflict-free) ----
__device__ __forceinline__ bf16x8 ldfrag(const __hip_bfloat16 s[][72], int b16, int kb, int fr, int kq) {
  return *(const bf16x8*)&s[b16 * 16 + fr][kb * 32 + kq * 8];
}
__device__ __forceinline__ void stage64(const __hip_bfloat16* __restrict__ g, int ldg,
                                        __hip_bfloat16 s[][72], int tid) {
#pragma unroll
  for (int l = 0; l < 2; ++l) {
    int f = tid + l * 256;
    int r = f >> 3, c = (f & 7) << 3;
    *(int4*)&s[r][c] = *(const int4*)&g[(size_t)r * ldg + c];
  }
}

// ---- global_load_lds 16B direct-to-LDS ----
typedef const __attribute__((address_space(1))) void* as1cv;
typedef __attribute__((address_space(3))) void* as3v;
__device__ __forceinline__ void gl16(const __hip_bfloat16* g, __hip_bfloat16* l) {
  __builtin_amdgcn_global_load_lds((as1cv)g, (as3v)l, 16, 0, 0);
}

// ======================= split fp32 -> bf16 hi/lo =======================
__global__ __launch_bounds__(256) void split_f32(const float* __restrict__ in,
                                                 __hip_bfloat16* __restrict__ hi,
                                                 __hip_bfloat16* __restrict__ lo) {
  int i4 = blockIdx.x * 256 + threadIdx.x;
  float4 v = ((const float4*)in)[i4];
  s16x4 ph, pl;
  float c[4] = {v.x, v.y, v.z, v.w};
#pragma unroll
  for (int u = 0; u < 4; ++u) {
    __hip_bfloat16 h = __float2bfloat16(c[u]);
    ph[u] = *reinterpret_cast<short*>(&h);
    pl[u] = bf16s(c[u] - __bfloat162float(h));
  }
  ((s16x4*)hi)[i4] = ph;
  ((s16x4*)lo)[i4] = pl;
}

// ======================= transpose + split 4 weights (z-select) =======================
// z=0 (Wq), z=1 (Wk): hi only (1-pass bf16 consumers). z=2 (Wv), z=3 (Wo): hi+lo.
__global__ __launch_bounds__(256) void splitT4_k(const float* __restrict__ W0,
                                                 const float* __restrict__ W1,
                                                 const float* __restrict__ W2,
                                                 const float* __restrict__ W3,
                                                 __hip_bfloat16* __restrict__ t0h, __hip_bfloat16* __restrict__ t0l,
                                                 __hip_bfloat16* __restrict__ t1h, __hip_bfloat16* __restrict__ t1l,
                                                 __hip_bfloat16* __restrict__ t2h, __hip_bfloat16* __restrict__ t2l,
                                                 __hip_bfloat16* __restrict__ t3h, __hip_bfloat16* __restrict__ t3l) {
  __shared__ float tile[64][65];
  const int z = blockIdx.z;
  const float* Wm = (z == 0) ? W0 : (z == 1) ? W1 : (z == 2) ? W2 : W3;
  __hip_bfloat16* thi = (z == 0) ? t0h : (z == 1) ? t1h : (z == 2) ? t2h : t3h;
  __hip_bfloat16* tlo = (z == 0) ? t0l : (z == 1) ? t1l : (z == 2) ? t2l : t3l;
  const bool wantlo = (z >= 2);
  const int bn = blockIdx.x * 64, bk = blockIdx.y * 64;
  const int tid = threadIdx.x;
#pragma unroll
  for (int l = 0; l < 4; ++l) {
    int f = tid + l * 256; int r = f >> 4, c = (f & 15) << 2;
    *(float4*)&tile[r][c] = *(const float4*)&Wm[(size_t)(bk + r) * D_ + bn + c];
  }
  __syncthreads();
#pragma unroll
  for (int l = 0; l < 4; ++l) {
    int f = tid + l * 256; int n = f >> 4, k0 = (f & 15) << 2;
    s16x4 ph, pl;
#pragma unroll
    for (int u = 0; u < 4; ++u) {
      float v = tile[k0 + u][n];
      __hip_bfloat16 h = __float2bfloat16(v);
      ph[u] = *reinterpret_cast<short*>(&h);
      pl[u] = bf16s(v - __bfloat162float(h));
    }
    *(s16x4*)&thi[(size_t)(bn + n) * D_ + bk + k0] = ph;
    if (wantlo) *(s16x4*)&tlo[(size_t)(bn + n) * D_ + bk + k0] = pl;
  }
}

// ======================= concat+transpose+split small proj weights [wA|bw|gw] -> [64][D] ==
__global__ __launch_bounds__(256) void splitcat_k(const float* __restrict__ wA,
                                                  const float* __restrict__ bw,
                                                  const float* __restrict__ gw,
                                                  __hip_bfloat16* __restrict__ thi,
                                                  __hip_bfloat16* __restrict__ tlo) {
  int n = blockIdx.x;          // 0..63
  int tid = threadIdx.x;
  for (int k = tid; k < D_; k += 256) {
    float v;
    if (n < 32) v = wA[(size_t)k * R_ + n];
    else if (n < 48) v = bw[(size_t)k * H_ + (n - 32)];
    else v = gw[(size_t)k * H_ + (n - 48)];
    __hip_bfloat16 h = __float2bfloat16(v);
    thi[(size_t)n * D_ + k] = h;
    tlo[(size_t)n * D_ + k] = __float2bfloat16(v - __bfloat162float(h));
  }
}

// ======================= 64x64-tile GEMM, 4 waves (wave tile 16x64), K=1024 ============
// MODE 0: qk projection (1-pass bf16) with fused rmsnorm epilogue -> qb16/kb16.
// MODE 1: z-pass partial GEMM: z=0 ah*bh, z=1 al*bh, z=2 ah*bl -> C + z*1M fp32.
template<int MODE>
__global__ __launch_bounds__(256) void gemm_t(const __hip_bfloat16* __restrict__ ah,
                                              const __hip_bfloat16* __restrict__ al,
                                              const __hip_bfloat16* __restrict__ bh,
                                              const __hip_bfloat16* __restrict__ bl,
                                              float* __restrict__ Cbase,
                                              __hip_bfloat16* __restrict__ qb,
                                              __hip_bfloat16* __restrict__ kb,
                                              const float* __restrict__ qnw,
                                              const float* __restrict__ knw) {
  __shared__ __hip_bfloat16 As[64][64];
  __shared__ __hip_bfloat16 Bs[64][64];
  const int bm = blockIdx.y * 64, bn = blockIdx.x * 64;
  const int tid = threadIdx.x, w = tid >> 6, lane = tid & 63;
  const int fr = lane & 15, kq = lane >> 4;
  const __hip_bfloat16* a = ah;
  const __hip_bfloat16* b = bh;
  float* C = Cbase;
  if (MODE == 1) {
    int z = blockIdx.z;
    a = (z == 1) ? al : ah;
    b = (z == 2) ? bl : bh;
    C = Cbase + (size_t)z * (1u << 20);
  }
  const f32x4 zf = {0.f, 0.f, 0.f, 0.f};
  f32x4 acc[4] = {zf, zf, zf, zf};
  const __hip_bfloat16* ap = a + (size_t)bm * D_;
  const __hip_bfloat16* bp = b + (size_t)bn * D_;

  for (int t = 0; t < 16; ++t) {
    __syncthreads();
#pragma unroll
    for (int i = 0; i < 2; ++i) {
      int chunk = tid + i * 256;
      int row = chunk >> 3, c8 = (chunk & 7) ^ (row & 7);    // source pre-swizzle
      gl16(ap + (size_t)row * D_ + t * 64 + c8 * 8, &As[0][0] + chunk * 8);
      gl16(bp + (size_t)row * D_ + t * 64 + c8 * 8, &Bs[0][0] + chunk * 8);
    }
    __syncthreads();
    const int ra = w * 16 + fr, sa = ra & 7;
    bf16x8 a0 = *(const bf16x8*)&As[ra][(kq ^ sa) * 8];
    bf16x8 a1 = *(const bf16x8*)&As[ra][((kq + 4) ^ sa) * 8];
#pragma unroll
    for (int n = 0; n < 4; ++n) {
      int rb = n * 16 + fr, sb = rb & 7;
      bf16x8 b0 = *(const bf16x8*)&Bs[rb][(kq ^ sb) * 8];
      bf16x8 b1 = *(const bf16x8*)&Bs[rb][((kq + 4) ^ sb) * 8];
      acc[n] = MFMA_BF16(a0, b0, acc[n]);
      acc[n] = MFMA_BF16(a1, b1, acc[n]);
    }
  }

  if (MODE == 0) {
    float rs[4];
#pragma unroll
    for (int reg = 0; reg < 4; ++reg) {
      float s = 0.f;
#pragma unroll
      for (int n = 0; n < 4; ++n) s += acc[n][reg] * acc[n][reg];
#pragma unroll
      for (int mm = 1; mm <= 8; mm <<= 1) s += __shfl_xor(s, mm);
      rs[reg] = rsqrtf(s * (1.f / DH) + 1e-5f);
    }
    const bool isq = (bn < 1024);
    __hip_bfloat16* outp = isq ? qb : kb;
#pragma unroll
    for (int n = 0; n < 4; ++n) {
      int gn = bn + n * 16 + fr;
      int dd = gn & 63, h = (gn & 1023) >> 6;
      float nw = (isq ? qnw : knw)[dd];
#pragma unroll
      for (int reg = 0; reg < 4; ++reg) {
        int gm = bm + w * 16 + kq * 4 + reg;
        int bb = gm >> 9, tt = gm & 511;
        outp[(((size_t)(bb * H_ + h)) * T_ + tt) * DH + dd] =
            __float2bfloat16(acc[n][reg] * rs[reg] * nw);
      }
    }
  } else {
#pragma unroll
    for (int n = 0; n < 4; ++n) {
      int gn = bn + n * 16 + fr;
#pragma unroll
      for (int reg = 0; reg < 4; ++reg) {
        int gm = bm + w * 16 + kq * 4 + reg;
        C[(size_t)gm * D_ + gn] = acc[n][reg];
      }
    }
  }
}

// ======================= combine 3 V partials -> transposed hi/lo bf16 [BH,dh,T] ==========
__global__ __launch_bounds__(256) void combine_v(const float* __restrict__ p,
                                                 __hip_bfloat16* __restrict__ vhi,
                                                 __hip_bfloat16* __restrict__ vlo) {
  __shared__ float Ls[64][65];          // [n][m]
  const int n0 = blockIdx.x * 64, m0 = blockIdx.y * 64;
  const int tid = threadIdx.x;
#pragma unroll
  for (int l = 0; l < 4; ++l) {
    int f = tid + l * 256; int r = f >> 4, c = (f & 15) << 2;
    const float* pp = &p[(size_t)(m0 + r) * D_ + n0 + c];
    float4 v0 = *(const float4*)pp;
    float4 v1 = *(const float4*)(pp + (1u << 20));
    float4 v2 = *(const float4*)(pp + (2u << 20));
    Ls[c + 0][r] = v0.x + v1.x + v2.x;
    Ls[c + 1][r] = v0.y + v1.y + v2.y;
    Ls[c + 2][r] = v0.z + v1.z + v2.z;
    Ls[c + 3][r] = v0.w + v1.w + v2.w;
  }
  __syncthreads();
  const int bb = m0 >> 9, t0 = m0 & 511, h = n0 >> 6;
  const size_t base = (((size_t)(bb * H_ + h)) * DH) * T_ + t0;
#pragma unroll
  for (int l = 0; l < 2; ++l) {
    int f = tid + l * 256;
    int dd = f >> 3, tq = (f & 7) * 8;
    bf16x8 ph, pl;
#pragma unroll
    for (int u = 0; u < 8; ++u) {
      float v = Ls[dd][tq + u];
      __hip_bfloat16 hv = __float2bfloat16(v);
      ph[u] = *reinterpret_cast<short*>(&hv);
      pl[u] = bf16s(v - __bfloat162float(hv));
    }
    *(bf16x8*)&vhi[base + (size_t)dd * T_ + tq] = ph;
    *(bf16x8*)&vlo[base + (size_t)dd * T_ + tq] = pl;
  }
}

// ======================= combine 3 O partials -> d_out fp32 =======================
__global__ __launch_bounds__(256) void combine_o(const float* __restrict__ p,
                                                 float* __restrict__ out) {
  int i4 = blockIdx.x * 256 + threadIdx.x;
  const float4* p4 = (const float4*)p;
  float4 a = p4[i4], b = p4[i4 + (1u << 18)], c = p4[i4 + (2u << 18)];
  float4 r;
  r.x = a.x + b.x + c.x; r.y = a.y + b.y + c.y;
  r.z = a.z + b.z + c.z; r.w = a.w + b.w + c.w;
  ((float4*)out)[i4] = r;
}

// ======================= small GEMM for ycat (M=BT, N=64) via 3x bf16 MFMA ============
__global__ __launch_bounds__(256) void gemm_ycat(const __hip_bfloat16* __restrict__ ah,
                                                 const __hip_bfloat16* __restrict__ al,
                                                 const __hip_bfloat16* __restrict__ bh,
                                                 const __hip_bfloat16* __restrict__ bl,
                                                 float* __restrict__ C) {
  __shared__ __hip_bfloat16 Ah[64][72], Al[64][72], Bh[64][72], Bl[64][72];
  const int bm = blockIdx.y * 64;
  const int tid = threadIdx.x, w = tid >> 6, lane = tid & 63;
  const int fr = lane & 15, kq = lane >> 4;
  const f32x4 zf = {0.f, 0.f, 0.f, 0.f};
  f32x4 acc[4] = {zf, zf, zf, zf};
  for (int k0 = 0; k0 < D_; k0 += 64) {
    __syncthreads();
    stage64(ah + (size_t)bm * D_ + k0, D_, Ah, tid);
    stage64(al + (size_t)bm * D_ + k0, D_, Al, tid);
    stage64(bh + k0, D_, Bh, tid);
    stage64(bl + k0, D_, Bl, tid);
    __syncthreads();
    bf16x8 ah0 = ldfrag(Ah, w, 0, fr, kq), ah1 = ldfrag(Ah, w, 1, fr, kq);
    bf16x8 al0 = ldfrag(Al, w, 0, fr, kq), al1 = ldfrag(Al, w, 1, fr, kq);
#pragma unroll
    for (int nb = 0; nb < 4; ++nb) {
      bf16x8 b0 = ldfrag(Bh, nb, 0, fr, kq), b1 = ldfrag(Bh, nb, 1, fr, kq);
      bf16x8 c0 = ldfrag(Bl, nb, 0, fr, kq), c1 = ldfrag(Bl, nb, 1, fr, kq);
      acc[nb] = MFMA_BF16(ah0, b0, acc[nb]); acc[nb] = MFMA_BF16(ah1, b1, acc[nb]);
      acc[nb] = MFMA_BF16(ah0, c0, acc[nb]); acc[nb] = MFMA_BF16(ah1, c1, acc[nb]);
      acc[nb] = MFMA_BF16(al0, b0, acc[nb]); acc[nb] = MFMA_BF16(al1, b1, acc[nb]);
    }
  }
#pragma unroll
  for (int nb = 0; nb < 4; ++nb) {
    int n = nb * 16 + fr;
#pragma unroll
    for (int reg = 0; reg < 4; ++reg) {
      int m = bm + w * 16 + kq * 4 + reg;
      C[(size_t)m * 64 + n] = acc[nb][reg];
    }
  }
}

// ======================= gates: beta, logsigmoid + cumsum =======================
__global__ __launch_bounds__(512) void gate_cumsum(const float* __restrict__ ycat,
                                                   const float* __restrict__ gb,
                                                   float* __restrict__ beta,
                                                   float* __restrict__ G) {
  __shared__ float s[T_];
  int bh = blockIdx.x, b = bh >> 4, h = bh & 15, t = threadIdx.x;
  int bt = b * T_ + t;
  float by = ycat[(size_t)bt * 64 + 32 + h];
  beta[(size_t)bh * T_ + t] = 2.f / (1.f + expf(-by));
  float gy = ycat[(size_t)bt * 64 + 48 + h] + gb[h];
  s[t] = fminf(gy, 0.f) - log1pf(expf(-fabsf(gy)));
  __syncthreads();
  for (int off = 1; off < T_; off <<= 1) {
    float v = (t >= off) ? s[t - off] : 0.f;
    __syncthreads();
    s[t] += v;
    __syncthreads();
  }
  G[(size_t)bh * T_ + t] = s[t];
}

// ======================= w: low-rank expand + conv3 + silu + unit-normalize ===========
__global__ __launch_bounds__(1024) void wdir_k(const float* __restrict__ ycat,
                                               const float* __restrict__ wB,
                                               const float* __restrict__ convw,
                                               float* __restrict__ wT,
                                               __hip_bfloat16* __restrict__ wb16) {
  int bt = blockIdx.x, b = bt / T_, t = bt - b * T_;
  __shared__ float wl[3][R_];
  int tid = threadIdx.x;
  if (tid < 3 * R_) {
    int row = tid / R_, r = tid - row * R_;
    int ts = t - row;
    wl[row][r] = (ts >= 0) ? ycat[(size_t)(b * T_ + ts) * 64 + r] : 0.f;
  }
  __syncthreads();
  float f0 = 0.f, f1 = 0.f, f2 = 0.f;
  for (int r = 0; r < R_; ++r) {
    float wb = wB[(size_t)r * D_ + tid];
    f0 += wl[0][r] * wb; f1 += wl[1][r] * wb; f2 += wl[2][r] * wb;
  }
  float y = f2 * convw[tid * 3 + 0] + f1 * convw[tid * 3 + 1] + f0 * convw[tid * 3 + 2];
  float s = y / (1.f + expf(-y));                       // silu
  float ss = s * s;
#pragma unroll
  for (int m = 32; m >= 1; m >>= 1) ss += __shfl_xor(ss, m);
  float outv = s * rsqrtf(ss + 1e-12f);
  int h = tid >> 6, dd = tid & 63;
  size_t o = (((size_t)(b * H_ + h)) * T_ + t) * DH + dd;
  wT[o] = outv;
  wb16[o] = __float2bfloat16(outv);
}

// ======================= per-block unit-lower-triangular inverse =======================
__global__ __launch_bounds__(256) void linv_k(const float* __restrict__ wT,
                                              const float* __restrict__ beta,
                                              __hip_bfloat16* __restrict__ linv) {
  __shared__ float Wsh[64][68];
  __shared__ float Csh[64][65];
  __shared__ float Li[64][68];
  __shared__ float bI[64];
  const int I = blockIdx.x, bhx = blockIdx.y;
  const int tid = threadIdx.x;
#pragma unroll
  for (int l = 0; l < 4; ++l) {
    int f = tid + l * 256; int r = f >> 4, c = (f & 15) << 2;
    *(float4*)&Wsh[r][c] = *(const float4*)&wT[((size_t)bhx * T_ + I * 64 + r) * DH + c];
  }
  if (tid < 64) bI[tid] = beta[(size_t)bhx * T_ + I * 64 + tid];
#pragma unroll
  for (int l = 0; l < 16; ++l) {
    int e = tid + l * 256; int r = e >> 6, c = e & 63;
    Li[r][c] = (r == c) ? 1.f : 0.f;
  }
  __syncthreads();
  const int tm = (tid >> 4) << 2, tn = (tid & 15) << 2;
  float cc[4][4] = {};
  for (int dd = 0; dd < 64; ++dd) {
    float a0 = Wsh[tm + 0][dd], a1 = Wsh[tm + 1][dd], a2 = Wsh[tm + 2][dd], a3 = Wsh[tm + 3][dd];
    float b0 = Wsh[tn + 0][dd], b1 = Wsh[tn + 1][dd], b2 = Wsh[tn + 2][dd], b3 = Wsh[tn + 3][dd];
    cc[0][0] += a0 * b0; cc[0][1] += a0 * b1; cc[0][2] += a0 * b2; cc[0][3] += a0 * b3;
    cc[1][0] += a1 * b0; cc[1][1] += a1 * b1; cc[1][2] += a1 * b2; cc[1][3] += a1 * b3;
    cc[2][0] += a2 * b0; cc[2][1] += a2 * b1; cc[2][2] += a2 * b2; cc[2][3] += a2 * b3;
    cc[3][0] += a3 * b0; cc[3][1] += a3 * b1; cc[3][2] += a3 * b2; cc[3][3] += a3 * b3;
  }
#pragma unroll
  for (int ii = 0; ii < 4; ++ii)
#pragma unroll
    for (int jj = 0; jj < 4; ++jj)
      Csh[tm + ii][tn + jj] = (tm + ii > tn + jj) ? cc[ii][jj] * bI[tn + jj] : 0.f;
  __syncthreads();
  const int sL = tid & 63, g = tid >> 6;
  for (int r = 0; r < 63; ++r) {
    float lr = Li[r][sL];
    for (int r2 = r + 1 + g; r2 < 64; r2 += 4)
      Li[r2][sL] -= Csh[r2][r] * lr;
    __syncthreads();
  }
#pragma unroll
  for (int l = 0; l < 4; ++l) {
    int f = tid + l * 256; int r = f >> 4, c0 = (f & 15) << 2;
    s16x4 p;
    p.x = bf16s(Li[r][c0 + 0]); p.y = bf16s(Li[r][c0 + 1]);
    p.z = bf16s(Li[r][c0 + 2]); p.w = bf16s(Li[r][c0 + 3]);
    *(s16x4*)&linv[((size_t)(bhx * 8 + I)) * 4096 + r * 64 + c0] = p;
  }
}

// ======================= WY chain + khat checkpoints =======================
__global__ __launch_bounds__(256) void chain_k(const __hip_bfloat16* __restrict__ kb,
                                               const __hip_bfloat16* __restrict__ wb,
                                               const __hip_bfloat16* __restrict__ linv,
                                               const float* __restrict__ beta,
                                               __hip_bfloat16* __restrict__ abT,
                                               __hip_bfloat16* __restrict__ khat) {
  __shared__ __hip_bfloat16 Kb[64][72];   // [j][d]
  __shared__ __hip_bfloat16 Ws[64][72];   // [t][d]
  __shared__ __hip_bfloat16 WsT[64][72];  // [d][t]
  __shared__ __hip_bfloat16 Ls[64][72];   // [t][s]
  __shared__ __hip_bfloat16 Mhi[64][72];  // [j][d] = -M hi
  __shared__ __hip_bfloat16 Mlo[64][72];  // [j][d] = -M lo
  __shared__ __hip_bfloat16 Ps[64][72];   // [j][t] PT, then reused as X
  __shared__ float bI[64];
  const int ch = blockIdx.x, bhx = blockIdx.y;
  const int tid = threadIdx.x, w = tid >> 6, lane = tid & 63;
  const int fr = lane & 15, kq = lane >> 4;
  const size_t hb = (size_t)bhx * T_;
  const f32x4 zf = {0.f, 0.f, 0.f, 0.f};

  stage64(kb + (hb + ch * 64) * DH, DH, Kb, tid);
  for (int f = tid; f < 576; f += 256) {
    ((int4*)Mhi)[f] = make_int4(0, 0, 0, 0);
    ((int4*)Mlo)[f] = make_int4(0, 0, 0, 0);
  }
  f32x4 macc[4] = {zf, zf, zf, zf};

  for (int I = ch; I < 8; ++I) {
    __syncthreads();                                           // B1
    stage64(wb + (hb + I * 64) * DH, DH, Ws, tid);
    stage64(linv + ((size_t)(bhx * 8 + I)) * 4096, 64, Ls, tid);
    if (tid < 64) bI[tid] = beta[hb + I * 64 + tid];
    const int jr = w * 16 + kq * 4;
    if (I > ch) {
#pragma unroll
      for (int nb = 0; nb < 4; ++nb) {
        int d = nb * 16 + fr;
#pragma unroll
        for (int reg = 0; reg < 4; ++reg) {
          float m = -macc[nb][reg];
          __hip_bfloat16 h = __float2bfloat16(m);
          Mhi[jr + reg][d] = h;
          Mlo[jr + reg][d] = __float2bfloat16(m - __bfloat162float(h));
        }
      }
    }
    __syncthreads();                                           // B2
    // khat checkpoint: khat^{(I)} = Kb + (-M)hi + (-M)lo
#pragma unroll
    for (int l = 0; l < 2; ++l) {
      int f = tid + l * 256;
      int r = f >> 3, c = (f & 7) << 3;
      bf16x8 kv = *(const bf16x8*)&Kb[r][c];
      bf16x8 mh = *(const bf16x8*)&Mhi[r][c];
      bf16x8 ml = *(const bf16x8*)&Mlo[r][c];
      bf16x8 o;
#pragma unroll
      for (int u = 0; u < 8; ++u) o[u] = bf16s(b2f(kv[u]) + b2f(mh[u]) + b2f(ml[u]));
      *(bf16x8*)&khat[(((size_t)(bhx * 8 + I)) * T_ + ch * 64 + r) * DH + c] = o;
    }
#pragma unroll
    for (int l = 0; l < 16; ++l) {
      int e = tid + l * 256;
      int t = e >> 6, d = e & 63;
      WsT[d][t] = Ws[t][d];
    }
    bf16x8 kb0 = ldfrag(Kb, w, 0, fr, kq), kb1 = ldfrag(Kb, w, 1, fr, kq);
    f32x4 pt[4];
#pragma unroll
    for (int nb = 0; nb < 4; ++nb) {
      bf16x8 b0 = ldfrag(Ws, nb, 0, fr, kq), b1 = ldfrag(Ws, nb, 1, fr, kq);
      pt[nb] = MFMA_BF16(kb0, b0, zf);
      pt[nb] = MFMA_BF16(kb1, b1, pt[nb]);
      if (I > ch) {
        bf16x8 mh0 = ldfrag(Mhi, w, 0, fr, kq), mh1 = ldfrag(Mhi, w, 1, fr, kq);
        bf16x8 ml0 = ldfrag(Mlo, w, 0, fr, kq), ml1 = ldfrag(Mlo, w, 1, fr, kq);
        pt[nb] = MFMA_BF16(mh0, b0, pt[nb]); pt[nb] = MFMA_BF16(mh1, b1, pt[nb]);
        pt[nb] = MFMA_BF16(ml0, b0, pt[nb]); pt[nb] = MFMA_BF16(ml1, b1, pt[nb]);
      }
    }
#pragma unroll
    for (int nb = 0; nb < 4; ++nb) {
      int t = nb * 16 + fr;
#pragma unroll
      for (int reg = 0; reg < 4; ++reg) {
        float v = pt[nb][reg];
        if (I == ch && t <= jr + reg) v = 0.f;
        Ps[jr + reg][t] = __float2bfloat16(v);
      }
    }
    __syncthreads();                                           // B3
    bf16x8 la0 = ldfrag(Ls, w, 0, fr, kq), la1 = ldfrag(Ls, w, 1, fr, kq);
    f32x4 av[4];
#pragma unroll
    for (int nb = 0; nb < 4; ++nb) {
      bf16x8 p0 = ldfrag(Ps, nb, 0, fr, kq), p1 = ldfrag(Ps, nb, 1, fr, kq);
      av[nb] = MFMA_BF16(la0, p0, zf);
      av[nb] = MFMA_BF16(la1, p1, av[nb]);
    }
    __syncthreads();                                           // B4
    const int tr = w * 16 + kq * 4;
#pragma unroll
    for (int nb = 0; nb < 4; ++nb) {
      s16x4 p;
      p.x = bf16s(bI[tr + 0] * av[nb][0]);
      p.y = bf16s(bI[tr + 1] * av[nb][1]);
      p.z = bf16s(bI[tr + 2] * av[nb][2]);
      p.w = bf16s(bI[tr + 3] * av[nb][3]);
      *(s16x4*)&Ps[nb * 16 + fr][tr] = p;
    }
    __syncthreads();                                           // B5
#pragma unroll
    for (int l = 0; l < 2; ++l) {
      int f = tid + l * 256;
      int r = f >> 3, c = (f & 7) << 3;
      *(int4*)&abT[(hb + ch * 64 + r) * T_ + I * 64 + c] = *(const int4*)&Ps[r][c];
    }
    bf16x8 xa0 = ldfrag(Ps, w, 0, fr, kq), xa1 = ldfrag(Ps, w, 1, fr, kq);
#pragma unroll
    for (int nb = 0; nb < 4; ++nb) {
      bf16x8 wt0 = ldfrag(WsT, nb, 0, fr, kq), wt1 = ldfrag(WsT, nb, 1, fr, kq);
      macc[nb] = MFMA_BF16(xa0, wt0, macc[nb]);
      macc[nb] = MFMA_BF16(xa1, wt1, macc[nb]);
    }
  }
}

// ======================= fused attention row-panel: S -> online softmax -> PV ==========
// grid (it=8, bh). Per jt-tile: S = Q khat^T + Ms @ Ab; logits + causal; online
// max/sum with O-rescale; P bf16 -> LDS; O += P V (hi+lo). Epilogue: O/l -> obhi/oblo.
__global__ __launch_bounds__(256) void attn_fused(const __hip_bfloat16* __restrict__ qb,
                                                  const __hip_bfloat16* __restrict__ wb,
                                                  const __hip_bfloat16* __restrict__ khat,
                                                  const __hip_bfloat16* __restrict__ abT,
                                                  const __hip_bfloat16* __restrict__ vhi,
                                                  const __hip_bfloat16* __restrict__ vlo,
                                                  const float* __restrict__ G,
                                                  __hip_bfloat16* __restrict__ ohi,
                                                  __hip_bfloat16* __restrict__ olo) {
  __shared__ __hip_bfloat16 Ms[64][72];   // masked -(Q W^T), persistent
  __shared__ __hip_bfloat16 Ks[64][72];   // khat tile [j][d] (init: Q)
  __shared__ __hip_bfloat16 Cs[64][72];   // abT tile [j][t]  (init: W)
  __shared__ __hip_bfloat16 Vh[64][72];   // V hi [dd][t]
  __shared__ __hip_bfloat16 Vl[64][72];   // V lo [dd][t]
  __shared__ __hip_bfloat16 Ps[64][72];   // P bf16 [i][t]
  const int it = blockIdx.x, bh = blockIdx.y;
  const int b = bh >> 4, h = bh & 15;
  const int tid = threadIdx.x, w = tid >> 6, lane = tid & 63;
  const int fr = lane & 15, kq = lane >> 4;
  const int row0 = w * 16 + kq * 4;
  const size_t hb = (size_t)bh * T_;
  const f32x4 zero = {0.f, 0.f, 0.f, 0.f};

  // init: Q, W -> Ms = masked -(Q W^T)
  stage64(qb + (hb + it * 64) * DH, DH, Ks, tid);
  stage64(wb + (hb + it * 64) * DH, DH, Cs, tid);
  __syncthreads();
  const bf16x8 a0 = ldfrag(Ks, w, 0, fr, kq);
  const bf16x8 a1 = ldfrag(Ks, w, 1, fr, kq);
  f32x4 qw[4];
#pragma unroll
  for (int nb = 0; nb < 4; ++nb) {
    qw[nb] = MFMA_BF16(a0, ldfrag(Cs, nb, 0, fr, kq), zero);
    qw[nb] = MFMA_BF16(a1, ldfrag(Cs, nb, 1, fr, kq), qw[nb]);
  }
#pragma unroll
  for (int nb = 0; nb < 4; ++nb) {
    int col = nb * 16 + fr;
#pragma unroll
    for (int reg = 0; reg < 4; ++reg) {
      float v = -qw[nb][reg];
      if (col > row0 + reg) v = 0.f;
      Ms[row0 + reg][col] = __float2bfloat16(v);
    }
  }
  __syncthreads();
  const bf16x8 m0 = ldfrag(Ms, w, 0, fr, kq);
  const bf16x8 m1 = ldfrag(Ms, w, 1, fr, kq);

  float Gi[4];
#pragma unroll
  for (int reg = 0; reg < 4; ++reg) Gi[reg] = G[hb + it * 64 + row0 + reg];
  float mrow[4] = {-3e38f, -3e38f, -3e38f, -3e38f};
  float lrow[4] = {0.f, 0.f, 0.f, 0.f};
  f32x4 acc_o[4] = {zero, zero, zero, zero};
  const __hip_bfloat16* kh = khat + ((size_t)(bh * 8 + it)) * T_ * DH;

  for (int jt = 0; jt <= it; ++jt) {
    __syncthreads();                       // prior iter's LDS reads done
    stage64(kh + (size_t)(jt * 64) * DH, DH, Ks, tid);
    stage64(abT + (hb + jt * 64) * T_ + it * 64, T_, Cs, tid);
    stage64(vhi + (size_t)bh * DH * T_ + jt * 64, T_, Vh, tid);
    stage64(vlo + (size_t)bh * DH * T_ + jt * 64, T_, Vl, tid);
    __syncthreads();                       // stages complete
    f32x4 acc[4];
#pragma unroll
    for (int nb = 0; nb < 4; ++nb) {
      acc[nb] = MFMA_BF16(a0, ldfrag(Ks, nb, 0, fr, kq), zero);
      acc[nb] = MFMA_BF16(a1, ldfrag(Ks, nb, 1, fr, kq), acc[nb]);
      acc[nb] = MFMA_BF16(m0, ldfrag(Cs, nb, 0, fr, kq), acc[nb]);
      acc[nb] = MFMA_BF16(m1, ldfrag(Cs, nb, 1, fr, kq), acc[nb]);
    }
    // logits + online softmax
    float gj[4];
#pragma unroll
    for (int nb = 0; nb < 4; ++nb) gj[nb] = G[hb + jt * 64 + nb * 16 + fr];
    const bool diag = (jt == it);
    float vv[4][4];
#pragma unroll
    for (int reg = 0; reg < 4; ++reg) {
      float tm = -3e38f;
#pragma unroll
      for (int nb = 0; nb < 4; ++nb) {
        float vx = acc[nb][reg] * 0.125f + Gi[reg] - gj[nb];
        if (diag && (nb * 16 + fr) > row0 + reg) vx = -3e38f;
        vv[nb][reg] = vx;
        tm = fmaxf(tm, vx);
      }
#pragma unroll
      for (int mm = 1; mm <= 8; mm <<= 1) tm = fmaxf(tm, __shfl_xor(tm, mm));
      float mnew = fmaxf(mrow[reg], tm);
      float sc = __expf(mrow[reg] - mnew);
      mrow[reg] = mnew;
      float tsum = 0.f;
#pragma unroll
      for (int nb = 0; nb < 4; ++nb) {
        float p = __expf(vv[nb][reg] - mnew);
        Ps[row0 + reg][nb * 16 + fr] = __float2bfloat16(p);
        tsum += p;
      }
#pragma unroll
      for (int mm = 1; mm <= 8; mm <<= 1) tsum += __shfl_xor(tsum, mm);
      lrow[reg] = lrow[reg] * sc + tsum;
#pragma unroll
      for (int nb = 0; nb < 4; ++nb) acc_o[nb][reg] *= sc;
    }
    __syncthreads();                       // Ps visible
    const bf16x8 p0 = ldfrag(Ps, w, 0, fr, kq);
    const bf16x8 p1 = ldfrag(Ps, w, 1, fr, kq);
#pragma unroll
    for (int nb = 0; nb < 4; ++nb) {
      acc_o[nb] = MFMA_BF16(p0, ldfrag(Vh, nb, 0, fr, kq), acc_o[nb]);
      acc_o[nb] = MFMA_BF16(p1, ldfrag(Vh, nb, 1, fr, kq), acc_o[nb]);
      acc_o[nb] = MFMA_BF16(p0, ldfrag(Vl, nb, 0, fr, kq), acc_o[nb]);
      acc_o[nb] = MFMA_BF16(p1, ldfrag(Vl, nb, 1, fr, kq), acc_o[nb]);
    }
  }
  // epilogue: normalize + hi/lo split write
#pragma unroll
  for (int reg = 0; reg < 4; ++reg) {
    float inv = 1.f / lrow[reg];
    int i = it * 64 + row0 + reg;
#pragma unroll
    for (int nb = 0; nb < 4; ++nb) {
      int dd = nb * 16 + fr;
      size_t oi = ((size_t)(b * T_ + i)) * D_ + h * 64 + dd;
      float v = acc_o[nb][reg] * inv;
      __hip_bfloat16 hv = __float2bfloat16(v);
      ohi[oi] = hv;
      olo[oi] = __float2bfloat16(v - __bfloat162float(hv));
    }
  }
}

// ======================= launch =======================
extern "C" void kernel_launch(void* const* d_in, const int* in_sizes, int n_in,
                              void* d_out, int out_size, void* d_ws, size_t ws_size,
                              hipStream_t stream) {
  (void)in_sizes; (void)n_in; (void)out_size; (void)ws_size;
  const float* x     = (const float*)d_in[0];
  const float* Wq    = (const float*)d_in[1];
  const float* Wk    = (const float*)d_in[2];
  const float* Wv    = (const float*)d_in[3];
  const float* Wo    = (const float*)d_in[4];
  const float* wA    = (const float*)d_in[5];
  const float* wB    = (const float*)d_in[6];
  const float* convw = (const float*)d_in[7];
  const float* bw    = (const float*)d_in[8];
  const float* gw    = (const float*)d_in[9];
  const float* gb    = (const float*)d_in[10];
  const float* qnw   = (const float*)d_in[11];
  const float* knw   = (const float*)d_in[12];

  const size_t N1 = (size_t)BT_ * D_;          // 1,048,576
  const size_t NTT = (size_t)BH_ * T_ * T_;    // 8,388,608
  float* ws = (float*)d_ws;
  float* wTb   = ws;                       // [BH,T,dh] fp32
  float* ycat  = wTb + N1;                 // [BT,64] fp32
  float* Wbuf  = ycat + (size_t)BT_ * 64;  // weight staging region (was S)
  float* beta  = Wbuf + NTT;
  float* G     = beta + (size_t)BH_ * T_;
  float* vpart = G + (size_t)BH_ * T_;     // [3][1024][1024] fp32
  float* opart = vpart + 3 * N1;           // [3][1024][1024] fp32
  __hip_bfloat16* qb16  = (__hip_bfloat16*)(opart + 3 * N1);
  __hip_bfloat16* kb16  = qb16 + N1;
  __hip_bfloat16* wb16  = kb16 + N1;
  __hip_bfloat16* abT   = wb16 + N1;            // [BH,T(j),T(t)] bf16
  __hip_bfloat16* linvb = abT + NTT;            // [BH,8,64,64] bf16
  __hip_bfloat16* xhi   = linvb + (size_t)BH_ * 8 * 4096;
  __hip_bfloat16* xlo   = xhi + N1;
  __hip_bfloat16* obhi  = xlo + N1;
  __hip_bfloat16* oblo  = obhi + N1;
  __hip_bfloat16* woThi = oblo + N1;
  __hip_bfloat16* woTlo = woThi + N1;
  __hip_bfloat16* vhi   = woTlo + N1;           // [BH,dh,T] bf16
  __hip_bfloat16* vlo   = vhi + N1;
  __hip_bfloat16* wcThi = vlo + N1;             // [64][D]
  __hip_bfloat16* wcTlo = wcThi + (size_t)64 * D_;
  __hip_bfloat16* khat  = wcTlo + (size_t)64 * D_;  // [BH,8,T,dh] bf16 = 16.8 MB
  // fused QKV weight [3072][1024] hi/lo in Wbuf region
  __hip_bfloat16* wqkvThi = (__hip_bfloat16*)Wbuf;
  __hip_bfloat16* wqkvTlo = wqkvThi + (size_t)3072 * D_;
  __hip_bfloat16* wvThi = wqkvThi + (size_t)2048 * D_;
  __hip_bfloat16* wvTlo = wqkvTlo + (size_t)2048 * D_;

  split_f32<<<1024, 256, 0, stream>>>(x, xhi, xlo);
  splitT4_k<<<dim3(16, 16, 4), 256, 0, stream>>>(
      Wq, Wk, Wv, Wo,
      wqkvThi, wqkvTlo,
      wqkvThi + (size_t)1024 * D_, wqkvTlo + (size_t)1024 * D_,
      wvThi, wvTlo,
      woThi, woTlo);
  splitcat_k<<<64, 256, 0, stream>>>(wA, bw, gw, wcThi, wcTlo);
  gemm_ycat<<<dim3(1, 16), 256, 0, stream>>>(xhi, xlo, wcThi, wcTlo, ycat);
  // qk projection: 1-pass bf16 + fused rmsnorm -> qb16/kb16 (512 blocks)
  gemm_t<0><<<dim3(32, 16), 256, 0, stream>>>(xhi, nullptr, wqkvThi, nullptr,
                                              nullptr, qb16, kb16, qnw, knw);
  // V projection: 3 z-passes -> fp32 partials (768 blocks)
  gemm_t<1><<<dim3(16, 16, 3), 256, 0, stream>>>(xhi, xlo, wvThi, wvTlo,
                                                 vpart, nullptr, nullptr, nullptr, nullptr);
  combine_v<<<dim3(16, 16), 256, 0, stream>>>(vpart, vhi, vlo);
  gate_cumsum<<<BH_, 512, 0, stream>>>(ycat, gb, beta, G);
  wdir_k<<<BT_, 1024, 0, stream>>>(ycat, wB, convw, wTb, wb16);
  linv_k<<<dim3(8, BH_), 256, 0, stream>>>(wTb, beta, linvb);
  chain_k<<<dim3(8, BH_), 256, 0, stream>>>(kb16, wb16, linvb, beta, abT, khat);
  attn_fused<<<dim3(8, BH_), 256, 0, stream>>>(qb16, wb16, khat, abT, vhi, vlo, G, obhi, oblo);
  // output projection: 3 z-passes -> fp32 partials (768 blocks), then sum -> d_out
  gemm_t<1><<<dim3(16, 16, 3), 256, 0, stream>>>(obhi, oblo, woThi, woTlo,
                                                 opart, nullptr, nullptr, nullptr, nullptr);
  combine_o<<<1024, 256, 0, stream>>>(opart, (float*)d_out);
}

// Round 10
// 163.730 us; speedup vs baseline: 1.8821x; 1.0951x over previous
//
#include <hip/hip_runtime.h>
#include <hip/hip_bf16.h>
#include <math.h>

#define B_ 2
#define T_ 512
#define D_ 1024
#define H_ 16
#define R_ 32
#define DH 64
#define BT_ (B_*T_)
#define BH_ (B_*H_)

typedef __attribute__((ext_vector_type(8))) short bf16x8;
typedef __attribute__((ext_vector_type(4))) short s16x4;
typedef __attribute__((ext_vector_type(4))) float f32x4;

#define MFMA_BF16(a, b, c) __builtin_amdgcn_mfma_f32_16x16x32_bf16(a, b, c, 0, 0, 0)

static __device__ __forceinline__ short bf16s(float v) {
  __hip_bfloat16 b = __float2bfloat16(v);
  return *reinterpret_cast<short*>(&b);
}
static __device__ __forceinline__ float b2f(short s) {
  __hip_bfloat16 h; *reinterpret_cast<short*>(&h) = s; return __bfloat162float(h);
}

// ---- shared MFMA helpers ([72] pad = 144B stride, conflict-free) ----
__device__ __forceinline__ bf16x8 ldfrag(const __hip_bfloat16 s[][72], int b16, int kb, int fr, int kq) {
  return *(const bf16x8*)&s[b16 * 16 + fr][kb * 32 + kq * 8];
}
__device__ __forceinline__ void stage64(const __hip_bfloat16* __restrict__ g, int ldg,
                                        __hip_bfloat16 s[][72], int tid) {
#pragma unroll
  for (int l = 0; l < 2; ++l) {
    int f = tid + l * 256;
    int r = f >> 3, c = (f & 7) << 3;
    *(int4*)&s[r][c] = *(const int4*)&g[(size_t)r * ldg + c];
  }
}

// ---- global_load_lds 16B direct-to-LDS ----
typedef const __attribute__((address_space(1))) void* as1cv;
typedef __attribute__((address_space(3))) void* as3v;
__device__ __forceinline__ void gl16(const __hip_bfloat16* g, __hip_bfloat16* l) {
  __builtin_amdgcn_global_load_lds((as1cv)g, (as3v)l, 16, 0, 0);
}

// ======================= split fp32 -> bf16 hi/lo =======================
__global__ __launch_bounds__(256) void split_f32(const float* __restrict__ in,
                                                 __hip_bfloat16* __restrict__ hi,
                                                 __hip_bfloat16* __restrict__ lo) {
  int i4 = blockIdx.x * 256 + threadIdx.x;
  float4 v = ((const float4*)in)[i4];
  s16x4 ph, pl;
  float c[4] = {v.x, v.y, v.z, v.w};
#pragma unroll
  for (int u = 0; u < 4; ++u) {
    __hip_bfloat16 h = __float2bfloat16(c[u]);
    ph[u] = *reinterpret_cast<short*>(&h);
    pl[u] = bf16s(c[u] - __bfloat162float(h));
  }
  ((s16x4*)hi)[i4] = ph;
  ((s16x4*)lo)[i4] = pl;
}

// ======================= transpose 4 weights -> bf16 hi only [N][K] =======================
__global__ __launch_bounds__(256) void splitT4_k(const float* __restrict__ W0,
                                                 const float* __restrict__ W1,
                                                 const float* __restrict__ W2,
                                                 const float* __restrict__ W3,
                                                 __hip_bfloat16* __restrict__ t0h,
                                                 __hip_bfloat16* __restrict__ t1h,
                                                 __hip_bfloat16* __restrict__ t2h,
                                                 __hip_bfloat16* __restrict__ t3h) {
  __shared__ float tile[64][65];
  const int z = blockIdx.z;
  const float* Wm = (z == 0) ? W0 : (z == 1) ? W1 : (z == 2) ? W2 : W3;
  __hip_bfloat16* thi = (z == 0) ? t0h : (z == 1) ? t1h : (z == 2) ? t2h : t3h;
  const int bn = blockIdx.x * 64, bk = blockIdx.y * 64;
  const int tid = threadIdx.x;
#pragma unroll
  for (int l = 0; l < 4; ++l) {
    int f = tid + l * 256; int r = f >> 4, c = (f & 15) << 2;
    *(float4*)&tile[r][c] = *(const float4*)&Wm[(size_t)(bk + r) * D_ + bn + c];
  }
  __syncthreads();
#pragma unroll
  for (int l = 0; l < 4; ++l) {
    int f = tid + l * 256; int n = f >> 4, k0 = (f & 15) << 2;
    s16x4 ph;
#pragma unroll
    for (int u = 0; u < 4; ++u) ph[u] = bf16s(tile[k0 + u][n]);
    *(s16x4*)&thi[(size_t)(bn + n) * D_ + bk + k0] = ph;
  }
}

// ======================= concat+transpose+split small proj weights [wA|bw|gw] -> [64][D] ==
__global__ __launch_bounds__(256) void splitcat_k(const float* __restrict__ wA,
                                                  const float* __restrict__ bw,
                                                  const float* __restrict__ gw,
                                                  __hip_bfloat16* __restrict__ thi,
                                                  __hip_bfloat16* __restrict__ tlo) {
  int n = blockIdx.x;          // 0..63
  int tid = threadIdx.x;
  for (int k = tid; k < D_; k += 256) {
    float v;
    if (n < 32) v = wA[(size_t)k * R_ + n];
    else if (n < 48) v = bw[(size_t)k * H_ + (n - 32)];
    else v = gw[(size_t)k * H_ + (n - 48)];
    __hip_bfloat16 h = __float2bfloat16(v);
    thi[(size_t)n * D_ + k] = h;
    tlo[(size_t)n * D_ + k] = __float2bfloat16(v - __bfloat162float(h));
  }
}

// ======================= 64x64-tile GEMM, 4 waves (wave tile 16x64), K=1024 ============
// MODE 0: qk projection (1-pass bf16) with fused rmsnorm epilogue -> qb16/kb16.
// MODE 1: 1-pass GEMM (z=0) -> C fp32 row-major [M][1024]. (used for Wo -> d_out)
template<int MODE>
__global__ __launch_bounds__(256) void gemm_t(const __hip_bfloat16* __restrict__ ah,
                                              const __hip_bfloat16* __restrict__ al,
                                              const __hip_bfloat16* __restrict__ bh,
                                              const __hip_bfloat16* __restrict__ bl,
                                              float* __restrict__ Cbase,
                                              __hip_bfloat16* __restrict__ qb,
                                              __hip_bfloat16* __restrict__ kb,
                                              const float* __restrict__ qnw,
                                              const float* __restrict__ knw) {
  __shared__ __hip_bfloat16 As[64][64];
  __shared__ __hip_bfloat16 Bs[64][64];
  const int bm = blockIdx.y * 64, bn = blockIdx.x * 64;
  const int tid = threadIdx.x, w = tid >> 6, lane = tid & 63;
  const int fr = lane & 15, kq = lane >> 4;
  const __hip_bfloat16* a = ah;
  const __hip_bfloat16* b = bh;
  float* C = Cbase;
  if (MODE == 1) {
    int z = blockIdx.z;
    a = (z == 1) ? al : ah;
    b = (z == 2) ? bl : bh;
    C = Cbase + (size_t)z * (1u << 20);
  }
  const f32x4 zf = {0.f, 0.f, 0.f, 0.f};
  f32x4 acc[4] = {zf, zf, zf, zf};
  const __hip_bfloat16* ap = a + (size_t)bm * D_;
  const __hip_bfloat16* bp = b + (size_t)bn * D_;

  for (int t = 0; t < 16; ++t) {
    __syncthreads();
#pragma unroll
    for (int i = 0; i < 2; ++i) {
      int chunk = tid + i * 256;
      int row = chunk >> 3, c8 = (chunk & 7) ^ (row & 7);    // source pre-swizzle
      gl16(ap + (size_t)row * D_ + t * 64 + c8 * 8, &As[0][0] + chunk * 8);
      gl16(bp + (size_t)row * D_ + t * 64 + c8 * 8, &Bs[0][0] + chunk * 8);
    }
    __syncthreads();
    const int ra = w * 16 + fr, sa = ra & 7;
    bf16x8 a0 = *(const bf16x8*)&As[ra][(kq ^ sa) * 8];
    bf16x8 a1 = *(const bf16x8*)&As[ra][((kq + 4) ^ sa) * 8];
#pragma unroll
    for (int n = 0; n < 4; ++n) {
      int rb = n * 16 + fr, sb = rb & 7;
      bf16x8 b0 = *(const bf16x8*)&Bs[rb][(kq ^ sb) * 8];
      bf16x8 b1 = *(const bf16x8*)&Bs[rb][((kq + 4) ^ sb) * 8];
      acc[n] = MFMA_BF16(a0, b0, acc[n]);
      acc[n] = MFMA_BF16(a1, b1, acc[n]);
    }
  }

  if (MODE == 0) {
    float rs[4];
#pragma unroll
    for (int reg = 0; reg < 4; ++reg) {
      float s = 0.f;
#pragma unroll
      for (int n = 0; n < 4; ++n) s += acc[n][reg] * acc[n][reg];
#pragma unroll
      for (int mm = 1; mm <= 8; mm <<= 1) s += __shfl_xor(s, mm);
      rs[reg] = rsqrtf(s * (1.f / DH) + 1e-5f);
    }
    const bool isq = (bn < 1024);
    __hip_bfloat16* outp = isq ? qb : kb;
#pragma unroll
    for (int n = 0; n < 4; ++n) {
      int gn = bn + n * 16 + fr;
      int dd = gn & 63, h = (gn & 1023) >> 6;
      float nw = (isq ? qnw : knw)[dd];
#pragma unroll
      for (int reg = 0; reg < 4; ++reg) {
        int gm = bm + w * 16 + kq * 4 + reg;
        int bb = gm >> 9, tt = gm & 511;
        outp[(((size_t)(bb * H_ + h)) * T_ + tt) * DH + dd] =
            __float2bfloat16(acc[n][reg] * rs[reg] * nw);
      }
    }
  } else {
#pragma unroll
    for (int n = 0; n < 4; ++n) {
      int gn = bn + n * 16 + fr;
#pragma unroll
      for (int reg = 0; reg < 4; ++reg) {
        int gm = bm + w * 16 + kq * 4 + reg;
        C[(size_t)gm * D_ + gn] = acc[n][reg];
      }
    }
  }
}

// ======================= V projection: 1-pass bf16, transposed epilogue -> vhi [BH,dh,T] ==
__global__ __launch_bounds__(256) void gemm_v(const __hip_bfloat16* __restrict__ ah,
                                              const __hip_bfloat16* __restrict__ bh,
                                              __hip_bfloat16* __restrict__ vhi) {
  __shared__ __hip_bfloat16 As[64][64];
  __shared__ __hip_bfloat16 Bs[64][64];
  __shared__ __hip_bfloat16 Lt[64][72];   // transpose staging [dd][t]
  const int bm = blockIdx.y * 64, bn = blockIdx.x * 64;
  const int tid = threadIdx.x, w = tid >> 6, lane = tid & 63;
  const int fr = lane & 15, kq = lane >> 4;
  const f32x4 zf = {0.f, 0.f, 0.f, 0.f};
  f32x4 acc[4] = {zf, zf, zf, zf};
  const __hip_bfloat16* ap = ah + (size_t)bm * D_;
  const __hip_bfloat16* bp = bh + (size_t)bn * D_;

  for (int t = 0; t < 16; ++t) {
    __syncthreads();
#pragma unroll
    for (int i = 0; i < 2; ++i) {
      int chunk = tid + i * 256;
      int row = chunk >> 3, c8 = (chunk & 7) ^ (row & 7);
      gl16(ap + (size_t)row * D_ + t * 64 + c8 * 8, &As[0][0] + chunk * 8);
      gl16(bp + (size_t)row * D_ + t * 64 + c8 * 8, &Bs[0][0] + chunk * 8);
    }
    __syncthreads();
    const int ra = w * 16 + fr, sa = ra & 7;
    bf16x8 a0 = *(const bf16x8*)&As[ra][(kq ^ sa) * 8];
    bf16x8 a1 = *(const bf16x8*)&As[ra][((kq + 4) ^ sa) * 8];
#pragma unroll
    for (int n = 0; n < 4; ++n) {
      int rb = n * 16 + fr, sb = rb & 7;
      bf16x8 b0 = *(const bf16x8*)&Bs[rb][(kq ^ sb) * 8];
      bf16x8 b1 = *(const bf16x8*)&Bs[rb][((kq + 4) ^ sb) * 8];
      acc[n] = MFMA_BF16(a0, b0, acc[n]);
      acc[n] = MFMA_BF16(a1, b1, acc[n]);
    }
  }
  // transpose via LDS: acc (t x dd) -> Lt[dd][t]
  const int row0 = w * 16 + kq * 4;
#pragma unroll
  for (int n = 0; n < 4; ++n) {
    int dd = n * 16 + fr;
#pragma unroll
    for (int reg = 0; reg < 4; ++reg) {
      Lt[dd][row0 + reg] = __float2bfloat16(acc[n][reg]);
    }
  }
  __syncthreads();
  const int b = bm >> 9, t0 = bm & 511, h = bn >> 6;
  const size_t base = ((size_t)(b * H_ + h)) * DH * T_;
#pragma unroll
  for (int l = 0; l < 2; ++l) {
    int f = tid + l * 256;
    int dd = f >> 3, tq = (f & 7) * 8;
    *(bf16x8*)&vhi[base + (size_t)dd * T_ + t0 + tq] = *(const bf16x8*)&Lt[dd][tq];
  }
}

// ======================= small GEMM for ycat (M=BT, N=64) via 3x bf16 MFMA ============
__global__ __launch_bounds__(256) void gemm_ycat(const __hip_bfloat16* __restrict__ ah,
                                                 const __hip_bfloat16* __restrict__ al,
                                                 const __hip_bfloat16* __restrict__ bh,
                                                 const __hip_bfloat16* __restrict__ bl,
                                                 float* __restrict__ C) {
  __shared__ __hip_bfloat16 Ah[64][72], Al[64][72], Bh[64][72], Bl[64][72];
  const int bm = blockIdx.y * 64;
  const int tid = threadIdx.x, w = tid >> 6, lane = tid & 63;
  const int fr = lane & 15, kq = lane >> 4;
  const f32x4 zf = {0.f, 0.f, 0.f, 0.f};
  f32x4 acc[4] = {zf, zf, zf, zf};
  for (int k0 = 0; k0 < D_; k0 += 64) {
    __syncthreads();
    stage64(ah + (size_t)bm * D_ + k0, D_, Ah, tid);
    stage64(al + (size_t)bm * D_ + k0, D_, Al, tid);
    stage64(bh + k0, D_, Bh, tid);
    stage64(bl + k0, D_, Bl, tid);
    __syncthreads();
    bf16x8 ah0 = ldfrag(Ah, w, 0, fr, kq), ah1 = ldfrag(Ah, w, 1, fr, kq);
    bf16x8 al0 = ldfrag(Al, w, 0, fr, kq), al1 = ldfrag(Al, w, 1, fr, kq);
#pragma unroll
    for (int nb = 0; nb < 4; ++nb) {
      bf16x8 b0 = ldfrag(Bh, nb, 0, fr, kq), b1 = ldfrag(Bh, nb, 1, fr, kq);
      bf16x8 c0 = ldfrag(Bl, nb, 0, fr, kq), c1 = ldfrag(Bl, nb, 1, fr, kq);
      acc[nb] = MFMA_BF16(ah0, b0, acc[nb]); acc[nb] = MFMA_BF16(ah1, b1, acc[nb]);
      acc[nb] = MFMA_BF16(ah0, c0, acc[nb]); acc[nb] = MFMA_BF16(ah1, c1, acc[nb]);
      acc[nb] = MFMA_BF16(al0, b0, acc[nb]); acc[nb] = MFMA_BF16(al1, b1, acc[nb]);
    }
  }
#pragma unroll
  for (int nb = 0; nb < 4; ++nb) {
    int n = nb * 16 + fr;
#pragma unroll
    for (int reg = 0; reg < 4; ++reg) {
      int m = bm + w * 16 + kq * 4 + reg;
      C[(size_t)m * 64 + n] = acc[nb][reg];
    }
  }
}

// ======================= gates: beta, logsigmoid + cumsum =======================
__global__ __launch_bounds__(512) void gate_cumsum(const float* __restrict__ ycat,
                                                   const float* __restrict__ gb,
                                                   float* __restrict__ beta,
                                                   float* __restrict__ G) {
  __shared__ float s[T_];
  int bh = blockIdx.x, b = bh >> 4, h = bh & 15, t = threadIdx.x;
  int bt = b * T_ + t;
  float by = ycat[(size_t)bt * 64 + 32 + h];
  beta[(size_t)bh * T_ + t] = 2.f / (1.f + expf(-by));
  float gy = ycat[(size_t)bt * 64 + 48 + h] + gb[h];
  s[t] = fminf(gy, 0.f) - log1pf(expf(-fabsf(gy)));
  __syncthreads();
  for (int off = 1; off < T_; off <<= 1) {
    float v = (t >= off) ? s[t - off] : 0.f;
    __syncthreads();
    s[t] += v;
    __syncthreads();
  }
  G[(size_t)bh * T_ + t] = s[t];
}

// ======================= w: low-rank expand + conv3 + silu + unit-normalize ===========
__global__ __launch_bounds__(1024) void wdir_k(const float* __restrict__ ycat,
                                               const float* __restrict__ wB,
                                               const float* __restrict__ convw,
                                               float* __restrict__ wT,
                                               __hip_bfloat16* __restrict__ wb16) {
  int bt = blockIdx.x, b = bt / T_, t = bt - b * T_;
  __shared__ float wl[3][R_];
  int tid = threadIdx.x;
  if (tid < 3 * R_) {
    int row = tid / R_, r = tid - row * R_;
    int ts = t - row;
    wl[row][r] = (ts >= 0) ? ycat[(size_t)(b * T_ + ts) * 64 + r] : 0.f;
  }
  __syncthreads();
  float f0 = 0.f, f1 = 0.f, f2 = 0.f;
  for (int r = 0; r < R_; ++r) {
    float wb = wB[(size_t)r * D_ + tid];
    f0 += wl[0][r] * wb; f1 += wl[1][r] * wb; f2 += wl[2][r] * wb;
  }
  float y = f2 * convw[tid * 3 + 0] + f1 * convw[tid * 3 + 1] + f0 * convw[tid * 3 + 2];
  float s = y / (1.f + expf(-y));                       // silu
  float ss = s * s;
#pragma unroll
  for (int m = 32; m >= 1; m >>= 1) ss += __shfl_xor(ss, m);
  float outv = s * rsqrtf(ss + 1e-12f);
  int h = tid >> 6, dd = tid & 63;
  size_t o = (((size_t)(b * H_ + h)) * T_ + t) * DH + dd;
  wT[o] = outv;
  wb16[o] = __float2bfloat16(outv);
}

// ======================= per-block unit-lower-triangular inverse =======================
__global__ __launch_bounds__(256) void linv_k(const float* __restrict__ wT,
                                              const float* __restrict__ beta,
                                              __hip_bfloat16* __restrict__ linv) {
  __shared__ float Wsh[64][68];
  __shared__ float Csh[64][65];
  __shared__ float Li[64][68];
  __shared__ float bI[64];
  const int I = blockIdx.x, bhx = blockIdx.y;
  const int tid = threadIdx.x;
#pragma unroll
  for (int l = 0; l < 4; ++l) {
    int f = tid + l * 256; int r = f >> 4, c = (f & 15) << 2;
    *(float4*)&Wsh[r][c] = *(const float4*)&wT[((size_t)bhx * T_ + I * 64 + r) * DH + c];
  }
  if (tid < 64) bI[tid] = beta[(size_t)bhx * T_ + I * 64 + tid];
#pragma unroll
  for (int l = 0; l < 16; ++l) {
    int e = tid + l * 256; int r = e >> 6, c = e & 63;
    Li[r][c] = (r == c) ? 1.f : 0.f;
  }
  __syncthreads();
  const int tm = (tid >> 4) << 2, tn = (tid & 15) << 2;
  float cc[4][4] = {};
  for (int dd = 0; dd < 64; ++dd) {
    float a0 = Wsh[tm + 0][dd], a1 = Wsh[tm + 1][dd], a2 = Wsh[tm + 2][dd], a3 = Wsh[tm + 3][dd];
    float b0 = Wsh[tn + 0][dd], b1 = Wsh[tn + 1][dd], b2 = Wsh[tn + 2][dd], b3 = Wsh[tn + 3][dd];
    cc[0][0] += a0 * b0; cc[0][1] += a0 * b1; cc[0][2] += a0 * b2; cc[0][3] += a0 * b3;
    cc[1][0] += a1 * b0; cc[1][1] += a1 * b1; cc[1][2] += a1 * b2; cc[1][3] += a1 * b3;
    cc[2][0] += a2 * b0; cc[2][1] += a2 * b1; cc[2][2] += a2 * b2; cc[2][3] += a2 * b3;
    cc[3][0] += a3 * b0; cc[3][1] += a3 * b1; cc[3][2] += a3 * b2; cc[3][3] += a3 * b3;
  }
#pragma unroll
  for (int ii = 0; ii < 4; ++ii)
#pragma unroll
    for (int jj = 0; jj < 4; ++jj)
      Csh[tm + ii][tn + jj] = (tm + ii > tn + jj) ? cc[ii][jj] * bI[tn + jj] : 0.f;
  __syncthreads();
  const int sL = tid & 63, g = tid >> 6;
  for (int r = 0; r < 63; ++r) {
    float lr = Li[r][sL];
    for (int r2 = r + 1 + g; r2 < 64; r2 += 4)
      Li[r2][sL] -= Csh[r2][r] * lr;
    __syncthreads();
  }
#pragma unroll
  for (int l = 0; l < 4; ++l) {
    int f = tid + l * 256; int r = f >> 4, c0 = (f & 15) << 2;
    s16x4 p;
    p.x = bf16s(Li[r][c0 + 0]); p.y = bf16s(Li[r][c0 + 1]);
    p.z = bf16s(Li[r][c0 + 2]); p.w = bf16s(Li[r][c0 + 3]);
    *(s16x4*)&linv[((size_t)(bhx * 8 + I)) * 4096 + r * 64 + c0] = p;
  }
}

// ======================= WY chain + khat checkpoints =======================
__global__ __launch_bounds__(256) void chain_k(const __hip_bfloat16* __restrict__ kb,
                                               const __hip_bfloat16* __restrict__ wb,
                                               const __hip_bfloat16* __restrict__ linv,
                                               const float* __restrict__ beta,
                                               __hip_bfloat16* __restrict__ abT,
                                               __hip_bfloat16* __restrict__ khat) {
  __shared__ __hip_bfloat16 Kb[64][72];   // [j][d]
  __shared__ __hip_bfloat16 Ws[64][72];   // [t][d]
  __shared__ __hip_bfloat16 WsT[64][72];  // [d][t]
  __shared__ __hip_bfloat16 Ls[64][72];   // [t][s]
  __shared__ __hip_bfloat16 Mhi[64][72];  // [j][d] = -M hi
  __shared__ __hip_bfloat16 Mlo[64][72];  // [j][d] = -M lo
  __shared__ __hip_bfloat16 Ps[64][72];   // [j][t] PT, then reused as X
  __shared__ float bI[64];
  const int ch = blockIdx.x, bhx = blockIdx.y;
  const int tid = threadIdx.x, w = tid >> 6, lane = tid & 63;
  const int fr = lane & 15, kq = lane >> 4;
  const size_t hb = (size_t)bhx * T_;
  const f32x4 zf = {0.f, 0.f, 0.f, 0.f};

  stage64(kb + (hb + ch * 64) * DH, DH, Kb, tid);
  for (int f = tid; f < 576; f += 256) {
    ((int4*)Mhi)[f] = make_int4(0, 0, 0, 0);
    ((int4*)Mlo)[f] = make_int4(0, 0, 0, 0);
  }
  f32x4 macc[4] = {zf, zf, zf, zf};

  for (int I = ch; I < 8; ++I) {
    __syncthreads();                                           // B1
    stage64(wb + (hb + I * 64) * DH, DH, Ws, tid);
    stage64(linv + ((size_t)(bhx * 8 + I)) * 4096, 64, Ls, tid);
    if (tid < 64) bI[tid] = beta[hb + I * 64 + tid];
    const int jr = w * 16 + kq * 4;
    if (I > ch) {
#pragma unroll
      for (int nb = 0; nb < 4; ++nb) {
        int d = nb * 16 + fr;
#pragma unroll
        for (int reg = 0; reg < 4; ++reg) {
          float m = -macc[nb][reg];
          __hip_bfloat16 h = __float2bfloat16(m);
          Mhi[jr + reg][d] = h;
          Mlo[jr + reg][d] = __float2bfloat16(m - __bfloat162float(h));
        }
      }
    }
    __syncthreads();                                           // B2
    // khat checkpoint: khat^{(I)} = Kb + (-M)hi + (-M)lo
#pragma unroll
    for (int l = 0; l < 2; ++l) {
      int f = tid + l * 256;
      int r = f >> 3, c = (f & 7) << 3;
      bf16x8 kv = *(const bf16x8*)&Kb[r][c];
      bf16x8 mh = *(const bf16x8*)&Mhi[r][c];
      bf16x8 ml = *(const bf16x8*)&Mlo[r][c];
      bf16x8 o;
#pragma unroll
      for (int u = 0; u < 8; ++u) o[u] = bf16s(b2f(kv[u]) + b2f(mh[u]) + b2f(ml[u]));
      *(bf16x8*)&khat[(((size_t)(bhx * 8 + I)) * T_ + ch * 64 + r) * DH + c] = o;
    }
#pragma unroll
    for (int l = 0; l < 16; ++l) {
      int e = tid + l * 256;
      int t = e >> 6, d = e & 63;
      WsT[d][t] = Ws[t][d];
    }
    bf16x8 kb0 = ldfrag(Kb, w, 0, fr, kq), kb1 = ldfrag(Kb, w, 1, fr, kq);
    f32x4 pt[4];
#pragma unroll
    for (int nb = 0; nb < 4; ++nb) {
      bf16x8 b0 = ldfrag(Ws, nb, 0, fr, kq), b1 = ldfrag(Ws, nb, 1, fr, kq);
      pt[nb] = MFMA_BF16(kb0, b0, zf);
      pt[nb] = MFMA_BF16(kb1, b1, pt[nb]);
      if (I > ch) {
        bf16x8 mh0 = ldfrag(Mhi, w, 0, fr, kq), mh1 = ldfrag(Mhi, w, 1, fr, kq);
        bf16x8 ml0 = ldfrag(Mlo, w, 0, fr, kq), ml1 = ldfrag(Mlo, w, 1, fr, kq);
        pt[nb] = MFMA_BF16(mh0, b0, pt[nb]); pt[nb] = MFMA_BF16(mh1, b1, pt[nb]);
        pt[nb] = MFMA_BF16(ml0, b0, pt[nb]); pt[nb] = MFMA_BF16(ml1, b1, pt[nb]);
      }
    }
#pragma unroll
    for (int nb = 0; nb < 4; ++nb) {
      int t = nb * 16 + fr;
#pragma unroll
      for (int reg = 0; reg < 4; ++reg) {
        float v = pt[nb][reg];
        if (I == ch && t <= jr + reg) v = 0.f;
        Ps[jr + reg][t] = __float2bfloat16(v);
      }
    }
    __syncthreads();                                           // B3
    bf16x8 la0 = ldfrag(Ls, w, 0, fr, kq), la1 = ldfrag(Ls, w, 1, fr, kq);
    f32x4 av[4];
#pragma unroll
    for (int nb = 0; nb < 4; ++nb) {
      bf16x8 p0 = ldfrag(Ps, nb, 0, fr, kq), p1 = ldfrag(Ps, nb, 1, fr, kq);
      av[nb] = MFMA_BF16(la0, p0, zf);
      av[nb] = MFMA_BF16(la1, p1, av[nb]);
    }
    __syncthreads();                                           // B4
    const int tr = w * 16 + kq * 4;
#pragma unroll
    for (int nb = 0; nb < 4; ++nb) {
      s16x4 p;
      p.x = bf16s(bI[tr + 0] * av[nb][0]);
      p.y = bf16s(bI[tr + 1] * av[nb][1]);
      p.z = bf16s(bI[tr + 2] * av[nb][2]);
      p.w = bf16s(bI[tr + 3] * av[nb][3]);
      *(s16x4*)&Ps[nb * 16 + fr][tr] = p;
    }
    __syncthreads();                                           // B5
#pragma unroll
    for (int l = 0; l < 2; ++l) {
      int f = tid + l * 256;
      int r = f >> 3, c = (f & 7) << 3;
      *(int4*)&abT[(hb + ch * 64 + r) * T_ + I * 64 + c] = *(const int4*)&Ps[r][c];
    }
    bf16x8 xa0 = ldfrag(Ps, w, 0, fr, kq), xa1 = ldfrag(Ps, w, 1, fr, kq);
#pragma unroll
    for (int nb = 0; nb < 4; ++nb) {
      bf16x8 wt0 = ldfrag(WsT, nb, 0, fr, kq), wt1 = ldfrag(WsT, nb, 1, fr, kq);
      macc[nb] = MFMA_BF16(xa0, wt0, macc[nb]);
      macc[nb] = MFMA_BF16(xa1, wt1, macc[nb]);
    }
  }
}

// ======================= fused attention row-panel: S -> online softmax -> PV ==========
__global__ __launch_bounds__(256) void attn_fused(const __hip_bfloat16* __restrict__ qb,
                                                  const __hip_bfloat16* __restrict__ wb,
                                                  const __hip_bfloat16* __restrict__ khat,
                                                  const __hip_bfloat16* __restrict__ abT,
                                                  const __hip_bfloat16* __restrict__ vhi,
                                                  const float* __restrict__ G,
                                                  __hip_bfloat16* __restrict__ ohi) {
  __shared__ __hip_bfloat16 Ms[64][72];   // masked -(Q W^T), persistent
  __shared__ __hip_bfloat16 Ks[64][72];   // khat tile [j][d] (init: Q)
  __shared__ __hip_bfloat16 Cs[64][72];   // abT tile [j][t]  (init: W)
  __shared__ __hip_bfloat16 Vh[64][72];   // V [dd][t]
  __shared__ __hip_bfloat16 Ps[64][72];   // P bf16 [i][t]
  const int it = blockIdx.x, bh = blockIdx.y;
  const int b = bh >> 4, h = bh & 15;
  const int tid = threadIdx.x, w = tid >> 6, lane = tid & 63;
  const int fr = lane & 15, kq = lane >> 4;
  const int row0 = w * 16 + kq * 4;
  const size_t hb = (size_t)bh * T_;
  const f32x4 zero = {0.f, 0.f, 0.f, 0.f};

  stage64(qb + (hb + it * 64) * DH, DH, Ks, tid);
  stage64(wb + (hb + it * 64) * DH, DH, Cs, tid);
  __syncthreads();
  const bf16x8 a0 = ldfrag(Ks, w, 0, fr, kq);
  const bf16x8 a1 = ldfrag(Ks, w, 1, fr, kq);
  f32x4 qw[4];
#pragma unroll
  for (int nb = 0; nb < 4; ++nb) {
    qw[nb] = MFMA_BF16(a0, ldfrag(Cs, nb, 0, fr, kq), zero);
    qw[nb] = MFMA_BF16(a1, ldfrag(Cs, nb, 1, fr, kq), qw[nb]);
  }
#pragma unroll
  for (int nb = 0; nb < 4; ++nb) {
    int col = nb * 16 + fr;
#pragma unroll
    for (int reg = 0; reg < 4; ++reg) {
      float v = -qw[nb][reg];
      if (col > row0 + reg) v = 0.f;
      Ms[row0 + reg][col] = __float2bfloat16(v);
    }
  }
  __syncthreads();
  const bf16x8 m0 = ldfrag(Ms, w, 0, fr, kq);
  const bf16x8 m1 = ldfrag(Ms, w, 1, fr, kq);

  float Gi[4];
#pragma unroll
  for (int reg = 0; reg < 4; ++reg) Gi[reg] = G[hb + it * 64 + row0 + reg];
  float mrow[4] = {-3e38f, -3e38f, -3e38f, -3e38f};
  float lrow[4] = {0.f, 0.f, 0.f, 0.f};
  f32x4 acc_o[4] = {zero, zero, zero, zero};
  const __hip_bfloat16* kh = khat + ((size_t)(bh * 8 + it)) * T_ * DH;

  for (int jt = 0; jt <= it; ++jt) {
    __syncthreads();
    stage64(kh + (size_t)(jt * 64) * DH, DH, Ks, tid);
    stage64(abT + (hb + jt * 64) * T_ + it * 64, T_, Cs, tid);
    stage64(vhi + (size_t)bh * DH * T_ + jt * 64, T_, Vh, tid);
    __syncthreads();
    f32x4 acc[4];
#pragma unroll
    for (int nb = 0; nb < 4; ++nb) {
      acc[nb] = MFMA_BF16(a0, ldfrag(Ks, nb, 0, fr, kq), zero);
      acc[nb] = MFMA_BF16(a1, ldfrag(Ks, nb, 1, fr, kq), acc[nb]);
      acc[nb] = MFMA_BF16(m0, ldfrag(Cs, nb, 0, fr, kq), acc[nb]);
      acc[nb] = MFMA_BF16(m1, ldfrag(Cs, nb, 1, fr, kq), acc[nb]);
    }
    float gj[4];
#pragma unroll
    for (int nb = 0; nb < 4; ++nb) gj[nb] = G[hb + jt * 64 + nb * 16 + fr];
    const bool diag = (jt == it);
    float vv[4][4];
#pragma unroll
    for (int reg = 0; reg < 4; ++reg) {
      float tm = -3e38f;
#pragma unroll
      for (int nb = 0; nb < 4; ++nb) {
        float vx = acc[nb][reg] * 0.125f + Gi[reg] - gj[nb];
        if (diag && (nb * 16 + fr) > row0 + reg) vx = -3e38f;
        vv[nb][reg] = vx;
        tm = fmaxf(tm, vx);
      }
#pragma unroll
      for (int mm = 1; mm <= 8; mm <<= 1) tm = fmaxf(tm, __shfl_xor(tm, mm));
      float mnew = fmaxf(mrow[reg], tm);
      float sc = __expf(mrow[reg] - mnew);
      mrow[reg] = mnew;
      float tsum = 0.f;
#pragma unroll
      for (int nb = 0; nb < 4; ++nb) {
        float p = __expf(vv[nb][reg] - mnew);
        Ps[row0 + reg][nb * 16 + fr] = __float2bfloat16(p);
        tsum += p;
      }
#pragma unroll
      for (int mm = 1; mm <= 8; mm <<= 1) tsum += __shfl_xor(tsum, mm);
      lrow[reg] = lrow[reg] * sc + tsum;
#pragma unroll
      for (int nb = 0; nb < 4; ++nb) acc_o[nb][reg] *= sc;
    }
    __syncthreads();
    const bf16x8 p0 = ldfrag(Ps, w, 0, fr, kq);
    const bf16x8 p1 = ldfrag(Ps, w, 1, fr, kq);
#pragma unroll
    for (int nb = 0; nb < 4; ++nb) {
      acc_o[nb] = MFMA_BF16(p0, ldfrag(Vh, nb, 0, fr, kq), acc_o[nb]);
      acc_o[nb] = MFMA_BF16(p1, ldfrag(Vh, nb, 1, fr, kq), acc_o[nb]);
    }
  }
#pragma unroll
  for (int reg = 0; reg < 4; ++reg) {
    float inv = 1.f / lrow[reg];
    int i = it * 64 + row0 + reg;
#pragma unroll
    for (int nb = 0; nb < 4; ++nb) {
      int dd = nb * 16 + fr;
      size_t oi = ((size_t)(b * T_ + i)) * D_ + h * 64 + dd;
      ohi[oi] = __float2bfloat16(acc_o[nb][reg] * inv);
    }
  }
}

// ======================= launch =======================
extern "C" void kernel_launch(void* const* d_in, const int* in_sizes, int n_in,
                              void* d_out, int out_size, void* d_ws, size_t ws_size,
                              hipStream_t stream) {
  (void)in_sizes; (void)n_in; (void)out_size; (void)ws_size;
  const float* x     = (const float*)d_in[0];
  const float* Wq    = (const float*)d_in[1];
  const float* Wk    = (const float*)d_in[2];
  const float* Wv    = (const float*)d_in[3];
  const float* Wo    = (const float*)d_in[4];
  const float* wA    = (const float*)d_in[5];
  const float* wB    = (const float*)d_in[6];
  const float* convw = (const float*)d_in[7];
  const float* bw    = (const float*)d_in[8];
  const float* gw    = (const float*)d_in[9];
  const float* gb    = (const float*)d_in[10];
  const float* qnw   = (const float*)d_in[11];
  const float* knw   = (const float*)d_in[12];

  const size_t N1 = (size_t)BT_ * D_;          // 1,048,576
  const size_t NTT = (size_t)BH_ * T_ * T_;    // 8,388,608
  float* ws = (float*)d_ws;
  float* wTb   = ws;                       // [BH,T,dh] fp32
  float* ycat  = wTb + N1;                 // [BT,64] fp32
  float* beta  = ycat + (size_t)BT_ * 64;
  float* G     = beta + (size_t)BH_ * T_;
  __hip_bfloat16* qb16  = (__hip_bfloat16*)(G + (size_t)BH_ * T_);
  __hip_bfloat16* kb16  = qb16 + N1;
  __hip_bfloat16* wb16  = kb16 + N1;
  __hip_bfloat16* abT   = wb16 + N1;            // [BH,T(j),T(t)] bf16
  __hip_bfloat16* linvb = abT + NTT;            // [BH,8,64,64] bf16
  __hip_bfloat16* xhi   = linvb + (size_t)BH_ * 8 * 4096;
  __hip_bfloat16* xlo   = xhi + N1;
  __hip_bfloat16* obhi  = xlo + N1;
  __hip_bfloat16* woThi = obhi + N1;
  __hip_bfloat16* vhi   = woThi + N1;           // [BH,dh,T] bf16
  __hip_bfloat16* wcThi = vhi + N1;             // [64][D]
  __hip_bfloat16* wcTlo = wcThi + (size_t)64 * D_;
  __hip_bfloat16* khat  = wcTlo + (size_t)64 * D_;  // [BH,8,T,dh] bf16 = 16.8 MB
  __hip_bfloat16* wqkThi = khat + (size_t)BH_ * 8 * T_ * DH;  // [2048][D]
  __hip_bfloat16* wvThi  = wqkThi + (size_t)2048 * D_;        // [1024][D]

  split_f32<<<1024, 256, 0, stream>>>(x, xhi, xlo);
  splitT4_k<<<dim3(16, 16, 4), 256, 0, stream>>>(
      Wq, Wk, Wv, Wo,
      wqkThi, wqkThi + (size_t)1024 * D_, wvThi, woThi);
  splitcat_k<<<64, 256, 0, stream>>>(wA, bw, gw, wcThi, wcTlo);
  gemm_ycat<<<dim3(1, 16), 256, 0, stream>>>(xhi, xlo, wcThi, wcTlo, ycat);
  // qk projection: 1-pass bf16 + fused rmsnorm -> qb16/kb16 (512 blocks)
  gemm_t<0><<<dim3(32, 16), 256, 0, stream>>>(xhi, nullptr, wqkThi, nullptr,
                                              nullptr, qb16, kb16, qnw, knw);
  // V projection: 1-pass bf16 with transposed epilogue -> vhi (256 blocks)
  gemm_v<<<dim3(16, 16), 256, 0, stream>>>(xhi, wvThi, vhi);
  gate_cumsum<<<BH_, 512, 0, stream>>>(ycat, gb, beta, G);
  wdir_k<<<BT_, 1024, 0, stream>>>(ycat, wB, convw, wTb, wb16);
  linv_k<<<dim3(8, BH_), 256, 0, stream>>>(wTb, beta, linvb);
  chain_k<<<dim3(8, BH_), 256, 0, stream>>>(kb16, wb16, linvb, beta, abT, khat);
  attn_fused<<<dim3(8, BH_), 256, 0, stream>>>(qb16, wb16, khat, abT, vhi, G, obhi);
  // output projection: 1-pass bf16 -> d_out fp32 (256 blocks)
  gemm_t<1><<<dim3(16, 16, 1), 256, 0, stream>>>(obhi, nullptr, woThi, nullptr,
                                                 (float*)d_out, nullptr, nullptr, nullptr, nullptr);
}

// Round 11
// 134.096 us; speedup vs baseline: 2.2981x; 1.2210x over previous
//
#include <hip/hip_runtime.h>
#include <hip/hip_bf16.h>
#include <math.h>

#define B_ 2
#define T_ 512
#define D_ 1024
#define H_ 16
#define R_ 32
#define DH 64
#define BT_ (B_*T_)
#define BH_ (B_*H_)

typedef __attribute__((ext_vector_type(8))) short bf16x8;
typedef __attribute__((ext_vector_type(4))) short s16x4;
typedef __attribute__((ext_vector_type(4))) float f32x4;

#define MFMA_BF16(a, b, c) __builtin_amdgcn_mfma_f32_16x16x32_bf16(a, b, c, 0, 0, 0)

static __device__ __forceinline__ short bf16s(float v) {
  __hip_bfloat16 b = __float2bfloat16(v);
  return *reinterpret_cast<short*>(&b);
}
static __device__ __forceinline__ float b2f(__hip_bfloat16 h) { return __bfloat162float(h); }

// ---- shared MFMA helpers ([72] pad = 144B stride, conflict-free) ----
__device__ __forceinline__ bf16x8 ldfrag(const __hip_bfloat16 s[][72], int b16, int kb, int fr, int kq) {
  return *(const bf16x8*)&s[b16 * 16 + fr][kb * 32 + kq * 8];
}
__device__ __forceinline__ void stage64(const __hip_bfloat16* __restrict__ g, int ldg,
                                        __hip_bfloat16 s[][72], int tid) {
#pragma unroll
  for (int l = 0; l < 2; ++l) {
    int f = tid + l * 256;
    int r = f >> 3, c = (f & 7) << 3;
    *(int4*)&s[r][c] = *(const int4*)&g[(size_t)r * ldg + c];
  }
}

// ---- global_load_lds 16B direct-to-LDS ----
typedef const __attribute__((address_space(1))) void* as1cv;
typedef __attribute__((address_space(3))) void* as3v;
__device__ __forceinline__ void gl16(const __hip_bfloat16* g, __hip_bfloat16* l) {
  __builtin_amdgcn_global_load_lds((as1cv)g, (as3v)l, 16, 0, 0);
}

// ======================= prep: split x (hi/lo), transpose weights (hi), splitcat ==========
// grid.x = 512 (x-split) + 1024 (4 weights x 256) + 64 (wcat) = 1600
__global__ __launch_bounds__(256) void prep_k(const float* __restrict__ x,
                                              const float* __restrict__ Wq,
                                              const float* __restrict__ Wk,
                                              const float* __restrict__ Wv,
                                              const float* __restrict__ Wo,
                                              const float* __restrict__ wA,
                                              const float* __restrict__ bw,
                                              const float* __restrict__ gw,
                                              __hip_bfloat16* __restrict__ xhi,
                                              __hip_bfloat16* __restrict__ xlo,
                                              __hip_bfloat16* __restrict__ wqkvT,  // [3072][D]
                                              __hip_bfloat16* __restrict__ woT,    // [1024][D]
                                              __hip_bfloat16* __restrict__ wcThi,
                                              __hip_bfloat16* __restrict__ wcTlo) {
  __shared__ float tile[64][65];
  const int bid = blockIdx.x, tid = threadIdx.x;
  if (bid < 512) {
    int i8 = bid * 256 + tid;                 // 131072 threads x 8 elems
    float4 v0 = ((const float4*)x)[i8 * 2];
    float4 v1 = ((const float4*)x)[i8 * 2 + 1];
    float c[8] = {v0.x, v0.y, v0.z, v0.w, v1.x, v1.y, v1.z, v1.w};
    bf16x8 ph, pl;
#pragma unroll
    for (int u = 0; u < 8; ++u) {
      __hip_bfloat16 h = __float2bfloat16(c[u]);
      ph[u] = *reinterpret_cast<short*>(&h);
      pl[u] = bf16s(c[u] - __bfloat162float(h));
    }
    *(bf16x8*)&xhi[(size_t)i8 * 8] = ph;
    *(bf16x8*)&xlo[(size_t)i8 * 8] = pl;
  } else if (bid < 1536) {
    const int zz = (bid - 512) >> 8, idx = (bid - 512) & 255;
    const float* Wm = (zz == 0) ? Wq : (zz == 1) ? Wk : (zz == 2) ? Wv : Wo;
    __hip_bfloat16* thi = (zz < 3) ? (wqkvT + (size_t)zz * 1024 * D_) : woT;
    const int bn = (idx & 15) * 64, bk = (idx >> 4) * 64;
#pragma unroll
    for (int l = 0; l < 4; ++l) {
      int f = tid + l * 256; int r = f >> 4, c = (f & 15) << 2;
      *(float4*)&tile[r][c] = *(const float4*)&Wm[(size_t)(bk + r) * D_ + bn + c];
    }
    __syncthreads();
#pragma unroll
    for (int l = 0; l < 4; ++l) {
      int f = tid + l * 256; int n = f >> 4, k0 = (f & 15) << 2;
      s16x4 ph;
#pragma unroll
      for (int u = 0; u < 4; ++u) ph[u] = bf16s(tile[k0 + u][n]);
      *(s16x4*)&thi[(size_t)(bn + n) * D_ + bk + k0] = ph;
    }
  } else {
    int n = bid - 1536;          // 0..63
    for (int k = tid; k < D_; k += 256) {
      float v;
      if (n < 32) v = wA[(size_t)k * R_ + n];
      else if (n < 48) v = bw[(size_t)k * H_ + (n - 32)];
      else v = gw[(size_t)k * H_ + (n - 48)];
      __hip_bfloat16 h = __float2bfloat16(v);
      wcThi[(size_t)n * D_ + k] = h;
      wcTlo[(size_t)n * D_ + k] = __float2bfloat16(v - __bfloat162float(h));
    }
  }
}

// ======================= fused QKV projection: 1-pass bf16, K=1024 =======================
// grid (48,16). bn<2048: q/k with fused rmsnorm -> qb/kb. bn>=2048: V, transposed -> vhi.
__global__ __launch_bounds__(256) void gemm_qkv(const __hip_bfloat16* __restrict__ ah,
                                                const __hip_bfloat16* __restrict__ bT,  // [3072][D]
                                                __hip_bfloat16* __restrict__ qb,
                                                __hip_bfloat16* __restrict__ kb,
                                                __hip_bfloat16* __restrict__ vhi,
                                                const float* __restrict__ qnw,
                                                const float* __restrict__ knw) {
  __shared__ __hip_bfloat16 As[64][64];
  __shared__ __hip_bfloat16 Bs[64][64];
  __shared__ __hip_bfloat16 Lt[64][72];
  const int bm = blockIdx.y * 64, bn = blockIdx.x * 64;
  const int tid = threadIdx.x, w = tid >> 6, lane = tid & 63;
  const int fr = lane & 15, kq = lane >> 4;
  const f32x4 zf = {0.f, 0.f, 0.f, 0.f};
  f32x4 acc[4] = {zf, zf, zf, zf};
  const __hip_bfloat16* ap = ah + (size_t)bm * D_;
  const __hip_bfloat16* bp = bT + (size_t)bn * D_;

  for (int t = 0; t < 16; ++t) {
    __syncthreads();
#pragma unroll
    for (int i = 0; i < 2; ++i) {
      int chunk = tid + i * 256;
      int row = chunk >> 3, c8 = (chunk & 7) ^ (row & 7);
      gl16(ap + (size_t)row * D_ + t * 64 + c8 * 8, &As[0][0] + chunk * 8);
      gl16(bp + (size_t)row * D_ + t * 64 + c8 * 8, &Bs[0][0] + chunk * 8);
    }
    __syncthreads();
    const int ra = w * 16 + fr, sa = ra & 7;
    bf16x8 a0 = *(const bf16x8*)&As[ra][(kq ^ sa) * 8];
    bf16x8 a1 = *(const bf16x8*)&As[ra][((kq + 4) ^ sa) * 8];
#pragma unroll
    for (int n = 0; n < 4; ++n) {
      int rb = n * 16 + fr, sb = rb & 7;
      bf16x8 b0 = *(const bf16x8*)&Bs[rb][(kq ^ sb) * 8];
      bf16x8 b1 = *(const bf16x8*)&Bs[rb][((kq + 4) ^ sb) * 8];
      acc[n] = MFMA_BF16(a0, b0, acc[n]);
      acc[n] = MFMA_BF16(a1, b1, acc[n]);
    }
  }

  if (bn < 2048) {
    float rs[4];
#pragma unroll
    for (int reg = 0; reg < 4; ++reg) {
      float s = 0.f;
#pragma unroll
      for (int n = 0; n < 4; ++n) s += acc[n][reg] * acc[n][reg];
#pragma unroll
      for (int mm = 1; mm <= 8; mm <<= 1) s += __shfl_xor(s, mm);
      rs[reg] = rsqrtf(s * (1.f / DH) + 1e-5f);
    }
    const bool isq = (bn < 1024);
    __hip_bfloat16* outp = isq ? qb : kb;
#pragma unroll
    for (int n = 0; n < 4; ++n) {
      int gn = bn + n * 16 + fr;
      int dd = gn & 63, h = (gn & 1023) >> 6;
      float nw = (isq ? qnw : knw)[dd];
#pragma unroll
      for (int reg = 0; reg < 4; ++reg) {
        int gm = bm + w * 16 + kq * 4 + reg;
        int bb = gm >> 9, tt = gm & 511;
        outp[(((size_t)(bb * H_ + h)) * T_ + tt) * DH + dd] =
            __float2bfloat16(acc[n][reg] * rs[reg] * nw);
      }
    }
  } else {
    const int row0 = w * 16 + kq * 4;
#pragma unroll
    for (int n = 0; n < 4; ++n) {
      int dd = n * 16 + fr;
#pragma unroll
      for (int reg = 0; reg < 4; ++reg) Lt[dd][row0 + reg] = __float2bfloat16(acc[n][reg]);
    }
    __syncthreads();
    const int b = bm >> 9, t0 = bm & 511, h = (bn - 2048) >> 6;
    const size_t base = ((size_t)(b * H_ + h)) * DH * T_;
#pragma unroll
    for (int l = 0; l < 2; ++l) {
      int f = tid + l * 256;
      int dd = f >> 3, tq = (f & 7) * 8;
      *(bf16x8*)&vhi[base + (size_t)dd * T_ + t0 + tq] = *(const bf16x8*)&Lt[dd][tq];
    }
  }
}

// ======================= Wo projection: 1-pass bf16 -> fp32 =======================
__global__ __launch_bounds__(256) void gemm_o(const __hip_bfloat16* __restrict__ ah,
                                              const __hip_bfloat16* __restrict__ bT,
                                              float* __restrict__ C) {
  __shared__ __hip_bfloat16 As[64][64];
  __shared__ __hip_bfloat16 Bs[64][64];
  const int bm = blockIdx.y * 64, bn = blockIdx.x * 64;
  const int tid = threadIdx.x, w = tid >> 6, lane = tid & 63;
  const int fr = lane & 15, kq = lane >> 4;
  const f32x4 zf = {0.f, 0.f, 0.f, 0.f};
  f32x4 acc[4] = {zf, zf, zf, zf};
  const __hip_bfloat16* ap = ah + (size_t)bm * D_;
  const __hip_bfloat16* bp = bT + (size_t)bn * D_;
  for (int t = 0; t < 16; ++t) {
    __syncthreads();
#pragma unroll
    for (int i = 0; i < 2; ++i) {
      int chunk = tid + i * 256;
      int row = chunk >> 3, c8 = (chunk & 7) ^ (row & 7);
      gl16(ap + (size_t)row * D_ + t * 64 + c8 * 8, &As[0][0] + chunk * 8);
      gl16(bp + (size_t)row * D_ + t * 64 + c8 * 8, &Bs[0][0] + chunk * 8);
    }
    __syncthreads();
    const int ra = w * 16 + fr, sa = ra & 7;
    bf16x8 a0 = *(const bf16x8*)&As[ra][(kq ^ sa) * 8];
    bf16x8 a1 = *(const bf16x8*)&As[ra][((kq + 4) ^ sa) * 8];
#pragma unroll
    for (int n = 0; n < 4; ++n) {
      int rb = n * 16 + fr, sb = rb & 7;
      bf16x8 b0 = *(const bf16x8*)&Bs[rb][(kq ^ sb) * 8];
      bf16x8 b1 = *(const bf16x8*)&Bs[rb][((kq + 4) ^ sb) * 8];
      acc[n] = MFMA_BF16(a0, b0, acc[n]);
      acc[n] = MFMA_BF16(a1, b1, acc[n]);
    }
  }
#pragma unroll
  for (int n = 0; n < 4; ++n) {
    int gn = bn + n * 16 + fr;
#pragma unroll
    for (int reg = 0; reg < 4; ++reg) {
      int gm = bm + w * 16 + kq * 4 + reg;
      C[(size_t)gm * D_ + gn] = acc[n][reg];
    }
  }
}

// ======================= ycat partials: 3-pass MFMA over K-quarter z =======================
// grid (4,16): z = K quarter. ypart[z][BT][64] fp32.
__global__ __launch_bounds__(256) void gemm_ycat(const __hip_bfloat16* __restrict__ ah,
                                                 const __hip_bfloat16* __restrict__ al,
                                                 const __hip_bfloat16* __restrict__ bh,
                                                 const __hip_bfloat16* __restrict__ bl,
                                                 float* __restrict__ ypart) {
  __shared__ __hip_bfloat16 Ah[64][72], Al[64][72], Bh[64][72], Bl[64][72];
  const int z = blockIdx.x, bm = blockIdx.y * 64;
  const int tid = threadIdx.x, w = tid >> 6, lane = tid & 63;
  const int fr = lane & 15, kq = lane >> 4;
  const f32x4 zf = {0.f, 0.f, 0.f, 0.f};
  f32x4 acc[4] = {zf, zf, zf, zf};
  float* C = ypart + (size_t)z * (BT_ * 64);
  for (int k0 = z * 256; k0 < z * 256 + 256; k0 += 64) {
    __syncthreads();
    stage64(ah + (size_t)bm * D_ + k0, D_, Ah, tid);
    stage64(al + (size_t)bm * D_ + k0, D_, Al, tid);
    stage64(bh + k0, D_, Bh, tid);
    stage64(bl + k0, D_, Bl, tid);
    __syncthreads();
    bf16x8 ah0 = ldfrag(Ah, w, 0, fr, kq), ah1 = ldfrag(Ah, w, 1, fr, kq);
    bf16x8 al0 = ldfrag(Al, w, 0, fr, kq), al1 = ldfrag(Al, w, 1, fr, kq);
#pragma unroll
    for (int nb = 0; nb < 4; ++nb) {
      bf16x8 b0 = ldfrag(Bh, nb, 0, fr, kq), b1 = ldfrag(Bh, nb, 1, fr, kq);
      bf16x8 c0 = ldfrag(Bl, nb, 0, fr, kq), c1 = ldfrag(Bl, nb, 1, fr, kq);
      acc[nb] = MFMA_BF16(ah0, b0, acc[nb]); acc[nb] = MFMA_BF16(ah1, b1, acc[nb]);
      acc[nb] = MFMA_BF16(ah0, c0, acc[nb]); acc[nb] = MFMA_BF16(ah1, c1, acc[nb]);
      acc[nb] = MFMA_BF16(al0, b0, acc[nb]); acc[nb] = MFMA_BF16(al1, b1, acc[nb]);
    }
  }
#pragma unroll
  for (int nb = 0; nb < 4; ++nb) {
    int n = nb * 16 + fr;
#pragma unroll
    for (int reg = 0; reg < 4; ++reg) {
      int m = bm + w * 16 + kq * 4 + reg;
      C[(size_t)m * 64 + n] = acc[nb][reg];
    }
  }
}

// ======================= gates: beta, logsigmoid + cumsum (sums 4 ypart) ==============
__global__ __launch_bounds__(512) void gate_cumsum(const float* __restrict__ ypart,
                                                   const float* __restrict__ gb,
                                                   float* __restrict__ beta,
                                                   float* __restrict__ G) {
  __shared__ float s[T_];
  int bh = blockIdx.x, b = bh >> 4, h = bh & 15, t = threadIdx.x;
  int bt = b * T_ + t;
  float by = 0.f, gy = gb[h];
#pragma unroll
  for (int z = 0; z < 4; ++z) {
    const float* yp = ypart + (size_t)z * (BT_ * 64) + (size_t)bt * 64;
    by += yp[32 + h];
    gy += yp[48 + h];
  }
  beta[(size_t)bh * T_ + t] = 2.f / (1.f + expf(-by));
  s[t] = fminf(gy, 0.f) - log1pf(expf(-fabsf(gy)));
  __syncthreads();
  for (int off = 1; off < T_; off <<= 1) {
    float v = (t >= off) ? s[t - off] : 0.f;
    __syncthreads();
    s[t] += v;
    __syncthreads();
  }
  G[(size_t)bh * T_ + t] = s[t];
}

// ======================= w: low-rank expand + conv3 + silu + unit-normalize ===========
__global__ __launch_bounds__(1024) void wdir_k(const float* __restrict__ ypart,
                                               const float* __restrict__ wB,
                                               const float* __restrict__ convw,
                                               float* __restrict__ wT,
                                               __hip_bfloat16* __restrict__ wb16) {
  int bt = blockIdx.x, b = bt / T_, t = bt - b * T_;
  __shared__ float wl[3][R_];
  int tid = threadIdx.x;
  if (tid < 3 * R_) {
    int row = tid / R_, r = tid - row * R_;
    int ts = t - row;
    float a = 0.f;
    if (ts >= 0) {
#pragma unroll
      for (int z = 0; z < 4; ++z)
        a += ypart[(size_t)z * (BT_ * 64) + (size_t)(b * T_ + ts) * 64 + r];
    }
    wl[row][r] = a;
  }
  __syncthreads();
  float f0 = 0.f, f1 = 0.f, f2 = 0.f;
  for (int r = 0; r < R_; ++r) {
    float wb = wB[(size_t)r * D_ + tid];
    f0 += wl[0][r] * wb; f1 += wl[1][r] * wb; f2 += wl[2][r] * wb;
  }
  float y = f2 * convw[tid * 3 + 0] + f1 * convw[tid * 3 + 1] + f0 * convw[tid * 3 + 2];
  float s = y / (1.f + expf(-y));                       // silu
  float ss = s * s;
#pragma unroll
  for (int m = 32; m >= 1; m >>= 1) ss += __shfl_xor(ss, m);
  float outv = s * rsqrtf(ss + 1e-12f);
  int h = tid >> 6, dd = tid & 63;
  size_t o = (((size_t)(b * H_ + h)) * T_ + t) * DH + dd;
  wT[o] = outv;
  wb16[o] = __float2bfloat16(outv);
}

// ======================= per-block unit-lower-triangular inverse =======================
__global__ __launch_bounds__(256) void linv_k(const float* __restrict__ wT,
                                              const float* __restrict__ beta,
                                              __hip_bfloat16* __restrict__ linv) {
  __shared__ float Wsh[64][68];
  __shared__ float Csh[64][65];
  __shared__ float Li[64][68];
  __shared__ float bI[64];
  const int I = blockIdx.x, bhx = blockIdx.y;
  const int tid = threadIdx.x;
#pragma unroll
  for (int l = 0; l < 4; ++l) {
    int f = tid + l * 256; int r = f >> 4, c = (f & 15) << 2;
    *(float4*)&Wsh[r][c] = *(const float4*)&wT[((size_t)bhx * T_ + I * 64 + r) * DH + c];
  }
  if (tid < 64) bI[tid] = beta[(size_t)bhx * T_ + I * 64 + tid];
#pragma unroll
  for (int l = 0; l < 16; ++l) {
    int e = tid + l * 256; int r = e >> 6, c = e & 63;
    Li[r][c] = (r == c) ? 1.f : 0.f;
  }
  __syncthreads();
  const int tm = (tid >> 4) << 2, tn = (tid & 15) << 2;
  float cc[4][4] = {};
  for (int dd = 0; dd < 64; ++dd) {
    float a0 = Wsh[tm + 0][dd], a1 = Wsh[tm + 1][dd], a2 = Wsh[tm + 2][dd], a3 = Wsh[tm + 3][dd];
    float b0 = Wsh[tn + 0][dd], b1 = Wsh[tn + 1][dd], b2 = Wsh[tn + 2][dd], b3 = Wsh[tn + 3][dd];
    cc[0][0] += a0 * b0; cc[0][1] += a0 * b1; cc[0][2] += a0 * b2; cc[0][3] += a0 * b3;
    cc[1][0] += a1 * b0; cc[1][1] += a1 * b1; cc[1][2] += a1 * b2; cc[1][3] += a1 * b3;
    cc[2][0] += a2 * b0; cc[2][1] += a2 * b1; cc[2][2] += a2 * b2; cc[2][3] += a2 * b3;
    cc[3][0] += a3 * b0; cc[3][1] += a3 * b1; cc[3][2] += a3 * b2; cc[3][3] += a3 * b3;
  }
#pragma unroll
  for (int ii = 0; ii < 4; ++ii)
#pragma unroll
    for (int jj = 0; jj < 4; ++jj)
      Csh[tm + ii][tn + jj] = (tm + ii > tn + jj) ? cc[ii][jj] * bI[tn + jj] : 0.f;
  __syncthreads();
  const int sL = tid & 63, g = tid >> 6;
  for (int r = 0; r < 63; ++r) {
    float lr = Li[r][sL];
    for (int r2 = r + 1 + g; r2 < 64; r2 += 4)
      Li[r2][sL] -= Csh[r2][r] * lr;
    __syncthreads();
  }
#pragma unroll
  for (int l = 0; l < 4; ++l) {
    int f = tid + l * 256; int r = f >> 4, c0 = (f & 15) << 2;
    s16x4 p;
    p.x = bf16s(Li[r][c0 + 0]); p.y = bf16s(Li[r][c0 + 1]);
    p.z = bf16s(Li[r][c0 + 2]); p.w = bf16s(Li[r][c0 + 3]);
    *(s16x4*)&linv[((size_t)(bhx * 8 + I)) * 4096 + r * 64 + c0] = p;
  }
}

// ======================= WY chain, khat-first form =======================
// Per iter I: Kh = bf16(Kb - M) (LDS + global ckpt); PT = Kh@W^T (mask);
// A = Linv@PT^T; X = (beta A)^T -> abT; M += X@W.  24 MFMA, 4 barriers.
__global__ __launch_bounds__(256) void chain_k(const __hip_bfloat16* __restrict__ kb,
                                               const __hip_bfloat16* __restrict__ wb,
                                               const __hip_bfloat16* __restrict__ linv,
                                               const float* __restrict__ beta,
                                               __hip_bfloat16* __restrict__ abT,
                                               __hip_bfloat16* __restrict__ khat) {
  __shared__ __hip_bfloat16 Kb[64][72];   // [j][d] (persistent)
  __shared__ __hip_bfloat16 Ws[64][72];   // [t][d]
  __shared__ __hip_bfloat16 WsT[64][72];  // [d][t]
  __shared__ __hip_bfloat16 Ls[64][72];   // [t][s]
  __shared__ __hip_bfloat16 Kh[64][72];   // [j][d] = bf16(K - M)
  __shared__ __hip_bfloat16 Ps[64][72];   // [j][t] PT
  __shared__ __hip_bfloat16 Xs[64][72];   // [j][t] X = (beta A)^T
  __shared__ float bI[64];
  const int ch = blockIdx.x, bhx = blockIdx.y;
  const int tid = threadIdx.x, w = tid >> 6, lane = tid & 63;
  const int fr = lane & 15, kq = lane >> 4;
  const int jr = w * 16 + kq * 4;
  const size_t hb = (size_t)bhx * T_;
  const f32x4 zf = {0.f, 0.f, 0.f, 0.f};

  stage64(kb + (hb + ch * 64) * DH, DH, Kb, tid);
  f32x4 macc[4] = {zf, zf, zf, zf};   // M[j][d]: rows jr+reg, cols nb*16+fr

  for (int I = ch; I < 8; ++I) {
    __syncthreads();                                           // B1: prev readers done
    stage64(wb + (hb + I * 64) * DH, DH, Ws, tid);
    stage64(linv + ((size_t)(bhx * 8 + I)) * 4096, 64, Ls, tid);
    if (tid < 64) bI[tid] = beta[hb + I * 64 + tid];
    // Kh = bf16(Kb - M)   (macc == 0 on first iteration -> Kh = Kb)
#pragma unroll
    for (int nb = 0; nb < 4; ++nb) {
      int d = nb * 16 + fr;
#pragma unroll
      for (int reg = 0; reg < 4; ++reg)
        Kh[jr + reg][d] = __float2bfloat16(b2f(Kb[jr + reg][d]) - macc[nb][reg]);
    }
    __syncthreads();                                           // B2: stages + Kh visible
    // khat checkpoint (coalesced)
#pragma unroll
    for (int l = 0; l < 2; ++l) {
      int f = tid + l * 256;
      int r = f >> 3, c = (f & 7) << 3;
      *(int4*)&khat[(((size_t)(bhx * 8 + I)) * T_ + ch * 64 + r) * DH + c] = *(const int4*)&Kh[r][c];
    }
    // W transpose for M update
#pragma unroll
    for (int l = 0; l < 16; ++l) {
      int e = tid + l * 256;
      int t = e >> 6, d = e & 63;
      WsT[d][t] = Ws[t][d];
    }
    // PT = Kh @ Ws^T
    bf16x8 kh0 = ldfrag(Kh, w, 0, fr, kq), kh1 = ldfrag(Kh, w, 1, fr, kq);
    f32x4 pt[4];
#pragma unroll
    for (int nb = 0; nb < 4; ++nb) {
      pt[nb] = MFMA_BF16(kh0, ldfrag(Ws, nb, 0, fr, kq), zf);
      pt[nb] = MFMA_BF16(kh1, ldfrag(Ws, nb, 1, fr, kq), pt[nb]);
    }
#pragma unroll
    for (int nb = 0; nb < 4; ++nb) {
      int t = nb * 16 + fr;
#pragma unroll
      for (int reg = 0; reg < 4; ++reg) {
        float v = pt[nb][reg];
        if (I == ch && t <= jr + reg) v = 0.f;
        Ps[jr + reg][t] = __float2bfloat16(v);
      }
    }
    __syncthreads();                                           // B3: Ps & WsT visible
    // A = Ls @ Ps^T  (rows t, cols j)
    bf16x8 la0 = ldfrag(Ls, w, 0, fr, kq), la1 = ldfrag(Ls, w, 1, fr, kq);
    f32x4 av[4];
#pragma unroll
    for (int nb = 0; nb < 4; ++nb) {
      av[nb] = MFMA_BF16(la0, ldfrag(Ps, nb, 0, fr, kq), zf);
      av[nb] = MFMA_BF16(la1, ldfrag(Ps, nb, 1, fr, kq), av[nb]);
    }
    // X = (beta * A)^T -> Xs[j][t]
#pragma unroll
    for (int nb = 0; nb < 4; ++nb) {
      s16x4 p;
      p.x = bf16s(bI[jr + 0] * av[nb][0]);
      p.y = bf16s(bI[jr + 1] * av[nb][1]);
      p.z = bf16s(bI[jr + 2] * av[nb][2]);
      p.w = bf16s(bI[jr + 3] * av[nb][3]);
      *(s16x4*)&Xs[nb * 16 + fr][jr] = p;
    }
    __syncthreads();                                           // B4: Xs visible
    // abT write + M update: M += Xs @ WsT
#pragma unroll
    for (int l = 0; l < 2; ++l) {
      int f = tid + l * 256;
      int r = f >> 3, c = (f & 7) << 3;
      *(int4*)&abT[(hb + ch * 64 + r) * T_ + I * 64 + c] = *(const int4*)&Xs[r][c];
    }
    bf16x8 xa0 = ldfrag(Xs, w, 0, fr, kq), xa1 = ldfrag(Xs, w, 1, fr, kq);
#pragma unroll
    for (int nb = 0; nb < 4; ++nb) {
      macc[nb] = MFMA_BF16(xa0, ldfrag(WsT, nb, 0, fr, kq), macc[nb]);
      macc[nb] = MFMA_BF16(xa1, ldfrag(WsT, nb, 1, fr, kq), macc[nb]);
    }
  }
}

// ======================= fused attention row-panel: S -> online softmax -> PV ==========
__global__ __launch_bounds__(256) void attn_fused(const __hip_bfloat16* __restrict__ qb,
                                                  const __hip_bfloat16* __restrict__ wb,
                                                  const __hip_bfloat16* __restrict__ khat,
                                                  const __hip_bfloat16* __restrict__ abT,
                                                  const __hip_bfloat16* __restrict__ vhi,
                                                  const float* __restrict__ G,
                                                  __hip_bfloat16* __restrict__ ohi) {
  __shared__ __hip_bfloat16 Ms[64][72];   // masked -(Q W^T), persistent
  __shared__ __hip_bfloat16 Ks[64][72];   // khat tile [j][d] (init: Q)
  __shared__ __hip_bfloat16 Cs[64][72];   // abT tile [j][t]  (init: W)
  __shared__ __hip_bfloat16 Vh[64][72];   // V [dd][t]
  __shared__ __hip_bfloat16 Ps[64][72];   // P bf16 [i][t]
  const int it = blockIdx.x, bh = blockIdx.y;
  const int b = bh >> 4, h = bh & 15;
  const int tid = threadIdx.x, w = tid >> 6, lane = tid & 63;
  const int fr = lane & 15, kq = lane >> 4;
  const int row0 = w * 16 + kq * 4;
  const size_t hb = (size_t)bh * T_;
  const f32x4 zero = {0.f, 0.f, 0.f, 0.f};

  stage64(qb + (hb + it * 64) * DH, DH, Ks, tid);
  stage64(wb + (hb + it * 64) * DH, DH, Cs, tid);
  __syncthreads();
  const bf16x8 a0 = ldfrag(Ks, w, 0, fr, kq);
  const bf16x8 a1 = ldfrag(Ks, w, 1, fr, kq);
  f32x4 qw[4];
#pragma unroll
  for (int nb = 0; nb < 4; ++nb) {
    qw[nb] = MFMA_BF16(a0, ldfrag(Cs, nb, 0, fr, kq), zero);
    qw[nb] = MFMA_BF16(a1, ldfrag(Cs, nb, 1, fr, kq), qw[nb]);
  }
#pragma unroll
  for (int nb = 0; nb < 4; ++nb) {
    int col = nb * 16 + fr;
#pragma unroll
    for (int reg = 0; reg < 4; ++reg) {
      float v = -qw[nb][reg];
      if (col > row0 + reg) v = 0.f;
      Ms[row0 + reg][col] = __float2bfloat16(v);
    }
  }
  __syncthreads();
  const bf16x8 m0 = ldfrag(Ms, w, 0, fr, kq);
  const bf16x8 m1 = ldfrag(Ms, w, 1, fr, kq);

  float Gi[4];
#pragma unroll
  for (int reg = 0; reg < 4; ++reg) Gi[reg] = G[hb + it * 64 + row0 + reg];
  float mrow[4] = {-3e38f, -3e38f, -3e38f, -3e38f};
  float lrow[4] = {0.f, 0.f, 0.f, 0.f};
  f32x4 acc_o[4] = {zero, zero, zero, zero};
  const __hip_bfloat16* kh = khat + ((size_t)(bh * 8 + it)) * T_ * DH;

  for (int jt = 0; jt <= it; ++jt) {
    __syncthreads();
    stage64(kh + (size_t)(jt * 64) * DH, DH, Ks, tid);
    stage64(abT + (hb + jt * 64) * T_ + it * 64, T_, Cs, tid);
    stage64(vhi + (size_t)bh * DH * T_ + jt * 64, T_, Vh, tid);
    __syncthreads();
    f32x4 acc[4];
#pragma unroll
    for (int nb = 0; nb < 4; ++nb) {
      acc[nb] = MFMA_BF16(a0, ldfrag(Ks, nb, 0, fr, kq), zero);
      acc[nb] = MFMA_BF16(a1, ldfrag(Ks, nb, 1, fr, kq), acc[nb]);
      acc[nb] = MFMA_BF16(m0, ldfrag(Cs, nb, 0, fr, kq), acc[nb]);
      acc[nb] = MFMA_BF16(m1, ldfrag(Cs, nb, 1, fr, kq), acc[nb]);
    }
    float gj[4];
#pragma unroll
    for (int nb = 0; nb < 4; ++nb) gj[nb] = G[hb + jt * 64 + nb * 16 + fr];
    const bool diag = (jt == it);
    float vv[4][4];
#pragma unroll
    for (int reg = 0; reg < 4; ++reg) {
      float tm = -3e38f;
#pragma unroll
      for (int nb = 0; nb < 4; ++nb) {
        float vx = acc[nb][reg] * 0.125f + Gi[reg] - gj[nb];
        if (diag && (nb * 16 + fr) > row0 + reg) vx = -3e38f;
        vv[nb][reg] = vx;
        tm = fmaxf(tm, vx);
      }
#pragma unroll
      for (int mm = 1; mm <= 8; mm <<= 1) tm = fmaxf(tm, __shfl_xor(tm, mm));
      float mnew = fmaxf(mrow[reg], tm);
      float sc = __expf(mrow[reg] - mnew);
      mrow[reg] = mnew;
      float tsum = 0.f;
#pragma unroll
      for (int nb = 0; nb < 4; ++nb) {
        float p = __expf(vv[nb][reg] - mnew);
        Ps[row0 + reg][nb * 16 + fr] = __float2bfloat16(p);
        tsum += p;
      }
#pragma unroll
      for (int mm = 1; mm <= 8; mm <<= 1) tsum += __shfl_xor(tsum, mm);
      lrow[reg] = lrow[reg] * sc + tsum;
#pragma unroll
      for (int nb = 0; nb < 4; ++nb) acc_o[nb][reg] *= sc;
    }
    __syncthreads();
    const bf16x8 p0 = ldfrag(Ps, w, 0, fr, kq);
    const bf16x8 p1 = ldfrag(Ps, w, 1, fr, kq);
#pragma unroll
    for (int nb = 0; nb < 4; ++nb) {
      acc_o[nb] = MFMA_BF16(p0, ldfrag(Vh, nb, 0, fr, kq), acc_o[nb]);
      acc_o[nb] = MFMA_BF16(p1, ldfrag(Vh, nb, 1, fr, kq), acc_o[nb]);
    }
  }
#pragma unroll
  for (int reg = 0; reg < 4; ++reg) {
    float inv = 1.f / lrow[reg];
    int i = it * 64 + row0 + reg;
#pragma unroll
    for (int nb = 0; nb < 4; ++nb) {
      int dd = nb * 16 + fr;
      size_t oi = ((size_t)(b * T_ + i)) * D_ + h * 64 + dd;
      ohi[oi] = __float2bfloat16(acc_o[nb][reg] * inv);
    }
  }
}

// ======================= launch =======================
extern "C" void kernel_launch(void* const* d_in, const int* in_sizes, int n_in,
                              void* d_out, int out_size, void* d_ws, size_t ws_size,
                              hipStream_t stream) {
  (void)in_sizes; (void)n_in; (void)out_size; (void)ws_size;
  const float* x     = (const float*)d_in[0];
  const float* Wq    = (const float*)d_in[1];
  const float* Wk    = (const float*)d_in[2];
  const float* Wv    = (const float*)d_in[3];
  const float* Wo    = (const float*)d_in[4];
  const float* wA    = (const float*)d_in[5];
  const float* wB    = (const float*)d_in[6];
  const float* convw = (const float*)d_in[7];
  const float* bw    = (const float*)d_in[8];
  const float* gw    = (const float*)d_in[9];
  const float* gb    = (const float*)d_in[10];
  const float* qnw   = (const float*)d_in[11];
  const float* knw   = (const float*)d_in[12];

  const size_t N1 = (size_t)BT_ * D_;          // 1,048,576
  const size_t NTT = (size_t)BH_ * T_ * T_;    // 8,388,608
  float* ws = (float*)d_ws;
  float* wTb   = ws;                       // [BH,T,dh] fp32
  float* ypart = wTb + N1;                 // [4][BT][64] fp32
  float* beta  = ypart + (size_t)4 * BT_ * 64;
  float* G     = beta + (size_t)BH_ * T_;
  __hip_bfloat16* qb16  = (__hip_bfloat16*)(G + (size_t)BH_ * T_);
  __hip_bfloat16* kb16  = qb16 + N1;
  __hip_bfloat16* wb16  = kb16 + N1;
  __hip_bfloat16* abT   = wb16 + N1;            // [BH,T(j),T(t)] bf16
  __hip_bfloat16* linvb = abT + NTT;            // [BH,8,64,64] bf16
  __hip_bfloat16* xhi   = linvb + (size_t)BH_ * 8 * 4096;
  __hip_bfloat16* xlo   = xhi + N1;
  __hip_bfloat16* obhi  = xlo + N1;
  __hip_bfloat16* woThi = obhi + N1;
  __hip_bfloat16* vhi   = woThi + N1;           // [BH,dh,T] bf16
  __hip_bfloat16* wcThi = vhi + N1;             // [64][D]
  __hip_bfloat16* wcTlo = wcThi + (size_t)64 * D_;
  __hip_bfloat16* khat  = wcTlo + (size_t)64 * D_;  // [BH,8,T,dh] bf16
  __hip_bfloat16* wqkvT = khat + (size_t)BH_ * 8 * T_ * DH;  // [3072][D] (Wq|Wk|Wv)

  prep_k<<<1600, 256, 0, stream>>>(x, Wq, Wk, Wv, Wo, wA, bw, gw,
                                   xhi, xlo, wqkvT, woThi, wcThi, wcTlo);
  gemm_ycat<<<dim3(4, 16), 256, 0, stream>>>(xhi, xlo, wcThi, wcTlo, ypart);
  // fused Q|K|V projection: 1-pass bf16, rmsnorm/V-transpose epilogues (768 blocks)
  gemm_qkv<<<dim3(48, 16), 256, 0, stream>>>(xhi, wqkvT, qb16, kb16, vhi, qnw, knw);
  gate_cumsum<<<BH_, 512, 0, stream>>>(ypart, gb, beta, G);
  wdir_k<<<BT_, 1024, 0, stream>>>(ypart, wB, convw, wTb, wb16);
  linv_k<<<dim3(8, BH_), 256, 0, stream>>>(wTb, beta, linvb);
  chain_k<<<dim3(8, BH_), 256, 0, stream>>>(kb16, wb16, linvb, beta, abT, khat);
  attn_fused<<<dim3(8, BH_), 256, 0, stream>>>(qb16, wb16, khat, abT, vhi, G, obhi);
  gemm_o<<<dim3(16, 16), 256, 0, stream>>>(obhi, woThi, (float*)d_out);
}